// Round 2
// baseline (2207.666 us; speedup 1.0000x reference)
//
#include <hip/hip_runtime.h>
#include <hip/hip_bf16.h>
#include <math.h>

// ---------------- block-wide sum & sumsq reduction ----------------
__device__ __forceinline__ void block_reduce2(float& a, float& b, float* sbuf){
  __syncthreads();               // protect sbuf reuse
  for (int off = 32; off; off >>= 1){
    a += __shfl_down(a, off);
    b += __shfl_down(b, off);
  }
  int lane = threadIdx.x & 63, w = threadIdx.x >> 6;
  if (lane == 0){ sbuf[2*w] = a; sbuf[2*w+1] = b; }
  __syncthreads();
  if (threadIdx.x == 0){
    int nw = blockDim.x >> 6;
    float sa = 0.f, sb = 0.f;
    for (int i = 0; i < nw; i++){ sa += sbuf[2*i]; sb += sbuf[2*i+1]; }
    sbuf[0] = sa; sbuf[1] = sb;
  }
  __syncthreads();
  a = sbuf[0]; b = sbuf[1];
}

// ---------------- tiled GEMM: C[M,N] = A[M,K] @ B[K,N] + bias ----------------
__global__ __launch_bounds__(256) void gemm_bias(
    const float* __restrict__ A, const float* __restrict__ B, const float* __restrict__ bias,
    float* __restrict__ C, int M, int N, int K)
{
  __shared__ float As[16][65];
  __shared__ float Bs[16][64];
  int tid = threadIdx.x;
  int tx = tid & 15, ty = tid >> 4;
  int bm = blockIdx.y * 64, bn = blockIdx.x * 64;
  float acc[4][4] = {};
  for (int k0 = 0; k0 < K; k0 += 16){
    for (int l = tid; l < 64*16; l += 256){
      int r = l >> 4, kk = l & 15;
      int gr = bm + r, gk = k0 + kk;
      As[kk][r] = (gr < M && gk < K) ? A[(size_t)gr*K + gk] : 0.f;
    }
    for (int l = tid; l < 16*64; l += 256){
      int kk = l >> 6, n = l & 63;
      int gk = k0 + kk, gn = bn + n;
      Bs[kk][n] = (gk < K && gn < N) ? B[(size_t)gk*N + gn] : 0.f;
    }
    __syncthreads();
    #pragma unroll
    for (int kk = 0; kk < 16; kk++){
      float a[4], b[4];
      #pragma unroll
      for (int i = 0; i < 4; i++) a[i] = As[kk][ty*4+i];
      #pragma unroll
      for (int j = 0; j < 4; j++) b[j] = Bs[kk][tx*4+j];
      #pragma unroll
      for (int i = 0; i < 4; i++)
        #pragma unroll
        for (int j = 0; j < 4; j++) acc[i][j] += a[i]*b[j];
    }
    __syncthreads();
  }
  for (int i = 0; i < 4; i++){
    int gr = bm + ty*4 + i;
    if (gr >= M) continue;
    for (int j = 0; j < 4; j++){
      int gn = bn + tx*4 + j;
      if (gn < N) C[(size_t)gr*N + gn] = acc[i][j] + bias[gn];
    }
  }
}

// ---------------- row LN + activation ----------------
// act: 0 none, 1 relu, 2 elu, 3 tanh, 4 sigmoid
__global__ __launch_bounds__(256) void row_ln(
    const float* __restrict__ in, int is, float* __restrict__ out, int os, int N, int act)
{
  __shared__ float sbuf[16];
  int row = blockIdx.x;
  const float* ip = in + (size_t)row*is;
  float s = 0.f, s2 = 0.f;
  for (int c = threadIdx.x; c < N; c += blockDim.x){ float v = ip[c]; s += v; s2 += v*v; }
  block_reduce2(s, s2, sbuf);
  float m = s / N;
  float r = rsqrtf(s2/N - m*m + 1e-5f);
  float* op = out + (size_t)row*os;
  for (int c = threadIdx.x; c < N; c += blockDim.x){
    float v = (ip[c]-m)*r;
    if (act == 1) v = fmaxf(v, 0.f);
    else if (act == 2) v = v > 0.f ? v : expm1f(v);
    else if (act == 3) v = tanhf(v);
    else if (act == 4) v = 1.f/(1.f+expf(-v));
    op[c] = v;
  }
}

// ---------------- encoder conv1: x([n,64,64,1]) -> (n,32,32,16), ln_all+elu ----------------
__global__ __launch_bounds__(256) void enc_conv1(
    const float* __restrict__ x, const float* __restrict__ w, const float* __restrict__ bias,
    float* __restrict__ out)
{
  __shared__ float wl[256];
  __shared__ float bs[16];
  __shared__ float sbuf[16];
  int n = blockIdx.x, tid = threadIdx.x;
  { int o = tid >> 4, c = tid & 15; wl[c*16 + o] = w[o*16 + c]; }
  if (tid < 16) bs[tid] = bias[tid];
  __syncthreads();
  const float* xin = x + (size_t)n*4096;
  float acc[64];
  float s = 0.f, s2 = 0.f;
  for (int r = 0; r < 64; r++){
    int idx = tid + (r<<8);
    int o = idx & 15, bq = (idx>>4)&31, aq = idx>>9;
    float a = 0.f;
    for (int kh = 0; kh < 4; kh++){
      int bb = 2*bq - 1 + kh;
      if ((unsigned)bb >= 64u) continue;
      for (int kw = 0; kw < 4; kw++){
        int aa = 2*aq - 1 + kw;
        if ((unsigned)aa >= 64u) continue;
        a += xin[aa*64 + bb] * wl[(kh*4+kw)*16 + o];
      }
    }
    a += bs[o];
    acc[r] = a; s += a; s2 += a*a;
  }
  block_reduce2(s, s2, sbuf);
  float m = s * (1.f/16384.f);
  float rs = rsqrtf(s2*(1.f/16384.f) - m*m + 1e-5f);
  float* op = out + (size_t)n*16384;
  for (int r = 0; r < 64; r++){
    float v = (acc[r]-m)*rs;
    op[tid + (r<<8)] = v > 0.f ? v : expm1f(v);
  }
}

// ---------------- encoder conv2: (n,32,32,16) -> (n,16,16,32), ln_all+elu ----------------
__global__ __launch_bounds__(256) void enc_conv2(
    const float* __restrict__ in, const float* __restrict__ w, const float* __restrict__ bias,
    float* __restrict__ out)
{
  __shared__ float wl[8192];   // [(i*16+kh*4+kw)][o32]
  __shared__ float bs[32];
  __shared__ float sbuf[16];
  int n = blockIdx.x, tid = threadIdx.x;
  for (int l = tid; l < 8192; l += 256){
    int o = l >> 8, c = l & 255;
    wl[c*32 + o] = w[l];
  }
  if (tid < 32) bs[tid] = bias[tid];
  __syncthreads();
  const float* ip = in + (size_t)n*16384;
  float acc[32]; float s = 0.f, s2 = 0.f;
  for (int r = 0; r < 32; r++){
    int idx = tid + (r<<8);
    int o = idx & 31, bq = (idx>>5)&15, aq = idx>>9;
    float a = 0.f;
    for (int kh = 0; kh < 4; kh++){
      int bb = 2*bq-1+kh; if ((unsigned)bb >= 32u) continue;
      for (int kw = 0; kw < 4; kw++){
        int aa = 2*aq-1+kw; if ((unsigned)aa >= 32u) continue;
        const float* px = ip + aa*512 + bb*16;
        const float* pw = wl + (kh*4+kw)*32 + o;
        #pragma unroll
        for (int i = 0; i < 16; i++) a += px[i] * pw[i*512];
      }
    }
    a += bs[o];
    acc[r] = a; s += a; s2 += a*a;
  }
  block_reduce2(s, s2, sbuf);
  float m = s*(1.f/8192.f);
  float rs = rsqrtf(s2*(1.f/8192.f) - m*m + 1e-5f);
  float* op = out + (size_t)n*8192;
  for (int r = 0; r < 32; r++){
    float v = (acc[r]-m)*rs;
    op[tid+(r<<8)] = v > 0.f ? v : expm1f(v);
  }
}

// ---------------- encoder conv3: (n,16,16,32) -> (n,8,8,64), ln_all+elu ----------------
__global__ __launch_bounds__(256) void enc_conv3(
    const float* __restrict__ in, const float* __restrict__ w, const float* __restrict__ bias,
    float* __restrict__ out)
{
  __shared__ float wl[8192];   // chunk of 8 i: [(il*16+c)][o64]
  __shared__ float bs[64];
  __shared__ float sbuf[16];
  int n = blockIdx.x, tid = threadIdx.x;
  if (tid < 64) bs[tid] = bias[tid];
  const float* ip = in + (size_t)n*8192;
  float acc[16] = {};
  for (int i0 = 0; i0 < 32; i0 += 8){
    __syncthreads();
    for (int l = tid; l < 8192; l += 256){
      int o = l & 63, q = l >> 6;       // q = il*16 + c
      int c = q & 15, il = q >> 4;
      wl[l] = w[o*512 + (i0+il)*16 + c];
    }
    __syncthreads();
    for (int r = 0; r < 16; r++){
      int idx = tid + (r<<8);
      int o = idx & 63, bq = (idx>>6)&7, aq = idx>>9;
      float a = 0.f;
      for (int kh = 0; kh < 4; kh++){
        int bb = 2*bq-1+kh; if ((unsigned)bb >= 16u) continue;
        for (int kw = 0; kw < 4; kw++){
          int aa = 2*aq-1+kw; if ((unsigned)aa >= 16u) continue;
          const float* px = ip + aa*512 + bb*32 + i0;
          const float* pw = wl + (kh*4+kw)*64 + o;
          #pragma unroll
          for (int il = 0; il < 8; il++) a += px[il] * pw[il*1024];
        }
      }
      acc[r] += a;
    }
  }
  float s = 0.f, s2 = 0.f;
  for (int r = 0; r < 16; r++){
    float a = acc[r] + bs[tid & 63];
    acc[r] = a; s += a; s2 += a*a;
  }
  block_reduce2(s, s2, sbuf);
  float m = s*(1.f/4096.f);
  float rs = rsqrtf(s2*(1.f/4096.f) - m*m + 1e-5f);
  float* op = out + (size_t)n*4096;
  for (int r = 0; r < 16; r++){
    float v = (acc[r]-m)*rs;
    op[tid+(r<<8)] = v > 0.f ? v : expm1f(v);
  }
}

// ---------------- pair build ----------------
__global__ __launch_bounds__(256) void pair_build(const float* __restrict__ tot, float* __restrict__ P)
{
  int r = blockIdx.x;            // 0..2687 = (j*8+i)*7+jj
  int jj = r % 7, fi = r / 7;
  int i = fi & 7, j = fi >> 3;
  int jidx = jj < i ? jj : jj+1;
  const float* srcf = tot + (size_t)fi*1012;
  const float* srco = tot + (size_t)(j*8+jidx)*1012;
  float* op = P + (size_t)r*500;
  for (int c = threadIdx.x; c < 250; c += blockDim.x){
    op[c] = srcf[c];
    op[250+c] = srco[c];
  }
}

// ---------------- att2: sigmoid(A1 @ w + b) ----------------
__global__ void att2_kernel(const float* __restrict__ A1, const float* __restrict__ w,
                            const float* __restrict__ b, float* __restrict__ att)
{
  int r = blockIdx.x*blockDim.x + threadIdx.x;
  if (r >= 2688) return;
  const float* ip = A1 + (size_t)r*100;
  float a = b[0];
  for (int c = 0; c < 100; c++) a += ip[c]*w[c];
  att[r] = 1.f/(1.f+expf(-a));
}

// ---------------- effect: sum over jj of ctx*att -> tot[:,250:500) ----------------
__global__ __launch_bounds__(256) void effect_kernel(const float* __restrict__ X1,
    const float* __restrict__ att, float* __restrict__ tot)
{
  int row = blockIdx.x;
  for (int h = threadIdx.x; h < 250; h += blockDim.x){
    float s = 0.f;
    for (int jj = 0; jj < 7; jj++)
      s += X1[((size_t)row*7+jj)*250 + h] * att[row*7+jj];
    tot[(size_t)row*1012 + 250 + h] = s;
  }
}

// ---------------- new_state: xr = sigmoid(ln(ns)), state_out = sigmoid(ns) ----------------
__global__ __launch_bounds__(256) void ns_kernel(const float* __restrict__ NS,
    float* __restrict__ XR, float* __restrict__ so)
{
  __shared__ float sbuf[16];
  int row = blockIdx.x;
  const float* ip = NS + (size_t)row*250;
  float s = 0.f, s2 = 0.f;
  for (int c = threadIdx.x; c < 250; c += blockDim.x){ float v = ip[c]; s += v; s2 += v*v; }
  block_reduce2(s, s2, sbuf);
  float m = s/250.f;
  float rs = rsqrtf(s2/250.f - m*m + 1e-5f);
  for (int c = threadIdx.x; c < 250; c += blockDim.x){
    float v = ip[c];
    XR[(size_t)row*250+c] = 1.f/(1.f+expf(-((v-m)*rs)));
    so[(size_t)row*250+c] = 1.f/(1.f+expf(-v));
  }
}

// ---------------- fold 4x4 weights over x4-upsample into phase 2x2 taps ----------------
// CW idx = (i*16 + pb*8 + pa*4 + db*2 + da)*O + o
__global__ void fold_kernel(const float* __restrict__ w, float* __restrict__ CW, int O, int I)
{
  int total = O*I*16;
  for (int l = blockIdx.x*blockDim.x + threadIdx.x; l < total; l += gridDim.x*blockDim.x){
    int o = l % O; int q = l / O;
    int da = q & 1, db = (q>>1)&1, pa = (q>>2)&1, pb = (q>>3)&1, i = q>>4;
    float s = 0.f;
    for (int kh = 0; kh < 4; kh++){
      bool inh = (pb==0) ? (db==0 ? (kh==0) : (kh>=1)) : (db==0 ? (kh<=2) : (kh==3));
      if (!inh) continue;
      for (int kw = 0; kw < 4; kw++){
        bool inw = (pa==0) ? (da==0 ? (kw==0) : (kw>=1)) : (da==0 ? (kw<=2) : (kw==3));
        if (!inw) continue;
        s += w[((o*I + i)*4 + kh)*4 + kw];
      }
    }
    CW[l] = s;
  }
}

// ---------------- decoder conv1: (n,8,8,64) -> (n,16,16,32), ln_all+relu ----------------
__global__ __launch_bounds__(256) void dec_conv1(
    const float* __restrict__ in, const float* __restrict__ CW, const float* __restrict__ bias,
    float* __restrict__ out)
{
  __shared__ float wl[8192];    // 16 i chunk
  __shared__ float bs[32];
  __shared__ float sbuf[16];
  int n = blockIdx.x, tid = threadIdx.x;
  if (tid < 32) bs[tid] = bias[tid];
  const float* ip = in + (size_t)n*4096;
  float acc[32] = {};
  for (int i0 = 0; i0 < 64; i0 += 16){
    __syncthreads();
    for (int l = tid; l < 8192; l += 256) wl[l] = CW[(size_t)i0*512 + l];
    __syncthreads();
    for (int r = 0; r < 32; r++){
      int idx = tid + (r<<8);
      int o = idx & 31, bq = (idx>>5)&15, aq = idx>>9;
      int ta = aq>>1, pa = aq&1, tb = bq>>1, pb = bq&1;
      float a = 0.f;
      #pragma unroll
      for (int db = 0; db < 2; db++){
        int sb = tb + db + (pb ? 0 : -1);
        if ((unsigned)sb >= 8u) continue;
        #pragma unroll
        for (int da = 0; da < 2; da++){
          int sa = ta + da + (pa ? 0 : -1);
          if ((unsigned)sa >= 8u) continue;
          const float* px = ip + sa*512 + sb*64 + i0;
          const float* pw = wl + (pb*8+pa*4+db*2+da)*32 + o;
          #pragma unroll
          for (int il = 0; il < 16; il++) a += px[il] * pw[il*512];
        }
      }
      acc[r] += a;
    }
  }
  float s = 0.f, s2 = 0.f;
  for (int r = 0; r < 32; r++){
    float a = acc[r] + bs[tid & 31];
    acc[r] = a; s += a; s2 += a*a;
  }
  block_reduce2(s, s2, sbuf);
  float m = s*(1.f/8192.f);
  float rs = rsqrtf(s2*(1.f/8192.f) - m*m + 1e-5f);
  float* op = out + (size_t)n*8192;
  for (int r = 0; r < 32; r++){
    float v = (acc[r]-m)*rs;
    op[tid+(r<<8)] = fmaxf(v, 0.f);
  }
}

// ---------------- decoder conv2: (n,16,16,32) -> (n,32,32,16), ln_all+relu ----------------
__global__ __launch_bounds__(256) void dec_conv2(
    const float* __restrict__ in, const float* __restrict__ CW, const float* __restrict__ bias,
    float* __restrict__ out)
{
  __shared__ float wl[8192];    // full: 32 i * 16 phases * 16 o
  __shared__ float bs[16];
  __shared__ float sbuf[16];
  int n = blockIdx.x, tid = threadIdx.x;
  if (tid < 16) bs[tid] = bias[tid];
  for (int l = tid; l < 8192; l += 256) wl[l] = CW[l];
  __syncthreads();
  const float* ip = in + (size_t)n*8192;
  float acc[64] = {};
  for (int r = 0; r < 64; r++){
    int idx = tid + (r<<8);
    int o = idx & 15, bq = (idx>>4)&31, aq = idx>>9;
    int ta = aq>>1, pa = aq&1, tb = bq>>1, pb = bq&1;
    float a = 0.f;
    #pragma unroll
    for (int db = 0; db < 2; db++){
      int sb = tb + db + (pb ? 0 : -1);
      if ((unsigned)sb >= 16u) continue;
      #pragma unroll
      for (int da = 0; da < 2; da++){
        int sa = ta + da + (pa ? 0 : -1);
        if ((unsigned)sa >= 16u) continue;
        const float* px = ip + sa*512 + sb*32;
        const float* pw = wl + (pb*8+pa*4+db*2+da)*16 + o;
        #pragma unroll
        for (int il = 0; il < 32; il++) a += px[il] * pw[il*256];
      }
    }
    acc[r] = a + bs[o];
  }
  float s = 0.f, s2 = 0.f;
  for (int r = 0; r < 64; r++){ s += acc[r]; s2 += acc[r]*acc[r]; }
  block_reduce2(s, s2, sbuf);
  float m = s*(1.f/16384.f);
  float rs = rsqrtf(s2*(1.f/16384.f) - m*m + 1e-5f);
  float* op = out + (size_t)n*16384;
  for (int r = 0; r < 64; r++){
    float v = (acc[r]-m)*rs;
    op[tid+(r<<8)] = fmaxf(v, 0.f);
  }
}

// ---------------- decoder conv3: (n,32,32,16) -> (n,64,64,1), sigmoid ----------------
__global__ __launch_bounds__(256) void dec_conv3(
    const float* __restrict__ in, const float* __restrict__ CW, const float* __restrict__ bias,
    float* __restrict__ out)
{
  __shared__ float wl[256];
  int n = blockIdx.x, tid = threadIdx.x;
  if (tid < 256) wl[tid] = CW[tid];
  __syncthreads();
  float bv = bias[0];
  const float* ip = in + (size_t)n*16384;
  float* op = out + (size_t)n*4096;
  for (int r = 0; r < 16; r++){
    int idx = tid + (r<<8);
    int bq = idx & 63, aq = idx >> 6;
    int ta = aq>>1, pa = aq&1, tb = bq>>1, pb = bq&1;
    float a = bv;
    #pragma unroll
    for (int db = 0; db < 2; db++){
      int sb = tb + db + (pb ? 0 : -1);
      if ((unsigned)sb >= 32u) continue;
      #pragma unroll
      for (int da = 0; da < 2; da++){
        int sa = ta + da + (pa ? 0 : -1);
        if ((unsigned)sa >= 32u) continue;
        const float* px = ip + sa*512 + sb*16;
        const float* pw = wl + (pb*8+pa*4+db*2+da);
        #pragma unroll
        for (int il = 0; il < 16; il++) a += px[il] * pw[il*16];
      }
    }
    op[idx] = 1.f/(1.f+expf(-a));
  }
}

extern "C" void kernel_launch(void* const* d_in, const int* in_sizes, int n_in,
                              void* d_out, int out_size, void* d_ws, size_t ws_size,
                              hipStream_t stream) {
  const float* x      = (const float*)d_in[0];
  const float* state  = (const float*)d_in[1];
  const float* c1w    = (const float*)d_in[2];
  const float* c1b    = (const float*)d_in[3];
  const float* c2w    = (const float*)d_in[4];
  const float* c2b    = (const float*)d_in[5];
  const float* c3w    = (const float*)d_in[6];
  const float* c3b    = (const float*)d_in[7];
  const float* efc_w  = (const float*)d_in[8];
  const float* efc_b  = (const float*)d_in[9];
  const float* renc_w = (const float*)d_in[10];
  const float* renc_b = (const float*)d_in[11];
  const float* core_w = (const float*)d_in[12];
  const float* core_b = (const float*)d_in[13];
  const float* ctx_w  = (const float*)d_in[14];
  const float* ctx_b  = (const float*)d_in[15];
  const float* att1_w = (const float*)d_in[16];
  const float* att1_b = (const float*)d_in[17];
  const float* att2_w = (const float*)d_in[18];
  const float* att2_b = (const float*)d_in[19];
  const float* out_w  = (const float*)d_in[20];
  const float* out_b  = (const float*)d_in[21];
  const float* dfc1_w = (const float*)d_in[22];
  const float* dfc1_b = (const float*)d_in[23];
  const float* dfc2_w = (const float*)d_in[24];
  const float* dfc2_b = (const float*)d_in[25];
  const float* d1w    = (const float*)d_in[26];
  const float* d1b    = (const float*)d_in[27];
  const float* d2w    = (const float*)d_in[28];
  const float* d2b    = (const float*)d_in[29];
  const float* d3w    = (const float*)d_in[30];
  const float* d3b    = (const float*)d_in[31];

  float* wsf = (float*)d_ws;
  size_t o = 0;
  float* E1  = wsf + o; o += (size_t)384*16384;   // also D2O (dec2 out)
  float* E2  = wsf + o; o += (size_t)384*8192;    // also D1O (dec1 out)
  float* E3  = wsf + o; o += (size_t)384*4096;    // also G2 (dfc2 out)
  float* TOT = wsf + o; o += (size_t)384*1012;
  float* F1  = wsf + o; o += (size_t)384*512;
  float* R1  = wsf + o; o += (size_t)384*250;
  float* P   = wsf + o; o += (size_t)2688*500;
  float* C1  = wsf + o; o += (size_t)2688*250;
  float* X1  = wsf + o; o += (size_t)2688*250;
  float* A1  = wsf + o; o += (size_t)2688*100;
  float* ATT = wsf + o; o += 2688;
  float* NS  = wsf + o; o += (size_t)384*250;
  float* XR  = wsf + o; o += (size_t)384*250;
  float* G1  = wsf + o; o += (size_t)384*512;
  float* CW1 = wsf + o; o += 32768;
  float* CW2 = wsf + o; o += 8192;
  float* CW3 = wsf + o; o += 256;
  float* D2O = E1;
  float* D1O = E2;
  float* G2  = E3;

  float* xout = (float*)d_out;                   // 384*4096
  float* sout = xout + (size_t)384*4096;         // 384*250

  // weight folding (independent of main chain)
  fold_kernel<<<128, 256, 0, stream>>>(d1w, CW1, 32, 64);
  fold_kernel<<<32, 256, 0, stream>>>(d2w, CW2, 16, 32);
  fold_kernel<<<1, 256, 0, stream>>>(d3w, CW3, 1, 16);

  // encoder
  enc_conv1<<<384, 256, 0, stream>>>(x, c1w, c1b, E1);
  enc_conv2<<<384, 256, 0, stream>>>(E1, c2w, c2b, E2);
  enc_conv3<<<384, 256, 0, stream>>>(E2, c3w, c3b, E3);
  gemm_bias<<<dim3(8,6), 256, 0, stream>>>(E3, efc_w, efc_b, F1, 384, 512, 4096);
  row_ln<<<384, 256, 0, stream>>>(F1, 512, TOT+500, 1012, 512, 2);       // elu -> tot[:,500:1012)

  // state path
  gemm_bias<<<dim3(4,6), 256, 0, stream>>>(state, renc_w, renc_b, R1, 384, 250, 250);
  row_ln<<<384, 256, 0, stream>>>(R1, 250, TOT, 1012, 250, 1);           // relu -> tot[:,0:250)
  pair_build<<<2688, 256, 0, stream>>>(TOT, P);
  gemm_bias<<<dim3(4,42), 256, 0, stream>>>(P, core_w, core_b, C1, 2688, 250, 500);
  row_ln<<<2688, 256, 0, stream>>>(C1, 250, C1, 250, 250, 1);            // relu in-place
  gemm_bias<<<dim3(4,42), 256, 0, stream>>>(C1, ctx_w, ctx_b, X1, 2688, 250, 250);
  row_ln<<<2688, 256, 0, stream>>>(X1, 250, X1, 250, 250, 1);
  gemm_bias<<<dim3(2,42), 256, 0, stream>>>(C1, att1_w, att1_b, A1, 2688, 100, 250);
  row_ln<<<2688, 256, 0, stream>>>(A1, 100, A1, 100, 100, 3);            // tanh
  att2_kernel<<<11, 256, 0, stream>>>(A1, att2_w, att2_b, ATT);
  effect_kernel<<<384, 256, 0, stream>>>(X1, ATT, TOT);                  // -> tot[:,250:500)

  // combine
  gemm_bias<<<dim3(4,6), 256, 0, stream>>>(TOT, out_w, out_b, NS, 384, 250, 1012);
  ns_kernel<<<384, 256, 0, stream>>>(NS, XR, sout);

  // decoder FC
  gemm_bias<<<dim3(8,6), 256, 0, stream>>>(XR, dfc1_w, dfc1_b, G1, 384, 512, 250);
  row_ln<<<384, 256, 0, stream>>>(G1, 512, G1, 512, 512, 1);
  gemm_bias<<<dim3(64,6), 256, 0, stream>>>(G1, dfc2_w, dfc2_b, G2, 384, 4096, 512);
  row_ln<<<384, 256, 0, stream>>>(G2, 4096, G2, 4096, 4096, 1);

  // decoder convs
  dec_conv1<<<384, 256, 0, stream>>>(G2, CW1, d1b, D1O);
  dec_conv2<<<384, 256, 0, stream>>>(D1O, CW2, d2b, D2O);
  dec_conv3<<<384, 256, 0, stream>>>(D2O, CW3, d3b, xout);

  (void)in_sizes; (void)n_in; (void)out_size; (void)ws_size;
}

// Round 3
// 1149.314 us; speedup vs baseline: 1.9209x; 1.9209x over previous
//
#include <hip/hip_runtime.h>
#include <hip/hip_bf16.h>
#include <math.h>

// ---------------- block-wide sum & sumsq reduction ----------------
__device__ __forceinline__ void block_reduce2(float& a, float& b, float* sbuf){
  __syncthreads();
  for (int off = 32; off; off >>= 1){
    a += __shfl_down(a, off);
    b += __shfl_down(b, off);
  }
  int lane = threadIdx.x & 63, w = threadIdx.x >> 6;
  if (lane == 0){ sbuf[2*w] = a; sbuf[2*w+1] = b; }
  __syncthreads();
  if (threadIdx.x == 0){
    int nw = blockDim.x >> 6;
    float sa = 0.f, sb = 0.f;
    for (int i = 0; i < nw; i++){ sa += sbuf[2*i]; sb += sbuf[2*i+1]; }
    sbuf[0] = sa; sbuf[1] = sb;
  }
  __syncthreads();
  a = sbuf[0]; b = sbuf[1];
}

// ---------------- split-K GEMM: P[ks][M][N] partial of A[M,K] @ B[K,N] ----------------
// grid (N/64, M/64, KS); register double-buffered staging.
__global__ __launch_bounds__(256) void gemm_splitk(
    const float* __restrict__ A, const float* __restrict__ B,
    float* __restrict__ P, int M, int N, int K, int KS)
{
  __shared__ float As[16][65];
  __shared__ float Bs[16][64];
  int tid = threadIdx.x;
  int tx = tid & 15, ty = tid >> 4;
  int bm = blockIdx.y * 64, bn = blockIdx.x * 64;
  int ks = blockIdx.z;
  int Kc = (K + KS - 1) / KS;
  int kb = ks * Kc;
  int ke = min(K, kb + Kc);

  // each thread stages 4 A elems + 4 B elems per k-tile
  float aR[4], bR[4];
  int ar[4], ak[4], bk[4], bn_[4];
  #pragma unroll
  for (int idx = 0; idx < 4; idx++){
    int l = tid + idx*256;
    ar[idx] = l >> 4; ak[idx] = l & 15;      // A tile: 64 rows x 16 k
    bk[idx] = l >> 6; bn_[idx] = l & 63;     // B tile: 16 k x 64 n
  }

  auto load_regs = [&](int k0){
    #pragma unroll
    for (int idx = 0; idx < 4; idx++){
      int gr = bm + ar[idx], gk = k0 + ak[idx];
      aR[idx] = (gr < M && gk < ke) ? A[(size_t)gr*K + gk] : 0.f;
      int gk2 = k0 + bk[idx], gn = bn + bn_[idx];
      bR[idx] = (gk2 < ke && gn < N) ? B[(size_t)gk2*N + gn] : 0.f;
    }
  };
  auto write_lds = [&](){
    #pragma unroll
    for (int idx = 0; idx < 4; idx++){
      As[ak[idx]][ar[idx]] = aR[idx];
      Bs[bk[idx]][bn_[idx]] = bR[idx];
    }
  };

  float acc[4][4] = {};
  load_regs(kb);
  write_lds();
  __syncthreads();
  for (int k0 = kb; k0 < ke; k0 += 16){
    int nxt = k0 + 16;
    if (nxt < ke) load_regs(nxt);            // issue next tile's global loads
    #pragma unroll
    for (int kk = 0; kk < 16; kk++){
      float a[4], b[4];
      #pragma unroll
      for (int i = 0; i < 4; i++) a[i] = As[kk][ty*4+i];
      #pragma unroll
      for (int j = 0; j < 4; j++) b[j] = Bs[kk][tx*4+j];
      #pragma unroll
      for (int i = 0; i < 4; i++)
        #pragma unroll
        for (int j = 0; j < 4; j++) acc[i][j] += a[i]*b[j];
    }
    __syncthreads();
    if (nxt < ke){ write_lds(); __syncthreads(); }
  }
  float* Pout = P + (size_t)ks*M*N;
  for (int i = 0; i < 4; i++){
    int gr = bm + ty*4 + i;
    if (gr >= M) continue;
    for (int j = 0; j < 4; j++){
      int gn = bn + tx*4 + j;
      if (gn < N) Pout[(size_t)gr*N + gn] = acc[i][j];
    }
  }
}

// ---------------- fused: out = act(LN_last(sum_ks P + bias)) ----------------
// act: 0 none, 1 relu, 2 elu, 3 tanh, 4 sigmoid
__global__ __launch_bounds__(256) void reduce_ln(
    const float* __restrict__ Pp, const float* __restrict__ bias,
    float* __restrict__ out, int M, int N, int KS, int os, int act)
{
  __shared__ float rowbuf[4096];
  __shared__ float sbuf[16];
  int row = blockIdx.x;
  size_t MN = (size_t)M*N;
  float s = 0.f, s2 = 0.f;
  for (int c = threadIdx.x; c < N; c += 256){
    float v = bias[c];
    for (int ks = 0; ks < KS; ks++) v += Pp[ks*MN + (size_t)row*N + c];
    rowbuf[c] = v; s += v; s2 += v*v;
  }
  block_reduce2(s, s2, sbuf);
  float m = s / N;
  float r = rsqrtf(s2/N - m*m + 1e-5f);
  float* op = out + (size_t)row*os;
  for (int c = threadIdx.x; c < N; c += 256){
    float v = (rowbuf[c]-m)*r;
    if (act == 1) v = fmaxf(v, 0.f);
    else if (act == 2) v = v > 0.f ? v : expm1f(v);
    else if (act == 3) v = tanhf(v);
    else if (act == 4) v = 1.f/(1.f+expf(-v));
    op[c] = v;
  }
}

// ---------------- fused NS: XR = sigmoid(LN(v)), sout = sigmoid(v), v = sum P + bias ----------------
__global__ __launch_bounds__(256) void reduce_ns(
    const float* __restrict__ Pp, const float* __restrict__ bias,
    float* __restrict__ XR, float* __restrict__ so, int M, int N, int KS)
{
  __shared__ float rowbuf[256];
  __shared__ float sbuf[16];
  int row = blockIdx.x;
  size_t MN = (size_t)M*N;
  float s = 0.f, s2 = 0.f;
  for (int c = threadIdx.x; c < N; c += 256){
    float v = bias[c];
    for (int ks = 0; ks < KS; ks++) v += Pp[ks*MN + (size_t)row*N + c];
    rowbuf[c] = v; s += v; s2 += v*v;
  }
  block_reduce2(s, s2, sbuf);
  float m = s / N;
  float r = rsqrtf(s2/N - m*m + 1e-5f);
  for (int c = threadIdx.x; c < N; c += 256){
    float v = rowbuf[c];
    XR[(size_t)row*N+c] = 1.f/(1.f+expf(-((v-m)*r)));
    so[(size_t)row*N+c] = 1.f/(1.f+expf(-v));
  }
}

// ---------------- encoder conv1: x([n,64,64,1]) -> (n,32,32,16), ln_all+elu ----------------
__global__ __launch_bounds__(256) void enc_conv1(
    const float* __restrict__ x, const float* __restrict__ w, const float* __restrict__ bias,
    float* __restrict__ out)
{
  __shared__ float wl[256];
  __shared__ float bs[16];
  __shared__ float sbuf[16];
  int n = blockIdx.x, tid = threadIdx.x;
  { int o = tid >> 4, c = tid & 15; wl[c*16 + o] = w[o*16 + c]; }
  if (tid < 16) bs[tid] = bias[tid];
  __syncthreads();
  const float* xin = x + (size_t)n*4096;
  float acc[64];
  float s = 0.f, s2 = 0.f;
  for (int r = 0; r < 64; r++){
    int idx = tid + (r<<8);
    int o = idx & 15, bq = (idx>>4)&31, aq = idx>>9;
    float a = 0.f;
    for (int kh = 0; kh < 4; kh++){
      int bb = 2*bq - 1 + kh;
      if ((unsigned)bb >= 64u) continue;
      for (int kw = 0; kw < 4; kw++){
        int aa = 2*aq - 1 + kw;
        if ((unsigned)aa >= 64u) continue;
        a += xin[aa*64 + bb] * wl[(kh*4+kw)*16 + o];
      }
    }
    a += bs[o];
    acc[r] = a; s += a; s2 += a*a;
  }
  block_reduce2(s, s2, sbuf);
  float m = s * (1.f/16384.f);
  float rs = rsqrtf(s2*(1.f/16384.f) - m*m + 1e-5f);
  float* op = out + (size_t)n*16384;
  for (int r = 0; r < 64; r++){
    float v = (acc[r]-m)*rs;
    op[tid + (r<<8)] = v > 0.f ? v : expm1f(v);
  }
}

// ---------------- encoder conv2: (n,32,32,16) -> (n,16,16,32), ln_all+elu ----------------
__global__ __launch_bounds__(256) void enc_conv2(
    const float* __restrict__ in, const float* __restrict__ w, const float* __restrict__ bias,
    float* __restrict__ out)
{
  __shared__ float wl[8192];
  __shared__ float bs[32];
  __shared__ float sbuf[16];
  int n = blockIdx.x, tid = threadIdx.x;
  for (int l = tid; l < 8192; l += 256){
    int o = l >> 8, c = l & 255;
    wl[c*32 + o] = w[l];
  }
  if (tid < 32) bs[tid] = bias[tid];
  __syncthreads();
  const float* ip = in + (size_t)n*16384;
  float acc[32]; float s = 0.f, s2 = 0.f;
  for (int r = 0; r < 32; r++){
    int idx = tid + (r<<8);
    int o = idx & 31, bq = (idx>>5)&15, aq = idx>>9;
    float a = 0.f;
    for (int kh = 0; kh < 4; kh++){
      int bb = 2*bq-1+kh; if ((unsigned)bb >= 32u) continue;
      for (int kw = 0; kw < 4; kw++){
        int aa = 2*aq-1+kw; if ((unsigned)aa >= 32u) continue;
        const float* px = ip + aa*512 + bb*16;
        const float* pw = wl + (kh*4+kw)*32 + o;
        #pragma unroll
        for (int i = 0; i < 16; i++) a += px[i] * pw[i*512];
      }
    }
    a += bs[o];
    acc[r] = a; s += a; s2 += a*a;
  }
  block_reduce2(s, s2, sbuf);
  float m = s*(1.f/8192.f);
  float rs = rsqrtf(s2*(1.f/8192.f) - m*m + 1e-5f);
  float* op = out + (size_t)n*8192;
  for (int r = 0; r < 32; r++){
    float v = (acc[r]-m)*rs;
    op[tid+(r<<8)] = v > 0.f ? v : expm1f(v);
  }
}

// ---------------- encoder conv3: (n,16,16,32) -> (n,8,8,64), ln_all+elu ----------------
__global__ __launch_bounds__(256) void enc_conv3(
    const float* __restrict__ in, const float* __restrict__ w, const float* __restrict__ bias,
    float* __restrict__ out)
{
  __shared__ float wl[8192];
  __shared__ float bs[64];
  __shared__ float sbuf[16];
  int n = blockIdx.x, tid = threadIdx.x;
  if (tid < 64) bs[tid] = bias[tid];
  const float* ip = in + (size_t)n*8192;
  float acc[16] = {};
  for (int i0 = 0; i0 < 32; i0 += 8){
    __syncthreads();
    for (int l = tid; l < 8192; l += 256){
      int o = l & 63, q = l >> 6;
      int c = q & 15, il = q >> 4;
      wl[l] = w[o*512 + (i0+il)*16 + c];
    }
    __syncthreads();
    for (int r = 0; r < 16; r++){
      int idx = tid + (r<<8);
      int o = idx & 63, bq = (idx>>6)&7, aq = idx>>9;
      float a = 0.f;
      for (int kh = 0; kh < 4; kh++){
        int bb = 2*bq-1+kh; if ((unsigned)bb >= 16u) continue;
        for (int kw = 0; kw < 4; kw++){
          int aa = 2*aq-1+kw; if ((unsigned)aa >= 16u) continue;
          const float* px = ip + aa*512 + bb*32 + i0;
          const float* pw = wl + (kh*4+kw)*64 + o;
          #pragma unroll
          for (int il = 0; il < 8; il++) a += px[il] * pw[il*1024];
        }
      }
      acc[r] += a;
    }
  }
  float s = 0.f, s2 = 0.f;
  for (int r = 0; r < 16; r++){
    float a = acc[r] + bs[tid & 63];
    acc[r] = a; s += a; s2 += a*a;
  }
  block_reduce2(s, s2, sbuf);
  float m = s*(1.f/4096.f);
  float rs = rsqrtf(s2*(1.f/4096.f) - m*m + 1e-5f);
  float* op = out + (size_t)n*4096;
  for (int r = 0; r < 16; r++){
    float v = (acc[r]-m)*rs;
    op[tid+(r<<8)] = v > 0.f ? v : expm1f(v);
  }
}

// ---------------- pair build ----------------
__global__ __launch_bounds__(256) void pair_build(const float* __restrict__ tot, float* __restrict__ P)
{
  int r = blockIdx.x;            // (j*8+i)*7+jj
  int jj = r % 7, fi = r / 7;
  int i = fi & 7, j = fi >> 3;
  int jidx = jj < i ? jj : jj+1;
  const float* srcf = tot + (size_t)fi*1012;
  const float* srco = tot + (size_t)(j*8+jidx)*1012;
  float* op = P + (size_t)r*500;
  for (int c = threadIdx.x; c < 250; c += blockDim.x){
    op[c] = srcf[c];
    op[250+c] = srco[c];
  }
}

// ---------------- att2: sigmoid(A1 @ w + b) ----------------
__global__ void att2_kernel(const float* __restrict__ A1, const float* __restrict__ w,
                            const float* __restrict__ b, float* __restrict__ att)
{
  int r = blockIdx.x*blockDim.x + threadIdx.x;
  if (r >= 2688) return;
  const float* ip = A1 + (size_t)r*100;
  float a = b[0];
  for (int c = 0; c < 100; c++) a += ip[c]*w[c];
  att[r] = 1.f/(1.f+expf(-a));
}

// ---------------- effect: sum over jj of ctx*att -> tot[:,250:500) ----------------
__global__ __launch_bounds__(256) void effect_kernel(const float* __restrict__ X1,
    const float* __restrict__ att, float* __restrict__ tot)
{
  int row = blockIdx.x;
  for (int h = threadIdx.x; h < 250; h += blockDim.x){
    float s = 0.f;
    for (int jj = 0; jj < 7; jj++)
      s += X1[((size_t)row*7+jj)*250 + h] * att[row*7+jj];
    tot[(size_t)row*1012 + 250 + h] = s;
  }
}

// ---------------- fold 4x4 weights over x4-upsample into phase 2x2 taps ----------------
__global__ void fold_kernel(const float* __restrict__ w, float* __restrict__ CW, int O, int I)
{
  int total = O*I*16;
  for (int l = blockIdx.x*blockDim.x + threadIdx.x; l < total; l += gridDim.x*blockDim.x){
    int o = l % O; int q = l / O;
    int da = q & 1, db = (q>>1)&1, pa = (q>>2)&1, pb = (q>>3)&1, i = q>>4;
    float s = 0.f;
    for (int kh = 0; kh < 4; kh++){
      bool inh = (pb==0) ? (db==0 ? (kh==0) : (kh>=1)) : (db==0 ? (kh<=2) : (kh==3));
      if (!inh) continue;
      for (int kw = 0; kw < 4; kw++){
        bool inw = (pa==0) ? (da==0 ? (kw==0) : (kw>=1)) : (da==0 ? (kw<=2) : (kw==3));
        if (!inw) continue;
        s += w[((o*I + i)*4 + kh)*4 + kw];
      }
    }
    CW[l] = s;
  }
}

// ---------------- decoder conv1: (n,8,8,64) -> (n,16,16,32), ln_all+relu ----------------
__global__ __launch_bounds__(256) void dec_conv1(
    const float* __restrict__ in, const float* __restrict__ CW, const float* __restrict__ bias,
    float* __restrict__ out)
{
  __shared__ float wl[8192];
  __shared__ float bs[32];
  __shared__ float sbuf[16];
  int n = blockIdx.x, tid = threadIdx.x;
  if (tid < 32) bs[tid] = bias[tid];
  const float* ip = in + (size_t)n*4096;
  float acc[32] = {};
  for (int i0 = 0; i0 < 64; i0 += 16){
    __syncthreads();
    for (int l = tid; l < 8192; l += 256) wl[l] = CW[(size_t)i0*512 + l];
    __syncthreads();
    for (int r = 0; r < 32; r++){
      int idx = tid + (r<<8);
      int o = idx & 31, bq = (idx>>5)&15, aq = idx>>9;
      int ta = aq>>1, pa = aq&1, tb = bq>>1, pb = bq&1;
      float a = 0.f;
      #pragma unroll
      for (int db = 0; db < 2; db++){
        int sb = tb + db + (pb ? 0 : -1);
        if ((unsigned)sb >= 8u) continue;
        #pragma unroll
        for (int da = 0; da < 2; da++){
          int sa = ta + da + (pa ? 0 : -1);
          if ((unsigned)sa >= 8u) continue;
          const float* px = ip + sa*512 + sb*64 + i0;
          const float* pw = wl + (pb*8+pa*4+db*2+da)*32 + o;
          #pragma unroll
          for (int il = 0; il < 16; il++) a += px[il] * pw[il*512];
        }
      }
      acc[r] += a;
    }
  }
  float s = 0.f, s2 = 0.f;
  for (int r = 0; r < 32; r++){
    float a = acc[r] + bs[tid & 31];
    acc[r] = a; s += a; s2 += a*a;
  }
  block_reduce2(s, s2, sbuf);
  float m = s*(1.f/8192.f);
  float rs = rsqrtf(s2*(1.f/8192.f) - m*m + 1e-5f);
  float* op = out + (size_t)n*8192;
  for (int r = 0; r < 32; r++){
    float v = (acc[r]-m)*rs;
    op[tid+(r<<8)] = fmaxf(v, 0.f);
  }
}

// ---------------- decoder conv2: (n,16,16,32) -> (n,32,32,16), ln_all+relu ----------------
__global__ __launch_bounds__(256) void dec_conv2(
    const float* __restrict__ in, const float* __restrict__ CW, const float* __restrict__ bias,
    float* __restrict__ out)
{
  __shared__ float wl[8192];
  __shared__ float bs[16];
  __shared__ float sbuf[16];
  int n = blockIdx.x, tid = threadIdx.x;
  if (tid < 16) bs[tid] = bias[tid];
  for (int l = tid; l < 8192; l += 256) wl[l] = CW[l];
  __syncthreads();
  const float* ip = in + (size_t)n*8192;
  float acc[64] = {};
  for (int r = 0; r < 64; r++){
    int idx = tid + (r<<8);
    int o = idx & 15, bq = (idx>>4)&31, aq = idx>>9;
    int ta = aq>>1, pa = aq&1, tb = bq>>1, pb = bq&1;
    float a = 0.f;
    #pragma unroll
    for (int db = 0; db < 2; db++){
      int sb = tb + db + (pb ? 0 : -1);
      if ((unsigned)sb >= 16u) continue;
      #pragma unroll
      for (int da = 0; da < 2; da++){
        int sa = ta + da + (pa ? 0 : -1);
        if ((unsigned)sa >= 16u) continue;
        const float* px = ip + sa*512 + sb*32;
        const float* pw = wl + (pb*8+pa*4+db*2+da)*16 + o;
        #pragma unroll
        for (int il = 0; il < 32; il++) a += px[il] * pw[il*256];
      }
    }
    acc[r] = a + bs[o];
  }
  float s = 0.f, s2 = 0.f;
  for (int r = 0; r < 64; r++){ s += acc[r]; s2 += acc[r]*acc[r]; }
  block_reduce2(s, s2, sbuf);
  float m = s*(1.f/16384.f);
  float rs = rsqrtf(s2*(1.f/16384.f) - m*m + 1e-5f);
  float* op = out + (size_t)n*16384;
  for (int r = 0; r < 64; r++){
    float v = (acc[r]-m)*rs;
    op[tid+(r<<8)] = fmaxf(v, 0.f);
  }
}

// ---------------- decoder conv3: (n,32,32,16) -> (n,64,64,1), sigmoid ----------------
__global__ __launch_bounds__(256) void dec_conv3(
    const float* __restrict__ in, const float* __restrict__ CW, const float* __restrict__ bias,
    float* __restrict__ out)
{
  __shared__ float wl[256];
  int n = blockIdx.x, tid = threadIdx.x;
  if (tid < 256) wl[tid] = CW[tid];
  __syncthreads();
  float bv = bias[0];
  const float* ip = in + (size_t)n*16384;
  float* op = out + (size_t)n*4096;
  for (int r = 0; r < 16; r++){
    int idx = tid + (r<<8);
    int bq = idx & 63, aq = idx >> 6;
    int ta = aq>>1, pa = aq&1, tb = bq>>1, pb = bq&1;
    float a = bv;
    #pragma unroll
    for (int db = 0; db < 2; db++){
      int sb = tb + db + (pb ? 0 : -1);
      if ((unsigned)sb >= 32u) continue;
      #pragma unroll
      for (int da = 0; da < 2; da++){
        int sa = ta + da + (pa ? 0 : -1);
        if ((unsigned)sa >= 32u) continue;
        const float* px = ip + sa*512 + sb*16;
        const float* pw = wl + (pb*8+pa*4+db*2+da);
        #pragma unroll
        for (int il = 0; il < 16; il++) a += px[il] * pw[il*16];
      }
    }
    op[idx] = 1.f/(1.f+expf(-a));
  }
}

extern "C" void kernel_launch(void* const* d_in, const int* in_sizes, int n_in,
                              void* d_out, int out_size, void* d_ws, size_t ws_size,
                              hipStream_t stream) {
  const float* x      = (const float*)d_in[0];
  const float* state  = (const float*)d_in[1];
  const float* c1w    = (const float*)d_in[2];
  const float* c1b    = (const float*)d_in[3];
  const float* c2w    = (const float*)d_in[4];
  const float* c2b    = (const float*)d_in[5];
  const float* c3w    = (const float*)d_in[6];
  const float* c3b    = (const float*)d_in[7];
  const float* efc_w  = (const float*)d_in[8];
  const float* efc_b  = (const float*)d_in[9];
  const float* renc_w = (const float*)d_in[10];
  const float* renc_b = (const float*)d_in[11];
  const float* core_w = (const float*)d_in[12];
  const float* core_b = (const float*)d_in[13];
  const float* ctx_w  = (const float*)d_in[14];
  const float* ctx_b  = (const float*)d_in[15];
  const float* att1_w = (const float*)d_in[16];
  const float* att1_b = (const float*)d_in[17];
  const float* att2_w = (const float*)d_in[18];
  const float* att2_b = (const float*)d_in[19];
  const float* out_w  = (const float*)d_in[20];
  const float* out_b  = (const float*)d_in[21];
  const float* dfc1_w = (const float*)d_in[22];
  const float* dfc1_b = (const float*)d_in[23];
  const float* dfc2_w = (const float*)d_in[24];
  const float* dfc2_b = (const float*)d_in[25];
  const float* d1w    = (const float*)d_in[26];
  const float* d1b    = (const float*)d_in[27];
  const float* d2w    = (const float*)d_in[28];
  const float* d2b    = (const float*)d_in[29];
  const float* d3w    = (const float*)d_in[30];
  const float* d3b    = (const float*)d_in[31];

  float* wsf = (float*)d_ws;
  size_t o = 0;
  float* E1  = wsf + o; o += (size_t)384*16384;   // also PB (gemm partials) and D2O
  float* E2  = wsf + o; o += (size_t)384*8192;    // also D1O
  float* E3  = wsf + o; o += (size_t)384*4096;    // also G2
  float* TOT = wsf + o; o += (size_t)384*1012;
  float* Pr  = wsf + o; o += (size_t)2688*500;
  float* C1  = wsf + o; o += (size_t)2688*250;
  float* X1  = wsf + o; o += (size_t)2688*250;
  float* A1  = wsf + o; o += (size_t)2688*100;
  float* ATT = wsf + o; o += 2688;
  float* XR  = wsf + o; o += (size_t)384*250;
  float* G1  = wsf + o; o += (size_t)384*512;
  float* CW1 = wsf + o; o += 32768;
  float* CW2 = wsf + o; o += 8192;
  float* CW3 = wsf + o; o += 256;
  float* PB  = E1;     // gemm partial buffer (max 1.57M floats; E1 is 6.29M and dead then)
  float* D2O = E1;
  float* D1O = E2;
  float* G2  = E3;

  float* xout = (float*)d_out;                   // 384*4096
  float* sout = xout + (size_t)384*4096;         // 384*250

  // weight folding (independent of main chain)
  fold_kernel<<<128, 256, 0, stream>>>(d1w, CW1, 32, 64);
  fold_kernel<<<32, 256, 0, stream>>>(d2w, CW2, 16, 32);
  fold_kernel<<<1, 256, 0, stream>>>(d3w, CW3, 1, 16);

  // encoder
  enc_conv1<<<384, 256, 0, stream>>>(x, c1w, c1b, E1);
  enc_conv2<<<384, 256, 0, stream>>>(E1, c2w, c2b, E2);
  enc_conv3<<<384, 256, 0, stream>>>(E2, c3w, c3b, E3);
  gemm_splitk<<<dim3(8,6,8), 256, 0, stream>>>(E3, efc_w, PB, 384, 512, 4096, 8);
  reduce_ln<<<384, 256, 0, stream>>>(PB, efc_b, TOT+500, 384, 512, 8, 1012, 2);  // elu

  // state path
  gemm_splitk<<<dim3(4,6,8), 256, 0, stream>>>(state, renc_w, PB, 384, 250, 250, 8);
  reduce_ln<<<384, 256, 0, stream>>>(PB, renc_b, TOT, 384, 250, 8, 1012, 1);     // relu
  pair_build<<<2688, 256, 0, stream>>>(TOT, Pr);
  gemm_splitk<<<dim3(4,42,2), 256, 0, stream>>>(Pr, core_w, PB, 2688, 250, 500, 2);
  reduce_ln<<<2688, 256, 0, stream>>>(PB, core_b, C1, 2688, 250, 2, 250, 1);
  gemm_splitk<<<dim3(4,42,2), 256, 0, stream>>>(C1, ctx_w, PB, 2688, 250, 250, 2);
  reduce_ln<<<2688, 256, 0, stream>>>(PB, ctx_b, X1, 2688, 250, 2, 250, 1);
  gemm_splitk<<<dim3(2,42,4), 256, 0, stream>>>(C1, att1_w, PB, 2688, 100, 250, 4);
  reduce_ln<<<2688, 256, 0, stream>>>(PB, att1_b, A1, 2688, 100, 4, 100, 3);     // tanh
  att2_kernel<<<11, 256, 0, stream>>>(A1, att2_w, att2_b, ATT);
  effect_kernel<<<384, 256, 0, stream>>>(X1, ATT, TOT);

  // combine
  gemm_splitk<<<dim3(4,6,8), 256, 0, stream>>>(TOT, out_w, PB, 384, 250, 1012, 8);
  reduce_ns<<<384, 256, 0, stream>>>(PB, out_b, XR, sout, 384, 250, 8);

  // decoder FC
  gemm_splitk<<<dim3(8,6,4), 256, 0, stream>>>(XR, dfc1_w, PB, 384, 512, 250, 4);
  reduce_ln<<<384, 256, 0, stream>>>(PB, dfc1_b, G1, 384, 512, 4, 512, 1);
  gemm_splitk<<<dim3(64,6,1), 256, 0, stream>>>(G1, dfc2_w, PB, 384, 4096, 512, 1);
  reduce_ln<<<384, 256, 0, stream>>>(PB, dfc2_b, G2, 384, 4096, 1, 4096, 1);

  // decoder convs
  dec_conv1<<<384, 256, 0, stream>>>(G2, CW1, d1b, D1O);
  dec_conv2<<<384, 256, 0, stream>>>(D1O, CW2, d2b, D2O);
  dec_conv3<<<384, 256, 0, stream>>>(D2O, CW3, d3b, xout);

  (void)in_sizes; (void)n_in; (void)out_size; (void)ws_size;
}

// Round 4
// 790.503 us; speedup vs baseline: 2.7927x; 1.4539x over previous
//
#include <hip/hip_runtime.h>
#include <hip/hip_bf16.h>
#include <math.h>

// stats slots (sum,sumsq per sample), 384 samples each
#define ST_ENC2 0
#define ST_ENC3 1
#define ST_DEC1 2
#define ST_DEC2 3

__device__ __forceinline__ float eluf(float v){ return v > 0.f ? v : expm1f(v); }
__device__ __forceinline__ float sigf(float v){ return 1.f/(1.f+expf(-v)); }

// ---------------- block-wide sum & sumsq reduction ----------------
__device__ __forceinline__ void block_reduce2(float& a, float& b, float* sbuf){
  __syncthreads();
  for (int off = 32; off; off >>= 1){
    a += __shfl_down(a, off);
    b += __shfl_down(b, off);
  }
  int lane = threadIdx.x & 63, w = threadIdx.x >> 6;
  if (lane == 0){ sbuf[2*w] = a; sbuf[2*w+1] = b; }
  __syncthreads();
  if (threadIdx.x == 0){
    int nw = blockDim.x >> 6;
    float sa = 0.f, sb = 0.f;
    for (int i = 0; i < nw; i++){ sa += sbuf[2*i]; sb += sbuf[2*i+1]; }
    sbuf[0] = sa; sbuf[1] = sb;
  }
  __syncthreads();
  a = sbuf[0]; b = sbuf[1];
}

// ---------------- zero stats ----------------
__global__ void zero_stats(float* __restrict__ st){
  int i = blockIdx.x*blockDim.x + threadIdx.x;
  if (i < 4*384*2) st[i] = 0.f;
}

// ---------------- weight transpose: WT[(t*I+i)*O+o] = w[o][i][t] ----------------
__global__ void transpose_w(const float* __restrict__ w, float* __restrict__ WT, int O, int I){
  int total = O*I*16;
  for (int l = blockIdx.x*blockDim.x + threadIdx.x; l < total; l += gridDim.x*blockDim.x){
    int o = l % O; int q = l / O; int i = q % I; int t = q / I;
    WT[(t*I + i)*O + o] = w[o*I*16 + i*16 + t];
  }
}

// ---------------- fold 4x4 weights over x4-upsample into phase 2x2 taps ----------------
// CWT idx = (((pb*2+pa)*4 + db*2+da)*I + i)*O + o
__global__ void fold_kernel(const float* __restrict__ w, float* __restrict__ CW, int O, int I){
  int total = O*I*16;
  for (int l = blockIdx.x*blockDim.x + threadIdx.x; l < total; l += gridDim.x*blockDim.x){
    int o = l % O; int q = l / O;
    int da = q & 1, db = (q>>1)&1, pa = (q>>2)&1, pb = (q>>3)&1, i = q>>4;
    float s = 0.f;
    for (int kh = 0; kh < 4; kh++){
      bool inh = (pb==0) ? (db==0 ? (kh==0) : (kh>=1)) : (db==0 ? (kh<=2) : (kh==3));
      if (!inh) continue;
      for (int kw = 0; kw < 4; kw++){
        bool inw = (pa==0) ? (da==0 ? (kw==0) : (kw>=1)) : (da==0 ? (kw<=2) : (kw==3));
        if (!inw) continue;
        s += w[((o*I + i)*4 + kh)*4 + kw];
      }
    }
    CW[(((pb*2+pa)*4 + db*2+da)*I + i)*O + o] = s;
  }
}

// ---------------- split-K GEMM with optional A-side LN+elu ----------------
__global__ __launch_bounds__(256) void gemm_splitk(
    const float* __restrict__ A, const float* __restrict__ B,
    float* __restrict__ P, int M, int N, int K, int KS,
    const float* __restrict__ Astat, float AinvN)
{
  __shared__ __align__(16) float As[16][68];
  __shared__ __align__(16) float Bs[16][64];
  int tid = threadIdx.x;
  int tx = tid & 15, ty = tid >> 4;
  int bm = blockIdx.y * 64, bn = blockIdx.x * 64;
  int ks = blockIdx.z;
  int Kc = (K + KS - 1) / KS;
  int kb = ks * Kc;
  int ke = min(K, kb + Kc);

  float aR[4], bR[4];
  int ar[4], ak[4], bk[4], bn_[4];
  #pragma unroll
  for (int idx = 0; idx < 4; idx++){
    int l = tid + idx*256;
    ar[idx] = l >> 4; ak[idx] = l & 15;
    bk[idx] = l >> 6; bn_[idx] = l & 63;
  }
  auto load_regs = [&](int k0){
    #pragma unroll
    for (int idx = 0; idx < 4; idx++){
      int gr = bm + ar[idx], gk = k0 + ak[idx];
      float v = 0.f;
      if (gr < M && gk < ke){
        v = A[(size_t)gr*K + gk];
        if (Astat){
          float sm = Astat[gr*2], sq = Astat[gr*2+1];
          float m = sm*AinvN;
          float rs = rsqrtf(sq*AinvN - m*m + 1e-5f);
          v = eluf((v-m)*rs);
        }
      }
      aR[idx] = v;
      int gk2 = k0 + bk[idx], gn = bn + bn_[idx];
      bR[idx] = (gk2 < ke && gn < N) ? B[(size_t)gk2*N + gn] : 0.f;
    }
  };
  auto write_lds = [&](){
    #pragma unroll
    for (int idx = 0; idx < 4; idx++){
      As[ak[idx]][ar[idx]] = aR[idx];
      Bs[bk[idx]][bn_[idx]] = bR[idx];
    }
  };

  float acc[4][4] = {};
  load_regs(kb);
  write_lds();
  __syncthreads();
  for (int k0 = kb; k0 < ke; k0 += 16){
    int nxt = k0 + 16;
    if (nxt < ke) load_regs(nxt);
    #pragma unroll
    for (int kk = 0; kk < 16; kk++){
      float4 a4 = *(const float4*)&As[kk][ty*4];
      float4 b4 = *(const float4*)&Bs[kk][tx*4];
      float a[4] = {a4.x,a4.y,a4.z,a4.w};
      float b[4] = {b4.x,b4.y,b4.z,b4.w};
      #pragma unroll
      for (int i = 0; i < 4; i++)
        #pragma unroll
        for (int j = 0; j < 4; j++) acc[i][j] += a[i]*b[j];
    }
    __syncthreads();
    if (nxt < ke){ write_lds(); __syncthreads(); }
  }
  float* Pout = P + (size_t)ks*M*N;
  for (int i = 0; i < 4; i++){
    int gr = bm + ty*4 + i;
    if (gr >= M) continue;
    for (int j = 0; j < 4; j++){
      int gn = bn + tx*4 + j;
      if (gn < N) Pout[(size_t)gr*N + gn] = acc[i][j];
    }
  }
}

// ---------------- fused: out = act(LN_last(sum_ks P + bias)) ----------------
__global__ __launch_bounds__(256) void reduce_ln(
    const float* __restrict__ Pp, const float* __restrict__ bias,
    float* __restrict__ out, int M, int N, int KS, int os, int act)
{
  __shared__ float rowbuf[4096];
  __shared__ float sbuf[16];
  int row = blockIdx.x;
  size_t MN = (size_t)M*N;
  float s = 0.f, s2 = 0.f;
  for (int c = threadIdx.x; c < N; c += 256){
    float v = bias[c];
    for (int ks = 0; ks < KS; ks++) v += Pp[ks*MN + (size_t)row*N + c];
    rowbuf[c] = v; s += v; s2 += v*v;
  }
  block_reduce2(s, s2, sbuf);
  float m = s / N;
  float r = rsqrtf(s2/N - m*m + 1e-5f);
  float* op = out + (size_t)row*os;
  for (int c = threadIdx.x; c < N; c += 256){
    float v = (rowbuf[c]-m)*r;
    if (act == 1) v = fmaxf(v, 0.f);
    else if (act == 2) v = eluf(v);
    else if (act == 3) v = tanhf(v);
    op[c] = v;
  }
}

// ---------------- fused NS ----------------
__global__ __launch_bounds__(256) void reduce_ns(
    const float* __restrict__ Pp, const float* __restrict__ bias,
    float* __restrict__ XR, float* __restrict__ so, int M, int N, int KS)
{
  __shared__ float rowbuf[256];
  __shared__ float sbuf[16];
  int row = blockIdx.x;
  size_t MN = (size_t)M*N;
  float s = 0.f, s2 = 0.f;
  for (int c = threadIdx.x; c < N; c += 256){
    float v = bias[c];
    for (int ks = 0; ks < KS; ks++) v += Pp[ks*MN + (size_t)row*N + c];
    rowbuf[c] = v; s += v; s2 += v*v;
  }
  block_reduce2(s, s2, sbuf);
  float m = s / N;
  float r = rsqrtf(s2/N - m*m + 1e-5f);
  for (int c = threadIdx.x; c < N; c += 256){
    float v = rowbuf[c];
    XR[(size_t)row*N+c] = sigf((v-m)*r);
    so[(size_t)row*N+c] = sigf(v);
  }
}

// ---------------- encoder conv1 (unchanged, fused ln_all+elu) ----------------
__global__ __launch_bounds__(256) void enc_conv1(
    const float* __restrict__ x, const float* __restrict__ w, const float* __restrict__ bias,
    float* __restrict__ out)
{
  __shared__ float wl[256];
  __shared__ float bs[16];
  __shared__ float sbuf[16];
  int n = blockIdx.x, tid = threadIdx.x;
  { int o = tid >> 4, c = tid & 15; wl[c*16 + o] = w[o*16 + c]; }
  if (tid < 16) bs[tid] = bias[tid];
  __syncthreads();
  const float* xin = x + (size_t)n*4096;
  float acc[64];
  float s = 0.f, s2 = 0.f;
  for (int r = 0; r < 64; r++){
    int idx = tid + (r<<8);
    int o = idx & 15, bq = (idx>>4)&31, aq = idx>>9;
    float a = 0.f;
    for (int kh = 0; kh < 4; kh++){
      int bb = 2*bq - 1 + kh;
      if ((unsigned)bb >= 64u) continue;
      for (int kw = 0; kw < 4; kw++){
        int aa = 2*aq - 1 + kw;
        if ((unsigned)aa >= 64u) continue;
        a += xin[aa*64 + bb] * wl[(kh*4+kw)*16 + o];
      }
    }
    a += bs[o];
    acc[r] = a; s += a; s2 += a*a;
  }
  block_reduce2(s, s2, sbuf);
  float m = s * (1.f/16384.f);
  float rs = rsqrtf(s2*(1.f/16384.f) - m*m + 1e-5f);
  float* op = out + (size_t)n*16384;
  for (int r = 0; r < 64; r++){
    float v = (acc[r]-m)*rs;
    op[tid + (r<<8)] = eluf(v);
  }
}

// ---------------- enc_conv2 implicit GEMM ----------------
// in E1 (n,32,32,16) final; out raw (n,16,16,32)+stats. grid 768 = n*2+bhalf, block 256
__global__ __launch_bounds__(256) void enc_conv2_ig(
    const float* __restrict__ in, const float* __restrict__ WT, const float* __restrict__ bias,
    float* __restrict__ outp, float* __restrict__ stat)
{
  __shared__ __align__(16) float in_t[9792];   // [i16][bb18][ph2][17]
  __shared__ __align__(16) float ws[512];      // [i16][o32] per tap
  __shared__ float sbuf[16];
  int bx = blockIdx.x;
  int n = bx >> 1, b0 = (bx & 1) * 8;
  int tid = threadIdx.x;
  const float* ip = in + (size_t)n*16384;
  for (int l = tid; l < 9792; l += 256){
    int i = l & 15, bb = (l >> 4) % 18, aap = l / 288;
    int aa = aap - 1;
    int bbg = 2*b0 - 1 + bb;
    float v = 0.f;
    if ((unsigned)aa < 32u && (unsigned)bbg < 32u) v = ip[aa*512 + bbg*16 + i];
    int ph = aa & 1;
    int idx = (aa + ph) >> 1;
    in_t[((i*18 + bb)*2 + ph)*17 + idx] = v;
  }
  int tx = tid & 7, bloc = (tid>>3)&7, ga = tid>>6;
  int b = b0 + bloc;
  float acc[4][4] = {};
  for (int kh = 0; kh < 4; kh++){
    int bb = 2*bloc + kh;                      // b-side pairs with kh
    for (int kw = 0; kw < 4; kw++){
      int ph = (kw & 1) ^ 1;                   // a-side pairs with kw
      int ao = (kw >= 2) ? 1 : 0;
      __syncthreads();
      { int t = kh*4 + kw;
        for (int l = tid; l < 512; l += 256) ws[l] = WT[t*512 + l]; }
      __syncthreads();
      #pragma unroll 4
      for (int i = 0; i < 16; i++){
        const float* ap = &in_t[((i*18 + bb)*2 + ph)*17 + ga*4 + ao];
        float4 w4 = *(const float4*)&ws[i*32 + tx*4];
        float av[4] = {ap[0], ap[1], ap[2], ap[3]};
        float wv[4] = {w4.x, w4.y, w4.z, w4.w};
        #pragma unroll
        for (int j = 0; j < 4; j++)
          #pragma unroll
          for (int q = 0; q < 4; q++) acc[j][q] += av[j]*wv[q];
      }
    }
  }
  float s = 0.f, s2 = 0.f;
  float bz[4];
  #pragma unroll
  for (int q = 0; q < 4; q++) bz[q] = bias[tx*4+q];
  #pragma unroll
  for (int j = 0; j < 4; j++)
    #pragma unroll
    for (int q = 0; q < 4; q++){
      float v = acc[j][q] + bz[q];
      acc[j][q] = v; s += v; s2 += v*v;
    }
  block_reduce2(s, s2, sbuf);
  if (tid == 0){ atomicAdd(&stat[n*2], s); atomicAdd(&stat[n*2+1], s2); }
  float* op = outp + (size_t)n*8192;
  #pragma unroll
  for (int j = 0; j < 4; j++){
    int a = ga*4 + j;
    float4 v4 = make_float4(acc[j][0], acc[j][1], acc[j][2], acc[j][3]);
    *(float4*)&op[a*512 + b*32 + tx*4] = v4;
  }
}

// ---------------- enc_conv3 implicit GEMM ----------------
// in E2 raw (n,16,16,32)+enc2 stats -> elu(LN) at stage; out raw (n,8,8,64)+stats.
// grid 768 = n*2+bhalf, block 128
__global__ __launch_bounds__(128) void enc_conv3_ig(
    const float* __restrict__ in, const float* __restrict__ WT, const float* __restrict__ bias,
    const float* __restrict__ stat_in, float* __restrict__ outp, float* __restrict__ stat)
{
  __shared__ __align__(16) float in_t[5760];   // [i32][bb10][ph2][9]
  __shared__ __align__(16) float ws[2048];     // [i32][o64] per tap
  __shared__ float sbuf[16];
  int bx = blockIdx.x;
  int n = bx >> 1, b0 = (bx & 1) * 4;
  int tid = threadIdx.x;
  float sm = stat_in[n*2], sq = stat_in[n*2+1];
  float m = sm*(1.f/8192.f), rs = rsqrtf(sq*(1.f/8192.f) - m*m + 1e-5f);
  const float* ip = in + (size_t)n*8192;
  for (int l = tid; l < 5760; l += 128){
    int i = l & 31, bb = (l >> 5) % 10, aap = l / 320;
    int aa = aap - 1;
    int bbg = 2*b0 - 1 + bb;
    float v = 0.f;
    if ((unsigned)aa < 16u && (unsigned)bbg < 16u) v = eluf((ip[aa*512 + bbg*32 + i]-m)*rs);
    int ph = aa & 1;
    int idx = (aa + ph) >> 1;
    in_t[((i*10 + bb)*2 + ph)*9 + idx] = v;
  }
  int tx = tid & 15, bloc = (tid>>4)&3, ga = tid>>6;
  int b = b0 + bloc;
  float acc[4][4] = {};
  for (int kh = 0; kh < 4; kh++){
    int bb = 2*bloc + kh;
    for (int kw = 0; kw < 4; kw++){
      int ph = (kw & 1) ^ 1;
      int ao = (kw >= 2) ? 1 : 0;
      __syncthreads();
      { int t = kh*4 + kw;
        for (int l = tid; l < 2048; l += 128) ws[l] = WT[t*2048 + l]; }
      __syncthreads();
      #pragma unroll 4
      for (int i = 0; i < 32; i++){
        const float* ap = &in_t[((i*10 + bb)*2 + ph)*9 + ga*4 + ao];
        float4 w4 = *(const float4*)&ws[i*64 + tx*4];
        float av[4] = {ap[0], ap[1], ap[2], ap[3]};
        float wv[4] = {w4.x, w4.y, w4.z, w4.w};
        #pragma unroll
        for (int j = 0; j < 4; j++)
          #pragma unroll
          for (int q = 0; q < 4; q++) acc[j][q] += av[j]*wv[q];
      }
    }
  }
  float s = 0.f, s2 = 0.f;
  float bz[4];
  #pragma unroll
  for (int q = 0; q < 4; q++) bz[q] = bias[tx*4+q];
  #pragma unroll
  for (int j = 0; j < 4; j++)
    #pragma unroll
    for (int q = 0; q < 4; q++){
      float v = acc[j][q] + bz[q];
      acc[j][q] = v; s += v; s2 += v*v;
    }
  block_reduce2(s, s2, sbuf);
  if (tid == 0){ atomicAdd(&stat[n*2], s); atomicAdd(&stat[n*2+1], s2); }
  float* op = outp + (size_t)n*4096;
  #pragma unroll
  for (int j = 0; j < 4; j++){
    int a = ga*4 + j;
    float4 v4 = make_float4(acc[j][0], acc[j][1], acc[j][2], acc[j][3]);
    *(float4*)&op[a*512 + b*64 + tx*4] = v4;
  }
}

// ---------------- dec_conv1 implicit GEMM ----------------
// in G2 (n,8,8,64) final; out raw (n,16,16,32)+stats. grid 768, block 256
__global__ __launch_bounds__(256) void dec_conv1_ig(
    const float* __restrict__ in, const float* __restrict__ CWT, const float* __restrict__ bias,
    float* __restrict__ outp, float* __restrict__ stat)
{
  __shared__ __align__(16) float in_t[3840];   // [i64][sb6][sa10]
  __shared__ __align__(16) float ws[8192];     // [ph4][i64][o32] per tap
  __shared__ float sbuf[16];
  int bx = blockIdx.x;
  int n = bx >> 1, b0 = (bx & 1) * 8, tb0 = b0 >> 1;
  int tid = threadIdx.x;
  const float* ip = in + (size_t)n*4096;
  for (int l = tid; l < 3840; l += 256){
    int i = l & 63, sb = (l >> 6) % 6, sap = l / 384;
    int sa = sap - 1, sbg = tb0 - 1 + sb;
    float v = 0.f;
    if ((unsigned)sa < 8u && (unsigned)sbg < 8u) v = ip[sa*512 + sbg*64 + i];
    in_t[(i*6 + sb)*10 + sap] = v;
  }
  int tx = tid & 7, bloc = (tid>>3)&7, ga = tid>>6;
  int b = b0 + bloc, pb = bloc & 1;
  float acc[4][4] = {};
  for (int tap = 0; tap < 4; tap++){
    int db = tap >> 1, da = tap & 1;
    __syncthreads();
    for (int l = tid; l < 8192; l += 256){
      int ph = l >> 11;
      ws[l] = CWT[(ph*4 + tap)*2048 + (l & 2047)];
    }
    __syncthreads();
    int sbl = (bloc>>1) + db + pb;
    int h = ga*2 + da;
    #pragma unroll 4
    for (int i = 0; i < 64; i++){
      const float* ap = &in_t[(i*6 + sbl)*10 + h];
      float4 w0 = *(const float4*)&ws[((pb*2+0)*64 + i)*32 + tx*4];
      float4 w1 = *(const float4*)&ws[((pb*2+1)*64 + i)*32 + tx*4];
      float r0 = ap[0], r1 = ap[1], r2 = ap[2];
      float w0v[4] = {w0.x,w0.y,w0.z,w0.w};
      float w1v[4] = {w1.x,w1.y,w1.z,w1.w};
      #pragma unroll
      for (int q = 0; q < 4; q++){
        acc[0][q] += r0*w0v[q];
        acc[1][q] += r1*w1v[q];
        acc[2][q] += r1*w0v[q];
        acc[3][q] += r2*w1v[q];
      }
    }
  }
  float s = 0.f, s2 = 0.f;
  float bz[4];
  #pragma unroll
  for (int q = 0; q < 4; q++) bz[q] = bias[tx*4+q];
  #pragma unroll
  for (int j = 0; j < 4; j++)
    #pragma unroll
    for (int q = 0; q < 4; q++){
      float v = acc[j][q] + bz[q];
      acc[j][q] = v; s += v; s2 += v*v;
    }
  block_reduce2(s, s2, sbuf);
  if (tid == 0){ atomicAdd(&stat[n*2], s); atomicAdd(&stat[n*2+1], s2); }
  float* op = outp + (size_t)n*8192;
  #pragma unroll
  for (int j = 0; j < 4; j++){
    int a = ga*4 + j;
    float4 v4 = make_float4(acc[j][0], acc[j][1], acc[j][2], acc[j][3]);
    *(float4*)&op[a*512 + b*32 + tx*4] = v4;
  }
}

// ---------------- dec_conv2 implicit GEMM ----------------
// in D1 raw (n,16,16,32)+dec1 stats -> relu(LN); out raw (n,32,32,16)+stats. grid 1536, block 256
__global__ __launch_bounds__(256) void dec_conv2_ig(
    const float* __restrict__ in, const float* __restrict__ CWT, const float* __restrict__ bias,
    const float* __restrict__ stat_in, float* __restrict__ outp, float* __restrict__ stat)
{
  __shared__ __align__(16) float in_t[3456];   // [i32][sb6][sa18]
  __shared__ __align__(16) float ws[2048];     // [ph4][i32][o16] per tap
  __shared__ float sbuf[16];
  int bx = blockIdx.x;
  int n = bx >> 2, b0 = (bx & 3) * 8, tb0 = b0 >> 1;
  int tid = threadIdx.x;
  float sm = stat_in[n*2], sq = stat_in[n*2+1];
  float m = sm*(1.f/8192.f), rs = rsqrtf(sq*(1.f/8192.f) - m*m + 1e-5f);
  const float* ip = in + (size_t)n*8192;
  for (int l = tid; l < 3456; l += 256){
    int i = l & 31, sb = (l >> 5) % 6, sap = l / 192;
    int sa = sap - 1, sbg = tb0 - 1 + sb;
    float v = 0.f;
    if ((unsigned)sa < 16u && (unsigned)sbg < 16u)
      v = fmaxf((ip[sa*512 + sbg*32 + i]-m)*rs, 0.f);
    in_t[(i*6 + sb)*18 + sap] = v;
  }
  int tx = tid & 3, bloc = (tid>>2)&7, ga = tid>>5;
  int b = b0 + bloc, pb = bloc & 1;
  float acc[4][4] = {};
  for (int tap = 0; tap < 4; tap++){
    int db = tap >> 1, da = tap & 1;
    __syncthreads();
    for (int l = tid; l < 2048; l += 256){
      int ph = l >> 9;
      ws[l] = CWT[(ph*4 + tap)*512 + (l & 511)];
    }
    __syncthreads();
    int sbl = (bloc>>1) + db + pb;
    int h = ga*2 + da;
    #pragma unroll 4
    for (int i = 0; i < 32; i++){
      const float* ap = &in_t[(i*6 + sbl)*18 + h];
      float4 w0 = *(const float4*)&ws[(pb*2+0)*512 + i*16 + tx*4];
      float4 w1 = *(const float4*)&ws[(pb*2+1)*512 + i*16 + tx*4];
      float r0 = ap[0], r1 = ap[1], r2 = ap[2];
      float w0v[4] = {w0.x,w0.y,w0.z,w0.w};
      float w1v[4] = {w1.x,w1.y,w1.z,w1.w};
      #pragma unroll
      for (int q = 0; q < 4; q++){
        acc[0][q] += r0*w0v[q];
        acc[1][q] += r1*w1v[q];
        acc[2][q] += r1*w0v[q];
        acc[3][q] += r2*w1v[q];
      }
    }
  }
  float s = 0.f, s2 = 0.f;
  float bz[4];
  #pragma unroll
  for (int q = 0; q < 4; q++) bz[q] = bias[tx*4+q];
  #pragma unroll
  for (int j = 0; j < 4; j++)
    #pragma unroll
    for (int q = 0; q < 4; q++){
      float v = acc[j][q] + bz[q];
      acc[j][q] = v; s += v; s2 += v*v;
    }
  block_reduce2(s, s2, sbuf);
  if (tid == 0){ atomicAdd(&stat[n*2], s); atomicAdd(&stat[n*2+1], s2); }
  float* op = outp + (size_t)n*16384;
  #pragma unroll
  for (int j = 0; j < 4; j++){
    int a = ga*4 + j;
    float4 v4 = make_float4(acc[j][0], acc[j][1], acc[j][2], acc[j][3]);
    *(float4*)&op[a*512 + b*16 + tx*4] = v4;
  }
}

// ---------------- dec_conv3: (n,32,32,16)+dec2 stats -> relu(LN) -> conv -> sigmoid ----------------
// grid 768, block 256
__global__ __launch_bounds__(256) void dec_conv3_ig(
    const float* __restrict__ in, const float* __restrict__ CWT, const float* __restrict__ bias,
    const float* __restrict__ stat_in, float* __restrict__ outp)
{
  __shared__ __align__(16) float in_t[9792];   // [sa34][sb18][i16]
  __shared__ __align__(16) float wl[256];
  int bx = blockIdx.x;
  int n = bx >> 1, b0 = (bx & 1) * 32, tb0 = b0 >> 1;
  int tid = threadIdx.x;
  float sm = stat_in[n*2], sq = stat_in[n*2+1];
  float m = sm*(1.f/16384.f), rs = rsqrtf(sq*(1.f/16384.f) - m*m + 1e-5f);
  const float* ip = in + (size_t)n*16384;
  for (int l = tid; l < 9792; l += 256){
    int i = l & 15, sb = (l >> 4) % 18, sap = l / 288;
    int sa = sap - 1, sbg = tb0 - 1 + sb;
    float v = 0.f;
    if ((unsigned)sa < 32u && (unsigned)sbg < 32u)
      v = fmaxf((ip[sa*512 + sbg*16 + i]-m)*rs, 0.f);
    in_t[(sap*18 + sb)*16 + i] = v;
  }
  if (tid < 256 && tid < 256) { if (tid < 256) {} }
  for (int l = tid; l < 256; l += 256) wl[l] = CWT[l];
  __syncthreads();
  float bv = bias[0];
  int bl = tid & 31, ath = tid >> 5;
  int b = b0 + bl;
  int tb = b >> 1, pb = b & 1;
  float* op = outp + (size_t)n*4096;
  #pragma unroll
  for (int j = 0; j < 8; j++){
    int a = ath*8 + j;
    int ta = a >> 1, pa = a & 1;
    float4 s4 = make_float4(0.f,0.f,0.f,0.f);
    #pragma unroll
    for (int db = 0; db < 2; db++){
      int sb = tb + db + (pb ? 0 : -1);
      int sbl = sb - (tb0 - 1);
      #pragma unroll
      for (int da = 0; da < 2; da++){
        int sa = ta + da + (pa ? 0 : -1);
        int sap = sa + 1;
        const float4* A4 = (const float4*)&in_t[(sap*18 + sbl)*16];
        const float4* B4 = (const float4*)&wl[((pb*2+pa)*4 + db*2+da)*16];
        #pragma unroll
        for (int q = 0; q < 4; q++){
          float4 av = A4[q], bw = B4[q];
          s4.x += av.x*bw.x; s4.y += av.y*bw.y;
          s4.z += av.z*bw.z; s4.w += av.w*bw.w;
        }
      }
    }
    op[a*64 + b] = sigf(bv + s4.x + s4.y + s4.z + s4.w);
  }
}

// ---------------- pair build ----------------
__global__ __launch_bounds__(256) void pair_build(const float* __restrict__ tot, float* __restrict__ P)
{
  int r = blockIdx.x;
  int jj = r % 7, fi = r / 7;
  int i = fi & 7, j = fi >> 3;
  int jidx = jj < i ? jj : jj+1;
  const float* srcf = tot + (size_t)fi*1012;
  const float* srco = tot + (size_t)(j*8+jidx)*1012;
  float* op = P + (size_t)r*500;
  for (int c = threadIdx.x; c < 250; c += blockDim.x){
    op[c] = srcf[c];
    op[250+c] = srco[c];
  }
}

// ---------------- att2 ----------------
__global__ void att2_kernel(const float* __restrict__ A1, const float* __restrict__ w,
                            const float* __restrict__ b, float* __restrict__ att)
{
  int r = blockIdx.x*blockDim.x + threadIdx.x;
  if (r >= 2688) return;
  const float* ip = A1 + (size_t)r*100;
  float a = b[0];
  for (int c = 0; c < 100; c++) a += ip[c]*w[c];
  att[r] = sigf(a);
}

// ---------------- effect ----------------
__global__ __launch_bounds__(256) void effect_kernel(const float* __restrict__ X1,
    const float* __restrict__ att, float* __restrict__ tot)
{
  int row = blockIdx.x;
  for (int h = threadIdx.x; h < 250; h += blockDim.x){
    float s = 0.f;
    for (int jj = 0; jj < 7; jj++)
      s += X1[((size_t)row*7+jj)*250 + h] * att[row*7+jj];
    tot[(size_t)row*1012 + 250 + h] = s;
  }
}

extern "C" void kernel_launch(void* const* d_in, const int* in_sizes, int n_in,
                              void* d_out, int out_size, void* d_ws, size_t ws_size,
                              hipStream_t stream) {
  const float* x      = (const float*)d_in[0];
  const float* state  = (const float*)d_in[1];
  const float* c1w    = (const float*)d_in[2];
  const float* c1b    = (const float*)d_in[3];
  const float* c2w    = (const float*)d_in[4];
  const float* c2b    = (const float*)d_in[5];
  const float* c3w    = (const float*)d_in[6];
  const float* c3b    = (const float*)d_in[7];
  const float* efc_w  = (const float*)d_in[8];
  const float* efc_b  = (const float*)d_in[9];
  const float* renc_w = (const float*)d_in[10];
  const float* renc_b = (const float*)d_in[11];
  const float* core_w = (const float*)d_in[12];
  const float* core_b = (const float*)d_in[13];
  const float* ctx_w  = (const float*)d_in[14];
  const float* ctx_b  = (const float*)d_in[15];
  const float* att1_w = (const float*)d_in[16];
  const float* att1_b = (const float*)d_in[17];
  const float* att2_w = (const float*)d_in[18];
  const float* att2_b = (const float*)d_in[19];
  const float* out_w  = (const float*)d_in[20];
  const float* out_b  = (const float*)d_in[21];
  const float* dfc1_w = (const float*)d_in[22];
  const float* dfc1_b = (const float*)d_in[23];
  const float* dfc2_w = (const float*)d_in[24];
  const float* dfc2_b = (const float*)d_in[25];
  const float* d1w    = (const float*)d_in[26];
  const float* d1b    = (const float*)d_in[27];
  const float* d2w    = (const float*)d_in[28];
  const float* d2b    = (const float*)d_in[29];
  const float* d3w    = (const float*)d_in[30];
  const float* d3b    = (const float*)d_in[31];

  float* wsf = (float*)d_ws;
  size_t o = 0;
  float* E1  = wsf + o; o += (size_t)384*16384;   // enc1 out; later PB, dec2 raw out
  float* E2  = wsf + o; o += (size_t)384*8192;    // enc2 raw; later dec1 raw
  float* E3  = wsf + o; o += (size_t)384*4096;    // enc3 raw; later G2
  float* TOT = wsf + o; o += (size_t)384*1012;
  float* Pr  = wsf + o; o += (size_t)2688*500;
  float* C1  = wsf + o; o += (size_t)2688*250;
  float* X1  = wsf + o; o += (size_t)2688*250;
  float* A1  = wsf + o; o += (size_t)2688*100;
  float* ATT = wsf + o; o += 2688;
  float* XR  = wsf + o; o += (size_t)384*250;
  float* G1  = wsf + o; o += (size_t)384*512;
  float* CWT1 = wsf + o; o += 32768;
  float* CWT2 = wsf + o; o += 8192;
  float* CWT3 = wsf + o; o += 256;
  float* WT2  = wsf + o; o += 8192;
  float* WT3  = wsf + o; o += 32768;
  float* STAT = wsf + o; o += 4*384*2;
  float* PB  = E1;
  float* D1O = E2;
  float* D2O = E1;
  float* G2  = E3;

  float* xout = (float*)d_out;
  float* sout = xout + (size_t)384*4096;

  // prep (independent)
  zero_stats<<<12, 256, 0, stream>>>(STAT);
  fold_kernel<<<128, 256, 0, stream>>>(d1w, CWT1, 32, 64);
  fold_kernel<<<32, 256, 0, stream>>>(d2w, CWT2, 16, 32);
  fold_kernel<<<1, 256, 0, stream>>>(d3w, CWT3, 1, 16);
  transpose_w<<<32, 256, 0, stream>>>(c2w, WT2, 32, 16);
  transpose_w<<<128, 256, 0, stream>>>(c3w, WT3, 64, 32);

  // encoder
  enc_conv1<<<384, 256, 0, stream>>>(x, c1w, c1b, E1);
  enc_conv2_ig<<<768, 256, 0, stream>>>(E1, WT2, c2b, E2, STAT + ST_ENC2*768);
  enc_conv3_ig<<<768, 128, 0, stream>>>(E2, WT3, c3b, STAT + ST_ENC2*768, E3, STAT + ST_ENC3*768);
  gemm_splitk<<<dim3(8,6,8), 256, 0, stream>>>(E3, efc_w, PB, 384, 512, 4096, 8,
                                               STAT + ST_ENC3*768, 1.f/4096.f);
  reduce_ln<<<384, 256, 0, stream>>>(PB, efc_b, TOT+500, 384, 512, 8, 1012, 2);

  // state path
  gemm_splitk<<<dim3(4,6,8), 256, 0, stream>>>(state, renc_w, PB, 384, 250, 250, 8, nullptr, 0.f);
  reduce_ln<<<384, 256, 0, stream>>>(PB, renc_b, TOT, 384, 250, 8, 1012, 1);
  pair_build<<<2688, 256, 0, stream>>>(TOT, Pr);
  gemm_splitk<<<dim3(4,42,2), 256, 0, stream>>>(Pr, core_w, PB, 2688, 250, 500, 2, nullptr, 0.f);
  reduce_ln<<<2688, 256, 0, stream>>>(PB, core_b, C1, 2688, 250, 2, 250, 1);
  gemm_splitk<<<dim3(4,42,2), 256, 0, stream>>>(C1, ctx_w, PB, 2688, 250, 250, 2, nullptr, 0.f);
  reduce_ln<<<2688, 256, 0, stream>>>(PB, ctx_b, X1, 2688, 250, 2, 250, 1);
  gemm_splitk<<<dim3(2,42,4), 256, 0, stream>>>(C1, att1_w, PB, 2688, 100, 250, 4, nullptr, 0.f);
  reduce_ln<<<2688, 256, 0, stream>>>(PB, att1_b, A1, 2688, 100, 4, 100, 3);
  att2_kernel<<<11, 256, 0, stream>>>(A1, att2_w, att2_b, ATT);
  effect_kernel<<<384, 256, 0, stream>>>(X1, ATT, TOT);

  // combine
  gemm_splitk<<<dim3(4,6,8), 256, 0, stream>>>(TOT, out_w, PB, 384, 250, 1012, 8, nullptr, 0.f);
  reduce_ns<<<384, 256, 0, stream>>>(PB, out_b, XR, sout, 384, 250, 8);

  // decoder FC
  gemm_splitk<<<dim3(8,6,4), 256, 0, stream>>>(XR, dfc1_w, PB, 384, 512, 250, 4, nullptr, 0.f);
  reduce_ln<<<384, 256, 0, stream>>>(PB, dfc1_b, G1, 384, 512, 4, 512, 1);
  gemm_splitk<<<dim3(64,6,1), 256, 0, stream>>>(G1, dfc2_w, PB, 384, 4096, 512, 1, nullptr, 0.f);
  reduce_ln<<<384, 256, 0, stream>>>(PB, dfc2_b, G2, 384, 4096, 1, 4096, 1);

  // decoder convs
  dec_conv1_ig<<<768, 256, 0, stream>>>(G2, CWT1, d1b, D1O, STAT + ST_DEC1*768);
  dec_conv2_ig<<<1536, 256, 0, stream>>>(D1O, CWT2, d2b, STAT + ST_DEC1*768, D2O, STAT + ST_DEC2*768);
  dec_conv3_ig<<<768, 256, 0, stream>>>(D2O, CWT3, d3b, STAT + ST_DEC2*768, xout);

  (void)in_sizes; (void)n_in; (void)out_size; (void)ws_size;
}

// Round 5
// 643.420 us; speedup vs baseline: 3.4311x; 1.2286x over previous
//
#include <hip/hip_runtime.h>
#include <hip/hip_bf16.h>
#include <math.h>

// stats slots (sum,sumsq per sample), 384 samples each
#define ST_ENC2 0
#define ST_ENC3 1
#define ST_DEC1 2
#define ST_DEC2 3
#define ST_ENC1 4

__device__ __forceinline__ float eluf(float v){ return v > 0.f ? v : expm1f(v); }
__device__ __forceinline__ float sigf(float v){ return 1.f/(1.f+expf(-v)); }

// ---------------- block-wide sum & sumsq reduction ----------------
__device__ __forceinline__ void block_reduce2(float& a, float& b, float* sbuf){
  __syncthreads();
  for (int off = 32; off; off >>= 1){
    a += __shfl_down(a, off);
    b += __shfl_down(b, off);
  }
  int lane = threadIdx.x & 63, w = threadIdx.x >> 6;
  if (lane == 0){ sbuf[2*w] = a; sbuf[2*w+1] = b; }
  __syncthreads();
  if (threadIdx.x == 0){
    int nw = blockDim.x >> 6;
    float sa = 0.f, sb = 0.f;
    for (int i = 0; i < nw; i++){ sa += sbuf[2*i]; sb += sbuf[2*i+1]; }
    sbuf[0] = sa; sbuf[1] = sb;
  }
  __syncthreads();
  a = sbuf[0]; b = sbuf[1];
}

// ---------------- zero stats ----------------
__global__ void zero_stats(float* __restrict__ st){
  int i = blockIdx.x*blockDim.x + threadIdx.x;
  if (i < 5*384*2) st[i] = 0.f;
}

// ---------------- weight transpose: WT[(t*I+i)*O+o] = w[o][i][t] ----------------
__global__ void transpose_w(const float* __restrict__ w, float* __restrict__ WT, int O, int I){
  int total = O*I*16;
  for (int l = blockIdx.x*blockDim.x + threadIdx.x; l < total; l += gridDim.x*blockDim.x){
    int o = l % O; int q = l / O; int i = q % I; int t = q / I;
    WT[(t*I + i)*O + o] = w[o*I*16 + i*16 + t];
  }
}

// ---------------- fold 4x4 weights over x4-upsample into phase 2x2 taps ----------------
__global__ void fold_kernel(const float* __restrict__ w, float* __restrict__ CW, int O, int I){
  int total = O*I*16;
  for (int l = blockIdx.x*blockDim.x + threadIdx.x; l < total; l += gridDim.x*blockDim.x){
    int o = l % O; int q = l / O;
    int da = q & 1, db = (q>>1)&1, pa = (q>>2)&1, pb = (q>>3)&1, i = q>>4;
    float s = 0.f;
    for (int kh = 0; kh < 4; kh++){
      bool inh = (pb==0) ? (db==0 ? (kh==0) : (kh>=1)) : (db==0 ? (kh<=2) : (kh==3));
      if (!inh) continue;
      for (int kw = 0; kw < 4; kw++){
        bool inw = (pa==0) ? (da==0 ? (kw==0) : (kw>=1)) : (da==0 ? (kw<=2) : (kw==3));
        if (!inw) continue;
        s += w[((o*I + i)*4 + kh)*4 + kw];
      }
    }
    CW[(((pb*2+pa)*4 + db*2+da)*I + i)*O + o] = s;
  }
}

// ---------------- split-K GEMM with optional A-side LN+elu ----------------
__global__ __launch_bounds__(256) void gemm_splitk(
    const float* __restrict__ A, const float* __restrict__ B,
    float* __restrict__ P, int M, int N, int K, int KS,
    const float* __restrict__ Astat, float AinvN)
{
  __shared__ __align__(16) float As[16][68];
  __shared__ __align__(16) float Bs[16][64];
  int tid = threadIdx.x;
  int tx = tid & 15, ty = tid >> 4;
  int bm = blockIdx.y * 64, bn = blockIdx.x * 64;
  int ks = blockIdx.z;
  int Kc = (K + KS - 1) / KS;
  int kb = ks * Kc;
  int ke = min(K, kb + Kc);

  float aR[4], bR[4];
  int ar[4], ak[4], bk[4], bn_[4];
  #pragma unroll
  for (int idx = 0; idx < 4; idx++){
    int l = tid + idx*256;
    ar[idx] = l >> 4; ak[idx] = l & 15;
    bk[idx] = l >> 6; bn_[idx] = l & 63;
  }
  auto load_regs = [&](int k0){
    #pragma unroll
    for (int idx = 0; idx < 4; idx++){
      int gr = bm + ar[idx], gk = k0 + ak[idx];
      float v = 0.f;
      if (gr < M && gk < ke){
        v = A[(size_t)gr*K + gk];
        if (Astat){
          float sm = Astat[gr*2], sq = Astat[gr*2+1];
          float m = sm*AinvN;
          float rs = rsqrtf(sq*AinvN - m*m + 1e-5f);
          v = eluf((v-m)*rs);
        }
      }
      aR[idx] = v;
      int gk2 = k0 + bk[idx], gn = bn + bn_[idx];
      bR[idx] = (gk2 < ke && gn < N) ? B[(size_t)gk2*N + gn] : 0.f;
    }
  };
  auto write_lds = [&](){
    #pragma unroll
    for (int idx = 0; idx < 4; idx++){
      As[ak[idx]][ar[idx]] = aR[idx];
      Bs[bk[idx]][bn_[idx]] = bR[idx];
    }
  };

  float acc[4][4] = {};
  load_regs(kb);
  write_lds();
  __syncthreads();
  for (int k0 = kb; k0 < ke; k0 += 16){
    int nxt = k0 + 16;
    if (nxt < ke) load_regs(nxt);
    #pragma unroll
    for (int kk = 0; kk < 16; kk++){
      float4 a4 = *(const float4*)&As[kk][ty*4];
      float4 b4 = *(const float4*)&Bs[kk][tx*4];
      float a[4] = {a4.x,a4.y,a4.z,a4.w};
      float b[4] = {b4.x,b4.y,b4.z,b4.w};
      #pragma unroll
      for (int i = 0; i < 4; i++)
        #pragma unroll
        for (int j = 0; j < 4; j++) acc[i][j] += a[i]*b[j];
    }
    __syncthreads();
    if (nxt < ke){ write_lds(); __syncthreads(); }
  }
  float* Pout = P + (size_t)ks*M*N;
  for (int i = 0; i < 4; i++){
    int gr = bm + ty*4 + i;
    if (gr >= M) continue;
    for (int j = 0; j < 4; j++){
      int gn = bn + tx*4 + j;
      if (gn < N) Pout[(size_t)gr*N + gn] = acc[i][j];
    }
  }
}

// ---------------- fused: out = act(LN_last(sum_ks P + bias)) ----------------
__global__ __launch_bounds__(256) void reduce_ln(
    const float* __restrict__ Pp, const float* __restrict__ bias,
    float* __restrict__ out, int M, int N, int KS, int os, int act)
{
  __shared__ float rowbuf[4096];
  __shared__ float sbuf[16];
  int row = blockIdx.x;
  size_t MN = (size_t)M*N;
  float s = 0.f, s2 = 0.f;
  for (int c = threadIdx.x; c < N; c += 256){
    float v = bias[c];
    for (int ks = 0; ks < KS; ks++) v += Pp[ks*MN + (size_t)row*N + c];
    rowbuf[c] = v; s += v; s2 += v*v;
  }
  block_reduce2(s, s2, sbuf);
  float m = s / N;
  float r = rsqrtf(s2/N - m*m + 1e-5f);
  float* op = out + (size_t)row*os;
  for (int c = threadIdx.x; c < N; c += 256){
    float v = (rowbuf[c]-m)*r;
    if (act == 1) v = fmaxf(v, 0.f);
    else if (act == 2) v = eluf(v);
    else if (act == 3) v = tanhf(v);
    op[c] = v;
  }
}

// ---------------- fused NS ----------------
__global__ __launch_bounds__(256) void reduce_ns(
    const float* __restrict__ Pp, const float* __restrict__ bias,
    float* __restrict__ XR, float* __restrict__ so, int M, int N, int KS)
{
  __shared__ float rowbuf[256];
  __shared__ float sbuf[16];
  int row = blockIdx.x;
  size_t MN = (size_t)M*N;
  float s = 0.f, s2 = 0.f;
  for (int c = threadIdx.x; c < N; c += 256){
    float v = bias[c];
    for (int ks = 0; ks < KS; ks++) v += Pp[ks*MN + (size_t)row*N + c];
    rowbuf[c] = v; s += v; s2 += v*v;
  }
  block_reduce2(s, s2, sbuf);
  float m = s / N;
  float r = rsqrtf(s2/N - m*m + 1e-5f);
  for (int c = threadIdx.x; c < N; c += 256){
    float v = rowbuf[c];
    XR[(size_t)row*N+c] = sigf((v-m)*r);
    so[(size_t)row*N+c] = sigf(v);
  }
}

// ---------------- enc_conv1: x(n,64,64) -> raw (n,32,32,16) + stats ----------------
// LDS-staged padded input, weights in registers, no acc array (no spill). grid 384.
__global__ __launch_bounds__(256) void enc_conv1_ig(
    const float* __restrict__ x, const float* __restrict__ w, const float* __restrict__ bias,
    float* __restrict__ outp, float* __restrict__ stat)
{
  __shared__ __align__(16) float in_t[66*68];   // [aa+1][bb+1], row stride 68 (16B-aligned)
  __shared__ float sbuf[16];
  int n = blockIdx.x, tid = threadIdx.x;
  for (int l = tid; l < 66*68; l += 256) in_t[l] = 0.f;
  __syncthreads();
  const float* xin = x + (size_t)n*4096;
  for (int l4 = tid; l4 < 1024; l4 += 256){
    float4 v = *(const float4*)&xin[l4*4];
    int aa = (l4*4) >> 6, bb = (l4*4) & 63;
    float* dst = &in_t[(aa+1)*68 + bb + 1];
    dst[0]=v.x; dst[1]=v.y; dst[2]=v.z; dst[3]=v.w;
  }
  int o = tid & 15;
  float wr[16];
  #pragma unroll
  for (int t = 0; t < 16; t++) wr[t] = w[o*16 + t];   // w[o][kh*4+kw]
  float bv = bias[o];
  __syncthreads();
  float s = 0.f, s2 = 0.f;
  float* op = outp + (size_t)n*16384;
  for (int r = 0; r < 64; r++){
    int idx = tid + (r<<8);
    int bq = (idx>>4)&31, aq = idx>>9;
    int a0 = 2*aq, b0 = 2*bq;     // padded coords: aa+1 = a0+kw, bb+1 = b0+kh
    float acc = bv;
    #pragma unroll
    for (int kw = 0; kw < 4; kw++){
      const float* row = &in_t[(a0+kw)*68 + b0];
      float2 p0 = *(const float2*)&row[0];
      float2 p1 = *(const float2*)&row[2];
      acc += p0.x*wr[0*4+kw] + p0.y*wr[1*4+kw] + p1.x*wr[2*4+kw] + p1.y*wr[3*4+kw];
    }
    op[idx] = acc;
    s += acc; s2 += acc*acc;
  }
  block_reduce2(s, s2, sbuf);
  if (tid == 0){ atomicAdd(&stat[n*2], s); atomicAdd(&stat[n*2+1], s2); }
}

// ---------------- enc_conv2 implicit GEMM ----------------
// in E1 raw (n,32,32,16)+enc1 stats -> elu(LN) at stage; out raw (n,16,16,32)+stats.
__global__ __launch_bounds__(256) void enc_conv2_ig(
    const float* __restrict__ in, const float* __restrict__ WT, const float* __restrict__ bias,
    const float* __restrict__ stat_in, float* __restrict__ outp, float* __restrict__ stat)
{
  __shared__ __align__(16) float in_t[9792];   // [i16][bb18][ph2][17]
  __shared__ __align__(16) float ws[512];      // [i16][o32] per tap
  __shared__ float sbuf[16];
  int bx = blockIdx.x;
  int n = bx >> 1, b0 = (bx & 1) * 8;
  int tid = threadIdx.x;
  float smv = stat_in[n*2], sqv = stat_in[n*2+1];
  float mI = smv*(1.f/16384.f), rsI = rsqrtf(sqv*(1.f/16384.f) - mI*mI + 1e-5f);
  const float* ip = in + (size_t)n*16384;
  for (int l = tid; l < 9792; l += 256){
    int i = l & 15, bb = (l >> 4) % 18, aap = l / 288;
    int aa = aap - 1;
    int bbg = 2*b0 - 1 + bb;
    float v = 0.f;
    if ((unsigned)aa < 32u && (unsigned)bbg < 32u)
      v = eluf((ip[aa*512 + bbg*16 + i]-mI)*rsI);
    int ph = aa & 1;
    int idx = (aa + ph) >> 1;
    in_t[((i*18 + bb)*2 + ph)*17 + idx] = v;
  }
  int tx = tid & 7, bloc = (tid>>3)&7, ga = tid>>6;
  int b = b0 + bloc;
  float acc[4][4] = {};
  for (int kh = 0; kh < 4; kh++){
    int bb = 2*bloc + kh;
    for (int kw = 0; kw < 4; kw++){
      int ph = (kw & 1) ^ 1;
      int ao = (kw >= 2) ? 1 : 0;
      __syncthreads();
      { int t = kh*4 + kw;
        for (int l = tid; l < 512; l += 256) ws[l] = WT[t*512 + l]; }
      __syncthreads();
      #pragma unroll 4
      for (int i = 0; i < 16; i++){
        const float* ap = &in_t[((i*18 + bb)*2 + ph)*17 + ga*4 + ao];
        float4 w4 = *(const float4*)&ws[i*32 + tx*4];
        float av[4] = {ap[0], ap[1], ap[2], ap[3]};
        float wv[4] = {w4.x, w4.y, w4.z, w4.w};
        #pragma unroll
        for (int j = 0; j < 4; j++)
          #pragma unroll
          for (int q = 0; q < 4; q++) acc[j][q] += av[j]*wv[q];
      }
    }
  }
  float s = 0.f, s2 = 0.f;
  float bz[4];
  #pragma unroll
  for (int q = 0; q < 4; q++) bz[q] = bias[tx*4+q];
  #pragma unroll
  for (int j = 0; j < 4; j++)
    #pragma unroll
    for (int q = 0; q < 4; q++){
      float v = acc[j][q] + bz[q];
      acc[j][q] = v; s += v; s2 += v*v;
    }
  block_reduce2(s, s2, sbuf);
  if (tid == 0){ atomicAdd(&stat[n*2], s); atomicAdd(&stat[n*2+1], s2); }
  float* op = outp + (size_t)n*8192;
  #pragma unroll
  for (int j = 0; j < 4; j++){
    int a = ga*4 + j;
    float4 v4 = make_float4(acc[j][0], acc[j][1], acc[j][2], acc[j][3]);
    *(float4*)&op[a*512 + b*32 + tx*4] = v4;
  }
}

// ---------------- enc_conv3 implicit GEMM ----------------
__global__ __launch_bounds__(128) void enc_conv3_ig(
    const float* __restrict__ in, const float* __restrict__ WT, const float* __restrict__ bias,
    const float* __restrict__ stat_in, float* __restrict__ outp, float* __restrict__ stat)
{
  __shared__ __align__(16) float in_t[5760];   // [i32][bb10][ph2][9]
  __shared__ __align__(16) float ws[2048];     // [i32][o64] per tap
  __shared__ float sbuf[16];
  int bx = blockIdx.x;
  int n = bx >> 1, b0 = (bx & 1) * 4;
  int tid = threadIdx.x;
  float sm = stat_in[n*2], sq = stat_in[n*2+1];
  float m = sm*(1.f/8192.f), rs = rsqrtf(sq*(1.f/8192.f) - m*m + 1e-5f);
  const float* ip = in + (size_t)n*8192;
  for (int l = tid; l < 5760; l += 128){
    int i = l & 31, bb = (l >> 5) % 10, aap = l / 320;
    int aa = aap - 1;
    int bbg = 2*b0 - 1 + bb;
    float v = 0.f;
    if ((unsigned)aa < 16u && (unsigned)bbg < 16u) v = eluf((ip[aa*512 + bbg*32 + i]-m)*rs);
    int ph = aa & 1;
    int idx = (aa + ph) >> 1;
    in_t[((i*10 + bb)*2 + ph)*9 + idx] = v;
  }
  int tx = tid & 15, bloc = (tid>>4)&3, ga = tid>>6;
  int b = b0 + bloc;
  float acc[4][4] = {};
  for (int kh = 0; kh < 4; kh++){
    int bb = 2*bloc + kh;
    for (int kw = 0; kw < 4; kw++){
      int ph = (kw & 1) ^ 1;
      int ao = (kw >= 2) ? 1 : 0;
      __syncthreads();
      { int t = kh*4 + kw;
        for (int l = tid; l < 2048; l += 128) ws[l] = WT[t*2048 + l]; }
      __syncthreads();
      #pragma unroll 4
      for (int i = 0; i < 32; i++){
        const float* ap = &in_t[((i*10 + bb)*2 + ph)*9 + ga*4 + ao];
        float4 w4 = *(const float4*)&ws[i*64 + tx*4];
        float av[4] = {ap[0], ap[1], ap[2], ap[3]};
        float wv[4] = {w4.x, w4.y, w4.z, w4.w};
        #pragma unroll
        for (int j = 0; j < 4; j++)
          #pragma unroll
          for (int q = 0; q < 4; q++) acc[j][q] += av[j]*wv[q];
      }
    }
  }
  float s = 0.f, s2 = 0.f;
  float bz[4];
  #pragma unroll
  for (int q = 0; q < 4; q++) bz[q] = bias[tx*4+q];
  #pragma unroll
  for (int j = 0; j < 4; j++)
    #pragma unroll
    for (int q = 0; q < 4; q++){
      float v = acc[j][q] + bz[q];
      acc[j][q] = v; s += v; s2 += v*v;
    }
  block_reduce2(s, s2, sbuf);
  if (tid == 0){ atomicAdd(&stat[n*2], s); atomicAdd(&stat[n*2+1], s2); }
  float* op = outp + (size_t)n*4096;
  #pragma unroll
  for (int j = 0; j < 4; j++){
    int a = ga*4 + j;
    float4 v4 = make_float4(acc[j][0], acc[j][1], acc[j][2], acc[j][3]);
    *(float4*)&op[a*512 + b*64 + tx*4] = v4;
  }
}

// ---------------- dec_conv1 implicit GEMM ----------------
__global__ __launch_bounds__(256) void dec_conv1_ig(
    const float* __restrict__ in, const float* __restrict__ CWT, const float* __restrict__ bias,
    float* __restrict__ outp, float* __restrict__ stat)
{
  __shared__ __align__(16) float in_t[3840];   // [i64][sb6][sa10]
  __shared__ __align__(16) float ws[8192];     // [ph4][i64][o32] per tap
  __shared__ float sbuf[16];
  int bx = blockIdx.x;
  int n = bx >> 1, b0 = (bx & 1) * 8, tb0 = b0 >> 1;
  int tid = threadIdx.x;
  const float* ip = in + (size_t)n*4096;
  for (int l = tid; l < 3840; l += 256){
    int i = l & 63, sb = (l >> 6) % 6, sap = l / 384;
    int sa = sap - 1, sbg = tb0 - 1 + sb;
    float v = 0.f;
    if ((unsigned)sa < 8u && (unsigned)sbg < 8u) v = ip[sa*512 + sbg*64 + i];
    in_t[(i*6 + sb)*10 + sap] = v;
  }
  int tx = tid & 7, bloc = (tid>>3)&7, ga = tid>>6;
  int b = b0 + bloc, pb = bloc & 1;
  float acc[4][4] = {};
  for (int tap = 0; tap < 4; tap++){
    int db = tap >> 1, da = tap & 1;
    __syncthreads();
    for (int l = tid; l < 8192; l += 256){
      int ph = l >> 11;
      ws[l] = CWT[(ph*4 + tap)*2048 + (l & 2047)];
    }
    __syncthreads();
    int sbl = (bloc>>1) + db + pb;
    int h = ga*2 + da;
    #pragma unroll 4
    for (int i = 0; i < 64; i++){
      const float* ap = &in_t[(i*6 + sbl)*10 + h];
      float4 w0 = *(const float4*)&ws[((pb*2+0)*64 + i)*32 + tx*4];
      float4 w1 = *(const float4*)&ws[((pb*2+1)*64 + i)*32 + tx*4];
      float r0 = ap[0], r1 = ap[1], r2 = ap[2];
      float w0v[4] = {w0.x,w0.y,w0.z,w0.w};
      float w1v[4] = {w1.x,w1.y,w1.z,w1.w};
      #pragma unroll
      for (int q = 0; q < 4; q++){
        acc[0][q] += r0*w0v[q];
        acc[1][q] += r1*w1v[q];
        acc[2][q] += r1*w0v[q];
        acc[3][q] += r2*w1v[q];
      }
    }
  }
  float s = 0.f, s2 = 0.f;
  float bz[4];
  #pragma unroll
  for (int q = 0; q < 4; q++) bz[q] = bias[tx*4+q];
  #pragma unroll
  for (int j = 0; j < 4; j++)
    #pragma unroll
    for (int q = 0; q < 4; q++){
      float v = acc[j][q] + bz[q];
      acc[j][q] = v; s += v; s2 += v*v;
    }
  block_reduce2(s, s2, sbuf);
  if (tid == 0){ atomicAdd(&stat[n*2], s); atomicAdd(&stat[n*2+1], s2); }
  float* op = outp + (size_t)n*8192;
  #pragma unroll
  for (int j = 0; j < 4; j++){
    int a = ga*4 + j;
    float4 v4 = make_float4(acc[j][0], acc[j][1], acc[j][2], acc[j][3]);
    *(float4*)&op[a*512 + b*32 + tx*4] = v4;
  }
}

// ---------------- dec_conv2 implicit GEMM ----------------
__global__ __launch_bounds__(256) void dec_conv2_ig(
    const float* __restrict__ in, const float* __restrict__ CWT, const float* __restrict__ bias,
    const float* __restrict__ stat_in, float* __restrict__ outp, float* __restrict__ stat)
{
  __shared__ __align__(16) float in_t[3456];   // [i32][sb6][sa18]
  __shared__ __align__(16) float ws[2048];     // [ph4][i32][o16] per tap
  __shared__ float sbuf[16];
  int bx = blockIdx.x;
  int n = bx >> 2, b0 = (bx & 3) * 8, tb0 = b0 >> 1;
  int tid = threadIdx.x;
  float sm = stat_in[n*2], sq = stat_in[n*2+1];
  float m = sm*(1.f/8192.f), rs = rsqrtf(sq*(1.f/8192.f) - m*m + 1e-5f);
  const float* ip = in + (size_t)n*8192;
  for (int l = tid; l < 3456; l += 256){
    int i = l & 31, sb = (l >> 5) % 6, sap = l / 192;
    int sa = sap - 1, sbg = tb0 - 1 + sb;
    float v = 0.f;
    if ((unsigned)sa < 16u && (unsigned)sbg < 16u)
      v = fmaxf((ip[sa*512 + sbg*32 + i]-m)*rs, 0.f);
    in_t[(i*6 + sb)*18 + sap] = v;
  }
  int tx = tid & 3, bloc = (tid>>2)&7, ga = tid>>5;
  int b = b0 + bloc, pb = bloc & 1;
  float acc[4][4] = {};
  for (int tap = 0; tap < 4; tap++){
    int db = tap >> 1, da = tap & 1;
    __syncthreads();
    for (int l = tid; l < 2048; l += 256){
      int ph = l >> 9;
      ws[l] = CWT[(ph*4 + tap)*512 + (l & 511)];
    }
    __syncthreads();
    int sbl = (bloc>>1) + db + pb;
    int h = ga*2 + da;
    #pragma unroll 4
    for (int i = 0; i < 32; i++){
      const float* ap = &in_t[(i*6 + sbl)*18 + h];
      float4 w0 = *(const float4*)&ws[(pb*2+0)*512 + i*16 + tx*4];
      float4 w1 = *(const float4*)&ws[(pb*2+1)*512 + i*16 + tx*4];
      float r0 = ap[0], r1 = ap[1], r2 = ap[2];
      float w0v[4] = {w0.x,w0.y,w0.z,w0.w};
      float w1v[4] = {w1.x,w1.y,w1.z,w1.w};
      #pragma unroll
      for (int q = 0; q < 4; q++){
        acc[0][q] += r0*w0v[q];
        acc[1][q] += r1*w1v[q];
        acc[2][q] += r1*w0v[q];
        acc[3][q] += r2*w1v[q];
      }
    }
  }
  float s = 0.f, s2 = 0.f;
  float bz[4];
  #pragma unroll
  for (int q = 0; q < 4; q++) bz[q] = bias[tx*4+q];
  #pragma unroll
  for (int j = 0; j < 4; j++)
    #pragma unroll
    for (int q = 0; q < 4; q++){
      float v = acc[j][q] + bz[q];
      acc[j][q] = v; s += v; s2 += v*v;
    }
  block_reduce2(s, s2, sbuf);
  if (tid == 0){ atomicAdd(&stat[n*2], s); atomicAdd(&stat[n*2+1], s2); }
  float* op = outp + (size_t)n*16384;
  #pragma unroll
  for (int j = 0; j < 4; j++){
    int a = ga*4 + j;
    float4 v4 = make_float4(acc[j][0], acc[j][1], acc[j][2], acc[j][3]);
    *(float4*)&op[a*512 + b*16 + tx*4] = v4;
  }
}

// ---------------- dec_conv3 ----------------
__global__ __launch_bounds__(256) void dec_conv3_ig(
    const float* __restrict__ in, const float* __restrict__ CWT, const float* __restrict__ bias,
    const float* __restrict__ stat_in, float* __restrict__ outp)
{
  __shared__ __align__(16) float in_t[9792];   // [sa34][sb18][i16]
  __shared__ __align__(16) float wl[256];
  int bx = blockIdx.x;
  int n = bx >> 1, b0 = (bx & 1) * 32, tb0 = b0 >> 1;
  int tid = threadIdx.x;
  float sm = stat_in[n*2], sq = stat_in[n*2+1];
  float m = sm*(1.f/16384.f), rs = rsqrtf(sq*(1.f/16384.f) - m*m + 1e-5f);
  const float* ip = in + (size_t)n*16384;
  for (int l = tid; l < 9792; l += 256){
    int i = l & 15, sb = (l >> 4) % 18, sap = l / 288;
    int sa = sap - 1, sbg = tb0 - 1 + sb;
    float v = 0.f;
    if ((unsigned)sa < 32u && (unsigned)sbg < 32u)
      v = fmaxf((ip[sa*512 + sbg*16 + i]-m)*rs, 0.f);
    in_t[(sap*18 + sb)*16 + i] = v;
  }
  for (int l = tid; l < 256; l += 256) wl[l] = CWT[l];
  __syncthreads();
  float bv = bias[0];
  int bl = tid & 31, ath = tid >> 5;
  int b = b0 + bl;
  int tb = b >> 1, pb = b & 1;
  float* op = outp + (size_t)n*4096;
  #pragma unroll
  for (int j = 0; j < 8; j++){
    int a = ath*8 + j;
    int ta = a >> 1, pa = a & 1;
    float4 s4 = make_float4(0.f,0.f,0.f,0.f);
    #pragma unroll
    for (int db = 0; db < 2; db++){
      int sb = tb + db + (pb ? 0 : -1);
      int sbl = sb - (tb0 - 1);
      #pragma unroll
      for (int da = 0; da < 2; da++){
        int sa = ta + da + (pa ? 0 : -1);
        int sap = sa + 1;
        const float4* A4 = (const float4*)&in_t[(sap*18 + sbl)*16];
        const float4* B4 = (const float4*)&wl[((pb*2+pa)*4 + db*2+da)*16];
        #pragma unroll
        for (int q = 0; q < 4; q++){
          float4 av = A4[q], bw = B4[q];
          s4.x += av.x*bw.x; s4.y += av.y*bw.y;
          s4.z += av.z*bw.z; s4.w += av.w*bw.w;
        }
      }
    }
    op[a*64 + b] = sigf(bv + s4.x + s4.y + s4.z + s4.w);
  }
}

// ---------------- pair build ----------------
__global__ __launch_bounds__(256) void pair_build(const float* __restrict__ tot, float* __restrict__ P)
{
  int r = blockIdx.x;
  int jj = r % 7, fi = r / 7;
  int i = fi & 7, j = fi >> 3;
  int jidx = jj < i ? jj : jj+1;
  const float* srcf = tot + (size_t)fi*1012;
  const float* srco = tot + (size_t)(j*8+jidx)*1012;
  float* op = P + (size_t)r*500;
  for (int c = threadIdx.x; c < 250; c += blockDim.x){
    op[c] = srcf[c];
    op[250+c] = srco[c];
  }
}

// ---------------- att2 ----------------
__global__ void att2_kernel(const float* __restrict__ A1, const float* __restrict__ w,
                            const float* __restrict__ b, float* __restrict__ att)
{
  int r = blockIdx.x*blockDim.x + threadIdx.x;
  if (r >= 2688) return;
  const float* ip = A1 + (size_t)r*100;
  float a = b[0];
  for (int c = 0; c < 100; c++) a += ip[c]*w[c];
  att[r] = sigf(a);
}

// ---------------- effect ----------------
__global__ __launch_bounds__(256) void effect_kernel(const float* __restrict__ X1,
    const float* __restrict__ att, float* __restrict__ tot)
{
  int row = blockIdx.x;
  for (int h = threadIdx.x; h < 250; h += blockDim.x){
    float s = 0.f;
    for (int jj = 0; jj < 7; jj++)
      s += X1[((size_t)row*7+jj)*250 + h] * att[row*7+jj];
    tot[(size_t)row*1012 + 250 + h] = s;
  }
}

extern "C" void kernel_launch(void* const* d_in, const int* in_sizes, int n_in,
                              void* d_out, int out_size, void* d_ws, size_t ws_size,
                              hipStream_t stream) {
  const float* x      = (const float*)d_in[0];
  const float* state  = (const float*)d_in[1];
  const float* c1w    = (const float*)d_in[2];
  const float* c1b    = (const float*)d_in[3];
  const float* c2w    = (const float*)d_in[4];
  const float* c2b    = (const float*)d_in[5];
  const float* c3w    = (const float*)d_in[6];
  const float* c3b    = (const float*)d_in[7];
  const float* efc_w  = (const float*)d_in[8];
  const float* efc_b  = (const float*)d_in[9];
  const float* renc_w = (const float*)d_in[10];
  const float* renc_b = (const float*)d_in[11];
  const float* core_w = (const float*)d_in[12];
  const float* core_b = (const float*)d_in[13];
  const float* ctx_w  = (const float*)d_in[14];
  const float* ctx_b  = (const float*)d_in[15];
  const float* att1_w = (const float*)d_in[16];
  const float* att1_b = (const float*)d_in[17];
  const float* att2_w = (const float*)d_in[18];
  const float* att2_b = (const float*)d_in[19];
  const float* out_w  = (const float*)d_in[20];
  const float* out_b  = (const float*)d_in[21];
  const float* dfc1_w = (const float*)d_in[22];
  const float* dfc1_b = (const float*)d_in[23];
  const float* dfc2_w = (const float*)d_in[24];
  const float* dfc2_b = (const float*)d_in[25];
  const float* d1w    = (const float*)d_in[26];
  const float* d1b    = (const float*)d_in[27];
  const float* d2w    = (const float*)d_in[28];
  const float* d2b    = (const float*)d_in[29];
  const float* d3w    = (const float*)d_in[30];
  const float* d3b    = (const float*)d_in[31];

  float* wsf = (float*)d_ws;
  size_t o = 0;
  float* E1  = wsf + o; o += (size_t)384*16384;   // enc1 raw; later PB, dec2 raw out
  float* E2  = wsf + o; o += (size_t)384*8192;    // enc2 raw; later dec1 raw
  float* E3  = wsf + o; o += (size_t)384*4096;    // enc3 raw; later G2
  float* TOT = wsf + o; o += (size_t)384*1012;
  float* Pr  = wsf + o; o += (size_t)2688*500;
  float* C1  = wsf + o; o += (size_t)2688*250;
  float* X1  = wsf + o; o += (size_t)2688*250;
  float* A1  = wsf + o; o += (size_t)2688*100;
  float* ATT = wsf + o; o += 2688;
  float* XR  = wsf + o; o += (size_t)384*250;
  float* G1  = wsf + o; o += (size_t)384*512;
  float* CWT1 = wsf + o; o += 32768;
  float* CWT2 = wsf + o; o += 8192;
  float* CWT3 = wsf + o; o += 256;
  float* WT2  = wsf + o; o += 8192;
  float* WT3  = wsf + o; o += 32768;
  float* STAT = wsf + o; o += 5*384*2;
  float* PB  = E1;
  float* D1O = E2;
  float* D2O = E1;
  float* G2  = E3;

  float* xout = (float*)d_out;
  float* sout = xout + (size_t)384*4096;

  // prep (independent)
  zero_stats<<<15, 256, 0, stream>>>(STAT);
  fold_kernel<<<128, 256, 0, stream>>>(d1w, CWT1, 32, 64);
  fold_kernel<<<32, 256, 0, stream>>>(d2w, CWT2, 16, 32);
  fold_kernel<<<1, 256, 0, stream>>>(d3w, CWT3, 1, 16);
  transpose_w<<<32, 256, 0, stream>>>(c2w, WT2, 32, 16);
  transpose_w<<<128, 256, 0, stream>>>(c3w, WT3, 64, 32);

  // encoder
  enc_conv1_ig<<<384, 256, 0, stream>>>(x, c1w, c1b, E1, STAT + ST_ENC1*768);
  enc_conv2_ig<<<768, 256, 0, stream>>>(E1, WT2, c2b, STAT + ST_ENC1*768, E2, STAT + ST_ENC2*768);
  enc_conv3_ig<<<768, 128, 0, stream>>>(E2, WT3, c3b, STAT + ST_ENC2*768, E3, STAT + ST_ENC3*768);
  gemm_splitk<<<dim3(8,6,8), 256, 0, stream>>>(E3, efc_w, PB, 384, 512, 4096, 8,
                                               STAT + ST_ENC3*768, 1.f/4096.f);
  reduce_ln<<<384, 256, 0, stream>>>(PB, efc_b, TOT+500, 384, 512, 8, 1012, 2);

  // state path
  gemm_splitk<<<dim3(4,6,8), 256, 0, stream>>>(state, renc_w, PB, 384, 250, 250, 8, nullptr, 0.f);
  reduce_ln<<<384, 256, 0, stream>>>(PB, renc_b, TOT, 384, 250, 8, 1012, 1);
  pair_build<<<2688, 256, 0, stream>>>(TOT, Pr);
  gemm_splitk<<<dim3(4,42,2), 256, 0, stream>>>(Pr, core_w, PB, 2688, 250, 500, 2, nullptr, 0.f);
  reduce_ln<<<2688, 256, 0, stream>>>(PB, core_b, C1, 2688, 250, 2, 250, 1);
  gemm_splitk<<<dim3(4,42,2), 256, 0, stream>>>(C1, ctx_w, PB, 2688, 250, 250, 2, nullptr, 0.f);
  reduce_ln<<<2688, 256, 0, stream>>>(PB, ctx_b, X1, 2688, 250, 2, 250, 1);
  gemm_splitk<<<dim3(2,42,4), 256, 0, stream>>>(C1, att1_w, PB, 2688, 100, 250, 4, nullptr, 0.f);
  reduce_ln<<<2688, 256, 0, stream>>>(PB, att1_b, A1, 2688, 100, 4, 100, 3);
  att2_kernel<<<11, 256, 0, stream>>>(A1, att2_w, att2_b, ATT);
  effect_kernel<<<384, 256, 0, stream>>>(X1, ATT, TOT);

  // combine
  gemm_splitk<<<dim3(4,6,8), 256, 0, stream>>>(TOT, out_w, PB, 384, 250, 1012, 8, nullptr, 0.f);
  reduce_ns<<<384, 256, 0, stream>>>(PB, out_b, XR, sout, 384, 250, 8);

  // decoder FC
  gemm_splitk<<<dim3(8,6,4), 256, 0, stream>>>(XR, dfc1_w, PB, 384, 512, 250, 4, nullptr, 0.f);
  reduce_ln<<<384, 256, 0, stream>>>(PB, dfc1_b, G1, 384, 512, 4, 512, 1);
  gemm_splitk<<<dim3(64,6,1), 256, 0, stream>>>(G1, dfc2_w, PB, 384, 4096, 512, 1, nullptr, 0.f);
  reduce_ln<<<384, 256, 0, stream>>>(PB, dfc2_b, G2, 384, 4096, 1, 4096, 1);

  // decoder convs
  dec_conv1_ig<<<768, 256, 0, stream>>>(G2, CWT1, d1b, D1O, STAT + ST_DEC1*768);
  dec_conv2_ig<<<1536, 256, 0, stream>>>(D1O, CWT2, d2b, STAT + ST_DEC1*768, D2O, STAT + ST_DEC2*768);
  dec_conv3_ig<<<768, 256, 0, stream>>>(D2O, CWT3, d3b, STAT + ST_DEC2*768, xout);

  (void)in_sizes; (void)n_in; (void)out_size; (void)ws_size;
}

// Round 6
// 585.045 us; speedup vs baseline: 3.7735x; 1.0998x over previous
//
#include <hip/hip_runtime.h>
#include <hip/hip_bf16.h>
#include <math.h>

// stats slots (sum,sumsq per sample), 384 samples each
#define ST_ENC2 0
#define ST_ENC3 1
#define ST_DEC1 2
#define ST_DEC2 3
#define ST_ENC1 4

typedef __attribute__((ext_vector_type(8))) short bf16x8;
typedef __attribute__((ext_vector_type(4))) float f32x4;

__device__ __forceinline__ float eluf(float v){ return v > 0.f ? v : expm1f(v); }
__device__ __forceinline__ float sigf(float v){ return 1.f/(1.f+expf(-v)); }
__device__ __forceinline__ unsigned short f2bf(float f){
  unsigned u = __float_as_uint(f);
  u += 0x7FFFu + ((u >> 16) & 1u);          // round-to-nearest-even
  return (unsigned short)(u >> 16);
}

// ---------------- block-wide sum & sumsq reduction ----------------
__device__ __forceinline__ void block_reduce2(float& a, float& b, float* sbuf){
  __syncthreads();
  for (int off = 32; off; off >>= 1){
    a += __shfl_down(a, off);
    b += __shfl_down(b, off);
  }
  int lane = threadIdx.x & 63, w = threadIdx.x >> 6;
  if (lane == 0){ sbuf[2*w] = a; sbuf[2*w+1] = b; }
  __syncthreads();
  if (threadIdx.x == 0){
    int nw = blockDim.x >> 6;
    float sa = 0.f, sb = 0.f;
    for (int i = 0; i < nw; i++){ sa += sbuf[2*i]; sb += sbuf[2*i+1]; }
    sbuf[0] = sa; sbuf[1] = sb;
  }
  __syncthreads();
  a = sbuf[0]; b = sbuf[1];
}

// ---------------- prep helpers ----------------
__device__ __forceinline__ void fold_elem(const float* __restrict__ w, float* __restrict__ CW,
                                          int O, int I, int l){
  int o = l % O; int q = l / O;
  int da = q & 1, db = (q>>1)&1, pa = (q>>2)&1, pb = (q>>3)&1, i = q>>4;
  float s = 0.f;
  for (int kh = 0; kh < 4; kh++){
    bool inh = (pb==0) ? (db==0 ? (kh==0) : (kh>=1)) : (db==0 ? (kh<=2) : (kh==3));
    if (!inh) continue;
    for (int kw = 0; kw < 4; kw++){
      bool inw = (pa==0) ? (da==0 ? (kw==0) : (kw>=1)) : (da==0 ? (kw<=2) : (kw==3));
      if (!inw) continue;
      s += w[((o*I + i)*4 + kh)*4 + kw];
    }
  }
  CW[(((pb*2+pa)*4 + db*2+da)*I + i)*O + o] = s;
}
__device__ __forceinline__ void tw_elem(const float* __restrict__ w, float* __restrict__ WT,
                                        int O, int I, int l){
  int o = l % O; int q = l / O; int i = q % I; int t = q / I;
  WT[(t*I + i)*O + o] = w[o*I*16 + i*16 + t];
}
__device__ __forceinline__ void cvt_elem(const float* __restrict__ W, short* __restrict__ D,
                                         int K, int N, int Kp, int l){
  int n = l / Kp, k = l - n*Kp;
  D[l] = (k < K) ? (short)f2bf(W[(size_t)k*N + n]) : (short)0;
}

// ---------------- single fused prep kernel ----------------
__global__ __launch_bounds__(256) void prep_all(
  float* __restrict__ stat,
  const float* __restrict__ d1w, float* __restrict__ CWT1,
  const float* __restrict__ d2w, float* __restrict__ CWT2,
  const float* __restrict__ d3w, float* __restrict__ CWT3,
  const float* __restrict__ c2w, float* __restrict__ WT2,
  const float* __restrict__ c3w, float* __restrict__ WT3,
  const float* __restrict__ efcw, short* __restrict__ Befc,
  const float* __restrict__ rencw, short* __restrict__ Brenc,
  const float* __restrict__ corew, short* __restrict__ Bcore,
  const float* __restrict__ ctxw, short* __restrict__ Bctx,
  const float* __restrict__ att1w, short* __restrict__ Batt1,
  const float* __restrict__ outw, short* __restrict__ Bout,
  const float* __restrict__ dfc1w, short* __restrict__ Bdfc1,
  const float* __restrict__ dfc2w, short* __restrict__ Bdfc2)
{
  const int S0=3840, S1=S0+32768, S2=S1+8192, S3=S2+256, S4=S3+8192, S5=S4+32768;
  const int C1=S5+2097152, C2=C1+64000, C3=C2+128000, C4=C3+64000,
            C5=C4+25600, C6=C5+256000, C7=C6+131072, TOTAL=C7+2097152;
  for (int l = blockIdx.x*blockDim.x + threadIdx.x; l < TOTAL; l += gridDim.x*blockDim.x){
    if (l < S0)      stat[l] = 0.f;
    else if (l < S1) fold_elem(d1w, CWT1, 32, 64, l - S0);
    else if (l < S2) fold_elem(d2w, CWT2, 16, 32, l - S1);
    else if (l < S3) fold_elem(d3w, CWT3, 1, 16, l - S2);
    else if (l < S4) tw_elem(c2w, WT2, 32, 16, l - S3);
    else if (l < S5) tw_elem(c3w, WT3, 64, 32, l - S4);
    else if (l < C1) cvt_elem(efcw,  Befc,  4096, 512,  4096, l - S5);
    else if (l < C2) cvt_elem(rencw, Brenc, 250,  250,  256,  l - C1);
    else if (l < C3) cvt_elem(corew, Bcore, 500,  250,  512,  l - C2);
    else if (l < C4) cvt_elem(ctxw,  Bctx,  250,  250,  256,  l - C3);
    else if (l < C5) cvt_elem(att1w, Batt1, 250,  100,  256,  l - C4);
    else if (l < C6) cvt_elem(outw,  Bout,  1012, 250,  1024, l - C5);
    else if (l < C7) cvt_elem(dfc1w, Bdfc1, 250,  512,  256,  l - C6);
    else             cvt_elem(dfc2w, Bdfc2, 512,  4096, 512,  l - C7);
  }
}

// ---------------- MFMA bf16 split-K GEMM ----------------
// P[ks][M][N] partial of A[M,K] @ B[K,N]; Bt is bf16 [N][Kp] (pre-transposed).
// grid (ceil(N/64), ceil(M/64), KS); block 256 = 4 waves, 64x64 tile, 2x2 16x16 frags/wave.
// Optional A-side transform: v = elu((v - mean)*rstd) from per-row stats.
__global__ __launch_bounds__(256) void gemm_mfma(
    const float* __restrict__ A, const short* __restrict__ Bt,
    float* __restrict__ P, int M, int N, int K, int Kc, int Kp,
    const float* __restrict__ Astat, float AinvN)
{
  __shared__ __align__(16) short As[64*32];
  __shared__ __align__(16) short Bs[64*32];
  int tid = threadIdx.x;
  int bm = blockIdx.y*64, bn = blockIdx.x*64;
  int kb = blockIdx.z * Kc;
  int kend = min(kb + Kc, Kp);

  // staging: thread -> (row = tid>>2, chunk = tid&3), 8 bf16 per thread
  int r = tid >> 2, c = tid & 3;
  int gr = bm + r;          // A row
  int gn = bn + r;          // Bt row (output col)
  bool aval = gr < M;
  bool bval = gn < N;
  float lnm = 0.f, lnr = 1.f;
  if (Astat && aval){
    float sm = Astat[gr*2], sq = Astat[gr*2+1];
    lnm = sm*AinvN;
    lnr = rsqrtf(sq*AinvN - lnm*lnm + 1e-5f);
  }
  const float* Arow = A + (size_t)gr*K;
  const short* Brow = Bt + (size_t)gn*Kp;

  uint4 hA, hB;
  auto load_regs = [&](int k0){
    int kk = k0 + c*8;
    float f[8];
    #pragma unroll
    for (int j = 0; j < 8; j++){
      int k = kk + j;
      float v = 0.f;
      if (aval && k < K){
        v = Arow[k];
        if (Astat) v = eluf((v - lnm)*lnr);
      }
      f[j] = v;
    }
    hA.x = f2bf(f[0]) | ((unsigned)f2bf(f[1]) << 16);
    hA.y = f2bf(f[2]) | ((unsigned)f2bf(f[3]) << 16);
    hA.z = f2bf(f[4]) | ((unsigned)f2bf(f[5]) << 16);
    hA.w = f2bf(f[6]) | ((unsigned)f2bf(f[7]) << 16);
    if (bval) hB = *(const uint4*)&Brow[kk];
    else      hB = make_uint4(0,0,0,0);
  };
  auto write_lds = [&](){
    *(uint4*)&As[r*32 + c*8] = hA;
    *(uint4*)&Bs[r*32 + c*8] = hB;
  };

  int wave = tid >> 6;
  int ln = tid & 15, quad = (tid >> 4) & 3;
  int wr = (wave >> 1) * 32, wc = (wave & 1) * 32;

  f32x4 zero = {0.f, 0.f, 0.f, 0.f};
  f32x4 acc[2][2] = {{zero, zero}, {zero, zero}};

  load_regs(kb);
  write_lds();
  __syncthreads();
  for (int k0 = kb; k0 < kend; k0 += 32){
    int nxt = k0 + 32;
    if (nxt < kend) load_regs(nxt);
    bf16x8 a0 = *(const bf16x8*)&As[(wr +      ln)*32 + quad*8];
    bf16x8 a1 = *(const bf16x8*)&As[(wr + 16 + ln)*32 + quad*8];
    bf16x8 b0 = *(const bf16x8*)&Bs[(wc +      ln)*32 + quad*8];
    bf16x8 b1 = *(const bf16x8*)&Bs[(wc + 16 + ln)*32 + quad*8];
    acc[0][0] = __builtin_amdgcn_mfma_f32_16x16x32_bf16(a0, b0, acc[0][0], 0, 0, 0);
    acc[0][1] = __builtin_amdgcn_mfma_f32_16x16x32_bf16(a0, b1, acc[0][1], 0, 0, 0);
    acc[1][0] = __builtin_amdgcn_mfma_f32_16x16x32_bf16(a1, b0, acc[1][0], 0, 0, 0);
    acc[1][1] = __builtin_amdgcn_mfma_f32_16x16x32_bf16(a1, b1, acc[1][1], 0, 0, 0);
    __syncthreads();
    if (nxt < kend){ write_lds(); __syncthreads(); }
  }

  float* Pout = P + (size_t)blockIdx.z*M*N;
  #pragma unroll
  for (int t = 0; t < 2; t++)
    #pragma unroll
    for (int u = 0; u < 2; u++)
      #pragma unroll
      for (int j = 0; j < 4; j++){
        int row = bm + wr + t*16 + quad*4 + j;
        int col = bn + wc + u*16 + ln;
        if (row < M && col < N) Pout[(size_t)row*N + col] = acc[t][u][j];
      }
}

// ---------------- fused: out = act(LN_last(sum_ks P + bias)) ----------------
__global__ __launch_bounds__(256) void reduce_ln(
    const float* __restrict__ Pp, const float* __restrict__ bias,
    float* __restrict__ out, int M, int N, int KS, int os, int act)
{
  __shared__ float rowbuf[4096];
  __shared__ float sbuf[16];
  int row = blockIdx.x;
  size_t MN = (size_t)M*N;
  float s = 0.f, s2 = 0.f;
  for (int c = threadIdx.x; c < N; c += 256){
    float v = bias[c];
    for (int ks = 0; ks < KS; ks++) v += Pp[ks*MN + (size_t)row*N + c];
    rowbuf[c] = v; s += v; s2 += v*v;
  }
  block_reduce2(s, s2, sbuf);
  float m = s / N;
  float r = rsqrtf(s2/N - m*m + 1e-5f);
  float* op = out + (size_t)row*os;
  for (int c = threadIdx.x; c < N; c += 256){
    float v = (rowbuf[c]-m)*r;
    if (act == 1) v = fmaxf(v, 0.f);
    else if (act == 2) v = eluf(v);
    else if (act == 3) v = tanhf(v);
    op[c] = v;
  }
}

// ---------------- fused NS ----------------
__global__ __launch_bounds__(256) void reduce_ns(
    const float* __restrict__ Pp, const float* __restrict__ bias,
    float* __restrict__ XR, float* __restrict__ so, int M, int N, int KS)
{
  __shared__ float rowbuf[256];
  __shared__ float sbuf[16];
  int row = blockIdx.x;
  size_t MN = (size_t)M*N;
  float s = 0.f, s2 = 0.f;
  for (int c = threadIdx.x; c < N; c += 256){
    float v = bias[c];
    for (int ks = 0; ks < KS; ks++) v += Pp[ks*MN + (size_t)row*N + c];
    rowbuf[c] = v; s += v; s2 += v*v;
  }
  block_reduce2(s, s2, sbuf);
  float m = s / N;
  float r = rsqrtf(s2/N - m*m + 1e-5f);
  for (int c = threadIdx.x; c < N; c += 256){
    float v = rowbuf[c];
    XR[(size_t)row*N+c] = sigf((v-m)*r);
    so[(size_t)row*N+c] = sigf(v);
  }
}

// ---------------- enc_conv1: x(n,64,64) -> raw (n,32,32,16) + stats ----------------
__global__ __launch_bounds__(256) void enc_conv1_ig(
    const float* __restrict__ x, const float* __restrict__ w, const float* __restrict__ bias,
    float* __restrict__ outp, float* __restrict__ stat)
{
  __shared__ __align__(16) float in_t[66*68];   // [aa+1][bb+1], row stride 68
  __shared__ float sbuf[16];
  int n = blockIdx.x, tid = threadIdx.x;
  for (int l = tid; l < 66*68; l += 256) in_t[l] = 0.f;
  __syncthreads();
  const float* xin = x + (size_t)n*4096;
  for (int l4 = tid; l4 < 1024; l4 += 256){
    float4 v = *(const float4*)&xin[l4*4];
    int aa = (l4*4) >> 6, bb = (l4*4) & 63;
    float* dst = &in_t[(aa+1)*68 + bb + 1];
    dst[0]=v.x; dst[1]=v.y; dst[2]=v.z; dst[3]=v.w;
  }
  int o = tid & 15;
  float wr[16];
  #pragma unroll
  for (int t = 0; t < 16; t++) wr[t] = w[o*16 + t];
  float bv = bias[o];
  __syncthreads();
  float s = 0.f, s2 = 0.f;
  float* op = outp + (size_t)n*16384;
  for (int r = 0; r < 64; r++){
    int idx = tid + (r<<8);
    int bq = (idx>>4)&31, aq = idx>>9;
    int a0 = 2*aq, b0 = 2*bq;
    float acc = bv;
    #pragma unroll
    for (int kw = 0; kw < 4; kw++){
      const float* row = &in_t[(a0+kw)*68 + b0];
      float2 p0 = *(const float2*)&row[0];
      float2 p1 = *(const float2*)&row[2];
      acc += p0.x*wr[0*4+kw] + p0.y*wr[1*4+kw] + p1.x*wr[2*4+kw] + p1.y*wr[3*4+kw];
    }
    op[idx] = acc;
    s += acc; s2 += acc*acc;
  }
  block_reduce2(s, s2, sbuf);
  if (tid == 0){ atomicAdd(&stat[n*2], s); atomicAdd(&stat[n*2+1], s2); }
}

// ---------------- enc_conv2 implicit GEMM ----------------
__global__ __launch_bounds__(256) void enc_conv2_ig(
    const float* __restrict__ in, const float* __restrict__ WT, const float* __restrict__ bias,
    const float* __restrict__ stat_in, float* __restrict__ outp, float* __restrict__ stat)
{
  __shared__ __align__(16) float in_t[9792];   // [i16][bb18][ph2][17]
  __shared__ __align__(16) float ws[512];
  __shared__ float sbuf[16];
  int bx = blockIdx.x;
  int n = bx >> 1, b0 = (bx & 1) * 8;
  int tid = threadIdx.x;
  float smv = stat_in[n*2], sqv = stat_in[n*2+1];
  float mI = smv*(1.f/16384.f), rsI = rsqrtf(sqv*(1.f/16384.f) - mI*mI + 1e-5f);
  const float* ip = in + (size_t)n*16384;
  for (int l = tid; l < 9792; l += 256){
    int i = l & 15, bb = (l >> 4) % 18, aap = l / 288;
    int aa = aap - 1;
    int bbg = 2*b0 - 1 + bb;
    float v = 0.f;
    if ((unsigned)aa < 32u && (unsigned)bbg < 32u)
      v = eluf((ip[aa*512 + bbg*16 + i]-mI)*rsI);
    int ph = aa & 1;
    int idx = (aa + ph) >> 1;
    in_t[((i*18 + bb)*2 + ph)*17 + idx] = v;
  }
  int tx = tid & 7, bloc = (tid>>3)&7, ga = tid>>6;
  int b = b0 + bloc;
  float acc[4][4] = {};
  for (int kh = 0; kh < 4; kh++){
    int bb = 2*bloc + kh;
    for (int kw = 0; kw < 4; kw++){
      int ph = (kw & 1) ^ 1;
      int ao = (kw >= 2) ? 1 : 0;
      __syncthreads();
      { int t = kh*4 + kw;
        for (int l = tid; l < 512; l += 256) ws[l] = WT[t*512 + l]; }
      __syncthreads();
      #pragma unroll 4
      for (int i = 0; i < 16; i++){
        const float* ap = &in_t[((i*18 + bb)*2 + ph)*17 + ga*4 + ao];
        float4 w4 = *(const float4*)&ws[i*32 + tx*4];
        float av[4] = {ap[0], ap[1], ap[2], ap[3]};
        float wv[4] = {w4.x, w4.y, w4.z, w4.w};
        #pragma unroll
        for (int j = 0; j < 4; j++)
          #pragma unroll
          for (int q = 0; q < 4; q++) acc[j][q] += av[j]*wv[q];
      }
    }
  }
  float s = 0.f, s2 = 0.f;
  float bz[4];
  #pragma unroll
  for (int q = 0; q < 4; q++) bz[q] = bias[tx*4+q];
  #pragma unroll
  for (int j = 0; j < 4; j++)
    #pragma unroll
    for (int q = 0; q < 4; q++){
      float v = acc[j][q] + bz[q];
      acc[j][q] = v; s += v; s2 += v*v;
    }
  block_reduce2(s, s2, sbuf);
  if (tid == 0){ atomicAdd(&stat[n*2], s); atomicAdd(&stat[n*2+1], s2); }
  float* op = outp + (size_t)n*8192;
  #pragma unroll
  for (int j = 0; j < 4; j++){
    int a = ga*4 + j;
    float4 v4 = make_float4(acc[j][0], acc[j][1], acc[j][2], acc[j][3]);
    *(float4*)&op[a*512 + b*32 + tx*4] = v4;
  }
}

// ---------------- enc_conv3 implicit GEMM ----------------
__global__ __launch_bounds__(128) void enc_conv3_ig(
    const float* __restrict__ in, const float* __restrict__ WT, const float* __restrict__ bias,
    const float* __restrict__ stat_in, float* __restrict__ outp, float* __restrict__ stat)
{
  __shared__ __align__(16) float in_t[5760];   // [i32][bb10][ph2][9]
  __shared__ __align__(16) float ws[2048];
  __shared__ float sbuf[16];
  int bx = blockIdx.x;
  int n = bx >> 1, b0 = (bx & 1) * 4;
  int tid = threadIdx.x;
  float sm = stat_in[n*2], sq = stat_in[n*2+1];
  float m = sm*(1.f/8192.f), rs = rsqrtf(sq*(1.f/8192.f) - m*m + 1e-5f);
  const float* ip = in + (size_t)n*8192;
  for (int l = tid; l < 5760; l += 128){
    int i = l & 31, bb = (l >> 5) % 10, aap = l / 320;
    int aa = aap - 1;
    int bbg = 2*b0 - 1 + bb;
    float v = 0.f;
    if ((unsigned)aa < 16u && (unsigned)bbg < 16u) v = eluf((ip[aa*512 + bbg*32 + i]-m)*rs);
    int ph = aa & 1;
    int idx = (aa + ph) >> 1;
    in_t[((i*10 + bb)*2 + ph)*9 + idx] = v;
  }
  int tx = tid & 15, bloc = (tid>>4)&3, ga = tid>>6;
  int b = b0 + bloc;
  float acc[4][4] = {};
  for (int kh = 0; kh < 4; kh++){
    int bb = 2*bloc + kh;
    for (int kw = 0; kw < 4; kw++){
      int ph = (kw & 1) ^ 1;
      int ao = (kw >= 2) ? 1 : 0;
      __syncthreads();
      { int t = kh*4 + kw;
        for (int l = tid; l < 2048; l += 128) ws[l] = WT[t*2048 + l]; }
      __syncthreads();
      #pragma unroll 4
      for (int i = 0; i < 32; i++){
        const float* ap = &in_t[((i*10 + bb)*2 + ph)*9 + ga*4 + ao];
        float4 w4 = *(const float4*)&ws[i*64 + tx*4];
        float av[4] = {ap[0], ap[1], ap[2], ap[3]};
        float wv[4] = {w4.x, w4.y, w4.z, w4.w};
        #pragma unroll
        for (int j = 0; j < 4; j++)
          #pragma unroll
          for (int q = 0; q < 4; q++) acc[j][q] += av[j]*wv[q];
      }
    }
  }
  float s = 0.f, s2 = 0.f;
  float bz[4];
  #pragma unroll
  for (int q = 0; q < 4; q++) bz[q] = bias[tx*4+q];
  #pragma unroll
  for (int j = 0; j < 4; j++)
    #pragma unroll
    for (int q = 0; q < 4; q++){
      float v = acc[j][q] + bz[q];
      acc[j][q] = v; s += v; s2 += v*v;
    }
  block_reduce2(s, s2, sbuf);
  if (tid == 0){ atomicAdd(&stat[n*2], s); atomicAdd(&stat[n*2+1], s2); }
  float* op = outp + (size_t)n*4096;
  #pragma unroll
  for (int j = 0; j < 4; j++){
    int a = ga*4 + j;
    float4 v4 = make_float4(acc[j][0], acc[j][1], acc[j][2], acc[j][3]);
    *(float4*)&op[a*512 + b*64 + tx*4] = v4;
  }
}

// ---------------- dec_conv1 implicit GEMM ----------------
__global__ __launch_bounds__(256) void dec_conv1_ig(
    const float* __restrict__ in, const float* __restrict__ CWT, const float* __restrict__ bias,
    float* __restrict__ outp, float* __restrict__ stat)
{
  __shared__ __align__(16) float in_t[3840];   // [i64][sb6][sa10]
  __shared__ __align__(16) float ws[8192];
  __shared__ float sbuf[16];
  int bx = blockIdx.x;
  int n = bx >> 1, b0 = (bx & 1) * 8, tb0 = b0 >> 1;
  int tid = threadIdx.x;
  const float* ip = in + (size_t)n*4096;
  for (int l = tid; l < 3840; l += 256){
    int i = l & 63, sb = (l >> 6) % 6, sap = l / 384;
    int sa = sap - 1, sbg = tb0 - 1 + sb;
    float v = 0.f;
    if ((unsigned)sa < 8u && (unsigned)sbg < 8u) v = ip[sa*512 + sbg*64 + i];
    in_t[(i*6 + sb)*10 + sap] = v;
  }
  int tx = tid & 7, bloc = (tid>>3)&7, ga = tid>>6;
  int b = b0 + bloc, pb = bloc & 1;
  float acc[4][4] = {};
  for (int tap = 0; tap < 4; tap++){
    int db = tap >> 1, da = tap & 1;
    __syncthreads();
    for (int l = tid; l < 8192; l += 256){
      int ph = l >> 11;
      ws[l] = CWT[(ph*4 + tap)*2048 + (l & 2047)];
    }
    __syncthreads();
    int sbl = (bloc>>1) + db + pb;
    int h = ga*2 + da;
    #pragma unroll 4
    for (int i = 0; i < 64; i++){
      const float* ap = &in_t[(i*6 + sbl)*10 + h];
      float4 w0 = *(const float4*)&ws[((pb*2+0)*64 + i)*32 + tx*4];
      float4 w1 = *(const float4*)&ws[((pb*2+1)*64 + i)*32 + tx*4];
      float r0 = ap[0], r1 = ap[1], r2 = ap[2];
      float w0v[4] = {w0.x,w0.y,w0.z,w0.w};
      float w1v[4] = {w1.x,w1.y,w1.z,w1.w};
      #pragma unroll
      for (int q = 0; q < 4; q++){
        acc[0][q] += r0*w0v[q];
        acc[1][q] += r1*w1v[q];
        acc[2][q] += r1*w0v[q];
        acc[3][q] += r2*w1v[q];
      }
    }
  }
  float s = 0.f, s2 = 0.f;
  float bz[4];
  #pragma unroll
  for (int q = 0; q < 4; q++) bz[q] = bias[tx*4+q];
  #pragma unroll
  for (int j = 0; j < 4; j++)
    #pragma unroll
    for (int q = 0; q < 4; q++){
      float v = acc[j][q] + bz[q];
      acc[j][q] = v; s += v; s2 += v*v;
    }
  block_reduce2(s, s2, sbuf);
  if (tid == 0){ atomicAdd(&stat[n*2], s); atomicAdd(&stat[n*2+1], s2); }
  float* op = outp + (size_t)n*8192;
  #pragma unroll
  for (int j = 0; j < 4; j++){
    int a = ga*4 + j;
    float4 v4 = make_float4(acc[j][0], acc[j][1], acc[j][2], acc[j][3]);
    *(float4*)&op[a*512 + b*32 + tx*4] = v4;
  }
}

// ---------------- dec_conv2 implicit GEMM ----------------
__global__ __launch_bounds__(256) void dec_conv2_ig(
    const float* __restrict__ in, const float* __restrict__ CWT, const float* __restrict__ bias,
    const float* __restrict__ stat_in, float* __restrict__ outp, float* __restrict__ stat)
{
  __shared__ __align__(16) float in_t[3456];   // [i32][sb6][sa18]
  __shared__ __align__(16) float ws[2048];
  __shared__ float sbuf[16];
  int bx = blockIdx.x;
  int n = bx >> 2, b0 = (bx & 3) * 8, tb0 = b0 >> 1;
  int tid = threadIdx.x;
  float sm = stat_in[n*2], sq = stat_in[n*2+1];
  float m = sm*(1.f/8192.f), rs = rsqrtf(sq*(1.f/8192.f) - m*m + 1e-5f);
  const float* ip = in + (size_t)n*8192;
  for (int l = tid; l < 3456; l += 256){
    int i = l & 31, sb = (l >> 5) % 6, sap = l / 192;
    int sa = sap - 1, sbg = tb0 - 1 + sb;
    float v = 0.f;
    if ((unsigned)sa < 16u && (unsigned)sbg < 16u)
      v = fmaxf((ip[sa*512 + sbg*32 + i]-m)*rs, 0.f);
    in_t[(i*6 + sb)*18 + sap] = v;
  }
  int tx = tid & 3, bloc = (tid>>2)&7, ga = tid>>5;
  int b = b0 + bloc, pb = bloc & 1;
  float acc[4][4] = {};
  for (int tap = 0; tap < 4; tap++){
    int db = tap >> 1, da = tap & 1;
    __syncthreads();
    for (int l = tid; l < 2048; l += 256){
      int ph = l >> 9;
      ws[l] = CWT[(ph*4 + tap)*512 + (l & 511)];
    }
    __syncthreads();
    int sbl = (bloc>>1) + db + pb;
    int h = ga*2 + da;
    #pragma unroll 4
    for (int i = 0; i < 32; i++){
      const float* ap = &in_t[(i*6 + sbl)*18 + h];
      float4 w0 = *(const float4*)&ws[(pb*2+0)*512 + i*16 + tx*4];
      float4 w1 = *(const float4*)&ws[(pb*2+1)*512 + i*16 + tx*4];
      float r0 = ap[0], r1 = ap[1], r2 = ap[2];
      float w0v[4] = {w0.x,w0.y,w0.z,w0.w};
      float w1v[4] = {w1.x,w1.y,w1.z,w1.w};
      #pragma unroll
      for (int q = 0; q < 4; q++){
        acc[0][q] += r0*w0v[q];
        acc[1][q] += r1*w1v[q];
        acc[2][q] += r1*w0v[q];
        acc[3][q] += r2*w1v[q];
      }
    }
  }
  float s = 0.f, s2 = 0.f;
  float bz[4];
  #pragma unroll
  for (int q = 0; q < 4; q++) bz[q] = bias[tx*4+q];
  #pragma unroll
  for (int j = 0; j < 4; j++)
    #pragma unroll
    for (int q = 0; q < 4; q++){
      float v = acc[j][q] + bz[q];
      acc[j][q] = v; s += v; s2 += v*v;
    }
  block_reduce2(s, s2, sbuf);
  if (tid == 0){ atomicAdd(&stat[n*2], s); atomicAdd(&stat[n*2+1], s2); }
  float* op = outp + (size_t)n*16384;
  #pragma unroll
  for (int j = 0; j < 4; j++){
    int a = ga*4 + j;
    float4 v4 = make_float4(acc[j][0], acc[j][1], acc[j][2], acc[j][3]);
    *(float4*)&op[a*512 + b*16 + tx*4] = v4;
  }
}

// ---------------- dec_conv3 ----------------
__global__ __launch_bounds__(256) void dec_conv3_ig(
    const float* __restrict__ in, const float* __restrict__ CWT, const float* __restrict__ bias,
    const float* __restrict__ stat_in, float* __restrict__ outp)
{
  __shared__ __align__(16) float in_t[9792];   // [sa34][sb18][i16]
  __shared__ __align__(16) float wl[256];
  int bx = blockIdx.x;
  int n = bx >> 1, b0 = (bx & 1) * 32, tb0 = b0 >> 1;
  int tid = threadIdx.x;
  float sm = stat_in[n*2], sq = stat_in[n*2+1];
  float m = sm*(1.f/16384.f), rs = rsqrtf(sq*(1.f/16384.f) - m*m + 1e-5f);
  const float* ip = in + (size_t)n*16384;
  for (int l = tid; l < 9792; l += 256){
    int i = l & 15, sb = (l >> 4) % 18, sap = l / 288;
    int sa = sap - 1, sbg = tb0 - 1 + sb;
    float v = 0.f;
    if ((unsigned)sa < 32u && (unsigned)sbg < 32u)
      v = fmaxf((ip[sa*512 + sbg*16 + i]-m)*rs, 0.f);
    in_t[(sap*18 + sb)*16 + i] = v;
  }
  for (int l = tid; l < 256; l += 256) wl[l] = CWT[l];
  __syncthreads();
  float bv = bias[0];
  int bl = tid & 31, ath = tid >> 5;
  int b = b0 + bl;
  int tb = b >> 1, pb = b & 1;
  float* op = outp + (size_t)n*4096;
  #pragma unroll
  for (int j = 0; j < 8; j++){
    int a = ath*8 + j;
    int ta = a >> 1, pa = a & 1;
    float4 s4 = make_float4(0.f,0.f,0.f,0.f);
    #pragma unroll
    for (int db = 0; db < 2; db++){
      int sb = tb + db + (pb ? 0 : -1);
      int sbl = sb - (tb0 - 1);
      #pragma unroll
      for (int da = 0; da < 2; da++){
        int sa = ta + da + (pa ? 0 : -1);
        int sap = sa + 1;
        const float4* A4 = (const float4*)&in_t[(sap*18 + sbl)*16];
        const float4* B4 = (const float4*)&wl[((pb*2+pa)*4 + db*2+da)*16];
        #pragma unroll
        for (int q = 0; q < 4; q++){
          float4 av = A4[q], bw = B4[q];
          s4.x += av.x*bw.x; s4.y += av.y*bw.y;
          s4.z += av.z*bw.z; s4.w += av.w*bw.w;
        }
      }
    }
    op[a*64 + b] = sigf(bv + s4.x + s4.y + s4.z + s4.w);
  }
}

// ---------------- pair build ----------------
__global__ __launch_bounds__(256) void pair_build(const float* __restrict__ tot, float* __restrict__ P)
{
  int r = blockIdx.x;
  int jj = r % 7, fi = r / 7;
  int i = fi & 7, j = fi >> 3;
  int jidx = jj < i ? jj : jj+1;
  const float* srcf = tot + (size_t)fi*1012;
  const float* srco = tot + (size_t)(j*8+jidx)*1012;
  float* op = P + (size_t)r*500;
  for (int c = threadIdx.x; c < 250; c += blockDim.x){
    op[c] = srcf[c];
    op[250+c] = srco[c];
  }
}

// ---------------- att2 ----------------
__global__ void att2_kernel(const float* __restrict__ A1, const float* __restrict__ w,
                            const float* __restrict__ b, float* __restrict__ att)
{
  int r = blockIdx.x*blockDim.x + threadIdx.x;
  if (r >= 2688) return;
  const float* ip = A1 + (size_t)r*100;
  float a = b[0];
  for (int c = 0; c < 100; c++) a += ip[c]*w[c];
  att[r] = sigf(a);
}

// ---------------- effect ----------------
__global__ __launch_bounds__(256) void effect_kernel(const float* __restrict__ X1,
    const float* __restrict__ att, float* __restrict__ tot)
{
  int row = blockIdx.x;
  for (int h = threadIdx.x; h < 250; h += blockDim.x){
    float s = 0.f;
    for (int jj = 0; jj < 7; jj++)
      s += X1[((size_t)row*7+jj)*250 + h] * att[row*7+jj];
    tot[(size_t)row*1012 + 250 + h] = s;
  }
}

extern "C" void kernel_launch(void* const* d_in, const int* in_sizes, int n_in,
                              void* d_out, int out_size, void* d_ws, size_t ws_size,
                              hipStream_t stream) {
  const float* x      = (const float*)d_in[0];
  const float* state  = (const float*)d_in[1];
  const float* c1w    = (const float*)d_in[2];
  const float* c1b    = (const float*)d_in[3];
  const float* c2w    = (const float*)d_in[4];
  const float* c2b    = (const float*)d_in[5];
  const float* c3w    = (const float*)d_in[6];
  const float* c3b    = (const float*)d_in[7];
  const float* efc_w  = (const float*)d_in[8];
  const float* efc_b  = (const float*)d_in[9];
  const float* renc_w = (const float*)d_in[10];
  const float* renc_b = (const float*)d_in[11];
  const float* core_w = (const float*)d_in[12];
  const float* core_b = (const float*)d_in[13];
  const float* ctx_w  = (const float*)d_in[14];
  const float* ctx_b  = (const float*)d_in[15];
  const float* att1_w = (const float*)d_in[16];
  const float* att1_b = (const float*)d_in[17];
  const float* att2_w = (const float*)d_in[18];
  const float* att2_b = (const float*)d_in[19];
  const float* out_w  = (const float*)d_in[20];
  const float* out_b  = (const float*)d_in[21];
  const float* dfc1_w = (const float*)d_in[22];
  const float* dfc1_b = (const float*)d_in[23];
  const float* dfc2_w = (const float*)d_in[24];
  const float* dfc2_b = (const float*)d_in[25];
  const float* d1w    = (const float*)d_in[26];
  const float* d1b    = (const float*)d_in[27];
  const float* d2w    = (const float*)d_in[28];
  const float* d2b    = (const float*)d_in[29];
  const float* d3w    = (const float*)d_in[30];
  const float* d3b    = (const float*)d_in[31];

  float* wsf = (float*)d_ws;
  size_t o = 0;
  float* E1  = wsf + o; o += (size_t)384*16384;   // enc1 raw; later PB, dec2 raw out
  float* E2  = wsf + o; o += (size_t)384*8192;    // enc2 raw; later dec1 raw
  float* E3  = wsf + o; o += (size_t)384*4096;    // enc3 raw; later G2
  float* TOT = wsf + o; o += (size_t)384*1012;
  float* Pr  = wsf + o; o += (size_t)2688*500;
  float* C1  = wsf + o; o += (size_t)2688*250;
  float* X1  = wsf + o; o += (size_t)2688*250;
  float* A1  = wsf + o; o += (size_t)2688*100;
  float* ATT = wsf + o; o += 2688;
  float* XR  = wsf + o; o += (size_t)384*250;
  float* G1  = wsf + o; o += (size_t)384*512;
  float* CWT1 = wsf + o; o += 32768;
  float* CWT2 = wsf + o; o += 8192;
  float* CWT3 = wsf + o; o += 256;
  float* WT2  = wsf + o; o += 8192;
  float* WT3  = wsf + o; o += 32768;
  float* STAT = wsf + o; o += 5*384*2;
  // bf16 transposed weight buffers (sizes in shorts; offsets in floats)
  short* BT_efc  = (short*)(wsf + o); o += 2097152/2;
  short* BT_renc = (short*)(wsf + o); o += 64000/2;
  short* BT_core = (short*)(wsf + o); o += 128000/2;
  short* BT_ctx  = (short*)(wsf + o); o += 64000/2;
  short* BT_att1 = (short*)(wsf + o); o += 25600/2;
  short* BT_out  = (short*)(wsf + o); o += 256000/2;
  short* BT_dfc1 = (short*)(wsf + o); o += 131072/2;
  short* BT_dfc2 = (short*)(wsf + o); o += 2097152/2;
  float* PB  = E1;
  float* D1O = E2;
  float* D2O = E1;
  float* G2  = E3;

  float* xout = (float*)d_out;
  float* sout = xout + (size_t)384*4096;

  // fused prep: stats zero + fold + transpose + bf16 weight conversion
  prep_all<<<1024, 256, 0, stream>>>(STAT,
      d1w, CWT1, d2w, CWT2, d3w, CWT3, c2w, WT2, c3w, WT3,
      efc_w, BT_efc, renc_w, BT_renc, core_w, BT_core, ctx_w, BT_ctx,
      att1_w, BT_att1, out_w, BT_out, dfc1_w, BT_dfc1, dfc2_w, BT_dfc2);

  // encoder
  enc_conv1_ig<<<384, 256, 0, stream>>>(x, c1w, c1b, E1, STAT + ST_ENC1*768);
  enc_conv2_ig<<<768, 256, 0, stream>>>(E1, WT2, c2b, STAT + ST_ENC1*768, E2, STAT + ST_ENC2*768);
  enc_conv3_ig<<<768, 128, 0, stream>>>(E2, WT3, c3b, STAT + ST_ENC2*768, E3, STAT + ST_ENC3*768);
  gemm_mfma<<<dim3(8,6,8), 256, 0, stream>>>(E3, BT_efc, PB, 384, 512, 4096, 512, 4096,
                                             STAT + ST_ENC3*768, 1.f/4096.f);
  reduce_ln<<<384, 256, 0, stream>>>(PB, efc_b, TOT+500, 384, 512, 8, 1012, 2);

  // state path
  gemm_mfma<<<dim3(4,6,8), 256, 0, stream>>>(state, BT_renc, PB, 384, 250, 250, 32, 256, nullptr, 0.f);
  reduce_ln<<<384, 256, 0, stream>>>(PB, renc_b, TOT, 384, 250, 8, 1012, 1);
  pair_build<<<2688, 256, 0, stream>>>(TOT, Pr);
  gemm_mfma<<<dim3(4,42,2), 256, 0, stream>>>(Pr, BT_core, PB, 2688, 250, 500, 256, 512, nullptr, 0.f);
  reduce_ln<<<2688, 256, 0, stream>>>(PB, core_b, C1, 2688, 250, 2, 250, 1);
  gemm_mfma<<<dim3(4,42,2), 256, 0, stream>>>(C1, BT_ctx, PB, 2688, 250, 250, 128, 256, nullptr, 0.f);
  reduce_ln<<<2688, 256, 0, stream>>>(PB, ctx_b, X1, 2688, 250, 2, 250, 1);
  gemm_mfma<<<dim3(2,42,4), 256, 0, stream>>>(C1, BT_att1, PB, 2688, 100, 250, 64, 256, nullptr, 0.f);
  reduce_ln<<<2688, 256, 0, stream>>>(PB, att1_b, A1, 2688, 100, 4, 100, 3);
  att2_kernel<<<11, 256, 0, stream>>>(A1, att2_w, att2_b, ATT);
  effect_kernel<<<384, 256, 0, stream>>>(X1, ATT, TOT);

  // combine
  gemm_mfma<<<dim3(4,6,8), 256, 0, stream>>>(TOT, BT_out, PB, 384, 250, 1012, 128, 1024, nullptr, 0.f);
  reduce_ns<<<384, 256, 0, stream>>>(PB, out_b, XR, sout, 384, 250, 8);

  // decoder FC
  gemm_mfma<<<dim3(8,6,4), 256, 0, stream>>>(XR, BT_dfc1, PB, 384, 512, 250, 64, 256, nullptr, 0.f);
  reduce_ln<<<384, 256, 0, stream>>>(PB, dfc1_b, G1, 384, 512, 4, 512, 1);
  gemm_mfma<<<dim3(64,6,1), 256, 0, stream>>>(G1, BT_dfc2, PB, 384, 4096, 512, 512, 512, nullptr, 0.f);
  reduce_ln<<<384, 256, 0, stream>>>(PB, dfc2_b, G2, 384, 4096, 1, 4096, 1);

  // decoder convs
  dec_conv1_ig<<<768, 256, 0, stream>>>(G2, CWT1, d1b, D1O, STAT + ST_DEC1*768);
  dec_conv2_ig<<<1536, 256, 0, stream>>>(D1O, CWT2, d2b, STAT + ST_DEC1*768, D2O, STAT + ST_DEC2*768);
  dec_conv3_ig<<<768, 256, 0, stream>>>(D2O, CWT3, d3b, STAT + ST_DEC2*768, xout);

  (void)in_sizes; (void)n_in; (void)out_size; (void)ws_size;
}

// Round 7
// 438.873 us; speedup vs baseline: 5.0303x; 1.3331x over previous
//
#include <hip/hip_runtime.h>
#include <hip/hip_bf16.h>
#include <math.h>

// stats slots (sum,sumsq per sample), 384 samples each
#define ST_ENC2 0
#define ST_ENC3 1
#define ST_DEC1 2
#define ST_DEC2 3
#define ST_ENC1 4

typedef __attribute__((ext_vector_type(8))) short bf16x8;
typedef __attribute__((ext_vector_type(4))) float f32x4;

__device__ __forceinline__ float eluf(float v){ return v > 0.f ? v : expm1f(v); }
__device__ __forceinline__ float sigf(float v){ return 1.f/(1.f+expf(-v)); }
__device__ __forceinline__ unsigned short f2bf(float f){
  unsigned u = __float_as_uint(f);
  u += 0x7FFFu + ((u >> 16) & 1u);          // round-to-nearest-even
  return (unsigned short)(u >> 16);
}

// ---------------- block-wide sum & sumsq reduction ----------------
__device__ __forceinline__ void block_reduce2(float& a, float& b, float* sbuf){
  __syncthreads();
  for (int off = 32; off; off >>= 1){
    a += __shfl_down(a, off);
    b += __shfl_down(b, off);
  }
  int lane = threadIdx.x & 63, w = threadIdx.x >> 6;
  if (lane == 0){ sbuf[2*w] = a; sbuf[2*w+1] = b; }
  __syncthreads();
  if (threadIdx.x == 0){
    int nw = blockDim.x >> 6;
    float sa = 0.f, sb = 0.f;
    for (int i = 0; i < nw; i++){ sa += sbuf[2*i]; sb += sbuf[2*i+1]; }
    sbuf[0] = sa; sbuf[1] = sb;
  }
  __syncthreads();
  a = sbuf[0]; b = sbuf[1];
}

// ---------------- prep helpers ----------------
__device__ __forceinline__ float fold_sum(const float* __restrict__ w, int O, int I,
                                          int o, int i, int pa, int pb, int da, int db){
  float s = 0.f;
  for (int kh = 0; kh < 4; kh++){
    bool inh = (pb==0) ? (db==0 ? (kh==0) : (kh>=1)) : (db==0 ? (kh<=2) : (kh==3));
    if (!inh) continue;
    for (int kw = 0; kw < 4; kw++){
      bool inw = (pa==0) ? (da==0 ? (kw==0) : (kw>=1)) : (da==0 ? (kw<=2) : (kw==3));
      if (!inw) continue;
      s += w[((o*I + i)*4 + kh)*4 + kw];
    }
  }
  return s;
}
__device__ __forceinline__ void fold_elem(const float* __restrict__ w, float* __restrict__ CW,
                                          int O, int I, int l){
  int o = l % O; int q = l / O;
  int da = q & 1, db = (q>>1)&1, pa = (q>>2)&1, pb = (q>>3)&1, i = q>>4;
  CW[(((pb*2+pa)*4 + db*2+da)*I + i)*O + o] = fold_sum(w, O, I, o, i, pa, pb, da, db);
}
__device__ __forceinline__ void cvt_elem(const float* __restrict__ W, short* __restrict__ D,
                                         int K, int N, int Kp, int l){
  int n = l / Kp, k = l - n*Kp;
  D[l] = (k < K) ? (short)f2bf(W[(size_t)k*N + n]) : (short)0;
}
__device__ __forceinline__ void cvtc2_elem(const float* __restrict__ w, short* __restrict__ D, int l){
  int i = l & 15, t = (l>>4) & 15, o = l>>8;        // k = t*16 + i
  D[l] = (short)f2bf(w[(o*16 + i)*16 + t]);
}
__device__ __forceinline__ void cvtc3_elem(const float* __restrict__ w, short* __restrict__ D, int l){
  int i = l & 31, t = (l>>5) & 15, o = l>>9;        // k = t*32 + i
  D[l] = (short)f2bf(w[(o*32 + i)*16 + t]);
}
__device__ __forceinline__ void foldd1_elem(const float* __restrict__ w, short* __restrict__ D, int l){
  int i = l & 63, tap = (l>>6)&3, o = (l>>8)&31, ph = l>>13;   // [(ph*32+o)*256 + tap*64 + i]
  D[l] = (short)f2bf(fold_sum(w, 32, 64, o, i, ph&1, ph>>1, tap&1, tap>>1));
}
__device__ __forceinline__ void foldd2_elem(const float* __restrict__ w, short* __restrict__ D, int l){
  int i = l & 31, tap = (l>>5)&3, o = (l>>7)&15, ph = l>>11;   // [(ph*16+o)*128 + tap*32 + i]
  D[l] = (short)f2bf(fold_sum(w, 16, 32, o, i, ph&1, ph>>1, tap&1, tap>>1));
}

// ---------------- single fused prep kernel ----------------
__global__ __launch_bounds__(256) void prep_all(
  float* __restrict__ stat,
  const float* __restrict__ d3w, float* __restrict__ CWT3,
  const float* __restrict__ c2w, short* __restrict__ BtC2,
  const float* __restrict__ c3w, short* __restrict__ BtC3,
  const float* __restrict__ d1w, short* __restrict__ BD1,
  const float* __restrict__ d2w, short* __restrict__ BD2,
  const float* __restrict__ efcw, short* __restrict__ Befc,
  const float* __restrict__ rencw, short* __restrict__ Brenc,
  const float* __restrict__ corew, short* __restrict__ Bcore,
  const float* __restrict__ ctxw, short* __restrict__ Bctx,
  const float* __restrict__ att1w, short* __restrict__ Batt1,
  const float* __restrict__ outw, short* __restrict__ Bout,
  const float* __restrict__ dfc1w, short* __restrict__ Bdfc1,
  const float* __restrict__ dfc2w, short* __restrict__ Bdfc2)
{
  const int S0=3840, F3=S0+256, P2=F3+8192, P3=P2+32768, P4=P3+32768, P5=P4+8192;
  const int C1=P5+2097152, C2=C1+64000, C3=C2+128000, C4=C3+64000,
            C5=C4+25600, C6=C5+256000, C7=C6+131072, TOTAL=C7+2097152;
  for (int l = blockIdx.x*blockDim.x + threadIdx.x; l < TOTAL; l += gridDim.x*blockDim.x){
    if (l < S0)      stat[l] = 0.f;
    else if (l < F3) fold_elem(d3w, CWT3, 1, 16, l - S0);
    else if (l < P2) cvtc2_elem(c2w, BtC2, l - F3);
    else if (l < P3) cvtc3_elem(c3w, BtC3, l - P2);
    else if (l < P4) foldd1_elem(d1w, BD1, l - P3);
    else if (l < P5) foldd2_elem(d2w, BD2, l - P4);
    else if (l < C1) cvt_elem(efcw,  Befc,  4096, 512,  4096, l - P5);
    else if (l < C2) cvt_elem(rencw, Brenc, 250,  250,  256,  l - C1);
    else if (l < C3) cvt_elem(corew, Bcore, 500,  250,  512,  l - C2);
    else if (l < C4) cvt_elem(ctxw,  Bctx,  250,  250,  256,  l - C3);
    else if (l < C5) cvt_elem(att1w, Batt1, 250,  100,  256,  l - C4);
    else if (l < C6) cvt_elem(outw,  Bout,  1012, 250,  1024, l - C5);
    else if (l < C7) cvt_elem(dfc1w, Bdfc1, 250,  512,  256,  l - C6);
    else             cvt_elem(dfc2w, Bdfc2, 512,  4096, 512,  l - C7);
  }
}

// ---------------- MFMA bf16 split-K GEMM ----------------
__global__ __launch_bounds__(256) void gemm_mfma(
    const float* __restrict__ A, const short* __restrict__ Bt,
    float* __restrict__ P, int M, int N, int K, int Kc, int Kp,
    const float* __restrict__ Astat, float AinvN)
{
  __shared__ __align__(16) short As[64*32];
  __shared__ __align__(16) short Bs[64*32];
  int tid = threadIdx.x;
  int bm = blockIdx.y*64, bn = blockIdx.x*64;
  int kb = blockIdx.z * Kc;
  int kend = min(kb + Kc, Kp);

  int r = tid >> 2, c = tid & 3;
  int gr = bm + r;
  int gn = bn + r;
  bool aval = gr < M;
  bool bval = gn < N;
  float lnm = 0.f, lnr = 1.f;
  if (Astat && aval){
    float sm = Astat[gr*2], sq = Astat[gr*2+1];
    lnm = sm*AinvN;
    lnr = rsqrtf(sq*AinvN - lnm*lnm + 1e-5f);
  }
  const float* Arow = A + (size_t)gr*K;
  const short* Brow = Bt + (size_t)gn*Kp;

  uint4 hA, hB;
  auto load_regs = [&](int k0){
    int kk = k0 + c*8;
    float f[8];
    #pragma unroll
    for (int j = 0; j < 8; j++){
      int k = kk + j;
      float v = 0.f;
      if (aval && k < K){
        v = Arow[k];
        if (Astat) v = eluf((v - lnm)*lnr);
      }
      f[j] = v;
    }
    hA.x = f2bf(f[0]) | ((unsigned)f2bf(f[1]) << 16);
    hA.y = f2bf(f[2]) | ((unsigned)f2bf(f[3]) << 16);
    hA.z = f2bf(f[4]) | ((unsigned)f2bf(f[5]) << 16);
    hA.w = f2bf(f[6]) | ((unsigned)f2bf(f[7]) << 16);
    if (bval) hB = *(const uint4*)&Brow[kk];
    else      hB = make_uint4(0,0,0,0);
  };
  auto write_lds = [&](){
    *(uint4*)&As[r*32 + c*8] = hA;
    *(uint4*)&Bs[r*32 + c*8] = hB;
  };

  int wave = tid >> 6;
  int ln = tid & 15, quad = (tid >> 4) & 3;
  int wr = (wave >> 1) * 32, wc = (wave & 1) * 32;

  f32x4 zero = {0.f, 0.f, 0.f, 0.f};
  f32x4 acc[2][2] = {{zero, zero}, {zero, zero}};

  load_regs(kb);
  write_lds();
  __syncthreads();
  for (int k0 = kb; k0 < kend; k0 += 32){
    int nxt = k0 + 32;
    if (nxt < kend) load_regs(nxt);
    bf16x8 a0 = *(const bf16x8*)&As[(wr +      ln)*32 + quad*8];
    bf16x8 a1 = *(const bf16x8*)&As[(wr + 16 + ln)*32 + quad*8];
    bf16x8 b0 = *(const bf16x8*)&Bs[(wc +      ln)*32 + quad*8];
    bf16x8 b1 = *(const bf16x8*)&Bs[(wc + 16 + ln)*32 + quad*8];
    acc[0][0] = __builtin_amdgcn_mfma_f32_16x16x32_bf16(a0, b0, acc[0][0], 0, 0, 0);
    acc[0][1] = __builtin_amdgcn_mfma_f32_16x16x32_bf16(a0, b1, acc[0][1], 0, 0, 0);
    acc[1][0] = __builtin_amdgcn_mfma_f32_16x16x32_bf16(a1, b0, acc[1][0], 0, 0, 0);
    acc[1][1] = __builtin_amdgcn_mfma_f32_16x16x32_bf16(a1, b1, acc[1][1], 0, 0, 0);
    __syncthreads();
    if (nxt < kend){ write_lds(); __syncthreads(); }
  }

  float* Pout = P + (size_t)blockIdx.z*M*N;
  #pragma unroll
  for (int t = 0; t < 2; t++)
    #pragma unroll
    for (int u = 0; u < 2; u++)
      #pragma unroll
      for (int j = 0; j < 4; j++){
        int row = bm + wr + t*16 + quad*4 + j;
        int col = bn + wc + u*16 + ln;
        if (row < M && col < N) Pout[(size_t)row*N + col] = acc[t][u][j];
      }
}

// ---------------- fused: out = act(LN_last(sum_ks P + bias)) ----------------
__global__ __launch_bounds__(256) void reduce_ln(
    const float* __restrict__ Pp, const float* __restrict__ bias,
    float* __restrict__ out, int M, int N, int KS, int os, int act)
{
  __shared__ float rowbuf[4096];
  __shared__ float sbuf[16];
  int row = blockIdx.x;
  size_t MN = (size_t)M*N;
  float s = 0.f, s2 = 0.f;
  for (int c = threadIdx.x; c < N; c += 256){
    float v = bias[c];
    for (int ks = 0; ks < KS; ks++) v += Pp[ks*MN + (size_t)row*N + c];
    rowbuf[c] = v; s += v; s2 += v*v;
  }
  block_reduce2(s, s2, sbuf);
  float m = s / N;
  float r = rsqrtf(s2/N - m*m + 1e-5f);
  float* op = out + (size_t)row*os;
  for (int c = threadIdx.x; c < N; c += 256){
    float v = (rowbuf[c]-m)*r;
    if (act == 1) v = fmaxf(v, 0.f);
    else if (act == 2) v = eluf(v);
    else if (act == 3) v = tanhf(v);
    op[c] = v;
  }
}

// ---------------- fused NS ----------------
__global__ __launch_bounds__(256) void reduce_ns(
    const float* __restrict__ Pp, const float* __restrict__ bias,
    float* __restrict__ XR, float* __restrict__ so, int M, int N, int KS)
{
  __shared__ float rowbuf[256];
  __shared__ float sbuf[16];
  int row = blockIdx.x;
  size_t MN = (size_t)M*N;
  float s = 0.f, s2 = 0.f;
  for (int c = threadIdx.x; c < N; c += 256){
    float v = bias[c];
    for (int ks = 0; ks < KS; ks++) v += Pp[ks*MN + (size_t)row*N + c];
    rowbuf[c] = v; s += v; s2 += v*v;
  }
  block_reduce2(s, s2, sbuf);
  float m = s / N;
  float r = rsqrtf(s2/N - m*m + 1e-5f);
  for (int c = threadIdx.x; c < N; c += 256){
    float v = rowbuf[c];
    XR[(size_t)row*N+c] = sigf((v-m)*r);
    so[(size_t)row*N+c] = sigf(v);
  }
}

// ---------------- enc_conv1: x(n,64,64) -> raw (n,32,32,16) + stats ----------------
__global__ __launch_bounds__(256) void enc_conv1_ig(
    const float* __restrict__ x, const float* __restrict__ w, const float* __restrict__ bias,
    float* __restrict__ outp, float* __restrict__ stat)
{
  __shared__ __align__(16) float in_t[66*68];
  __shared__ float sbuf[16];
  int n = blockIdx.x, tid = threadIdx.x;
  for (int l = tid; l < 66*68; l += 256) in_t[l] = 0.f;
  __syncthreads();
  const float* xin = x + (size_t)n*4096;
  for (int l4 = tid; l4 < 1024; l4 += 256){
    float4 v = *(const float4*)&xin[l4*4];
    int aa = (l4*4) >> 6, bb = (l4*4) & 63;
    float* dst = &in_t[(aa+1)*68 + bb + 1];
    dst[0]=v.x; dst[1]=v.y; dst[2]=v.z; dst[3]=v.w;
  }
  int o = tid & 15;
  float wr[16];
  #pragma unroll
  for (int t = 0; t < 16; t++) wr[t] = w[o*16 + t];
  float bv = bias[o];
  __syncthreads();
  float s = 0.f, s2 = 0.f;
  float* op = outp + (size_t)n*16384;
  for (int r = 0; r < 64; r++){
    int idx = tid + (r<<8);
    int bq = (idx>>4)&31, aq = idx>>9;
    int a0 = 2*aq, b0 = 2*bq;
    float acc = bv;
    #pragma unroll
    for (int kw = 0; kw < 4; kw++){
      const float* row = &in_t[(a0+kw)*68 + b0];
      float2 p0 = *(const float2*)&row[0];
      float2 p1 = *(const float2*)&row[2];
      acc += p0.x*wr[0*4+kw] + p0.y*wr[1*4+kw] + p1.x*wr[2*4+kw] + p1.y*wr[3*4+kw];
    }
    op[idx] = acc;
    s += acc; s2 += acc*acc;
  }
  block_reduce2(s, s2, sbuf);
  if (tid == 0){ atomicAdd(&stat[n*2], s); atomicAdd(&stat[n*2+1], s2); }
}

// ---------------- enc_conv2 MFMA implicit GEMM ----------------
// in E1 raw (n,32,32,16)+enc1 stats -> elu(LN) staged bf16; out raw (n,16,16,32)+stats.
// M=256 pos, N=32, K=256 (k = tap*16+i). grid 384, block 256.
__global__ __launch_bounds__(256) void enc_conv2_mfma(
    const float* __restrict__ in, const short* __restrict__ Bt, const float* __restrict__ bias,
    const float* __restrict__ stat_in, float* __restrict__ outp, float* __restrict__ stat)
{
  __shared__ __align__(16) short in_t[34*34*16];
  __shared__ float sbuf[16];
  int n = blockIdx.x, tid = threadIdx.x;
  float smv = stat_in[n*2], sqv = stat_in[n*2+1];
  float m = smv*(1.f/16384.f), rs = rsqrtf(sqv*(1.f/16384.f) - m*m + 1e-5f);
  for (int l = tid; l < 34*34*16/4; l += 256) ((unsigned long long*)in_t)[l] = 0ull;
  __syncthreads();
  const float* ip = in + (size_t)n*16384;
  for (int l = tid; l < 4096; l += 256){
    int i4 = l & 3, bb = (l>>2) & 31, aa = l>>7;
    float4 v = *(const float4*)&ip[aa*512 + bb*16 + i4*4];
    uint2 pk;
    pk.x = f2bf(eluf((v.x-m)*rs)) | ((unsigned)f2bf(eluf((v.y-m)*rs))<<16);
    pk.y = f2bf(eluf((v.z-m)*rs)) | ((unsigned)f2bf(eluf((v.w-m)*rs))<<16);
    *(uint2*)&in_t[((aa+1)*34 + (bb+1))*16 + i4*4] = pk;
  }
  int wave = tid>>6, ln = tid&15, quad = (tid>>4)&3;
  bf16x8 bfr[2][8];
  #pragma unroll
  for (int nt = 0; nt < 2; nt++){
    const short* Brow = Bt + (nt*16 + ln)*256;
    #pragma unroll
    for (int ks = 0; ks < 8; ks++)
      bfr[nt][ks] = *(const bf16x8*)&Brow[ks*32 + quad*8];
  }
  __syncthreads();
  f32x4 z = {0.f,0.f,0.f,0.f};
  f32x4 acc[2][4] = {{z,z,z,z},{z,z,z,z}};
  int tapq = quad>>1, io = (quad&1)*8;
  #pragma unroll
  for (int ks = 0; ks < 8; ks++){
    int t = 2*ks + tapq;
    int kh = t>>2, kw = t&3;
    #pragma unroll
    for (int mt = 0; mt < 4; mt++){
      int p = (wave*4 + mt)*16 + ln;
      int oa = p>>4, ob = p&15;
      bf16x8 a = *(const bf16x8*)&in_t[((2*oa+kw)*34 + (2*ob+kh))*16 + io];
      acc[0][mt] = __builtin_amdgcn_mfma_f32_16x16x32_bf16(a, bfr[0][ks], acc[0][mt],0,0,0);
      acc[1][mt] = __builtin_amdgcn_mfma_f32_16x16x32_bf16(a, bfr[1][ks], acc[1][mt],0,0,0);
    }
  }
  float s = 0.f, s2 = 0.f;
  float* op = outp + (size_t)n*8192;
  #pragma unroll
  for (int nt = 0; nt < 2; nt++){
    int o = nt*16 + ln;
    float bz = bias[o];
    #pragma unroll
    for (int mt = 0; mt < 4; mt++)
      #pragma unroll
      for (int j = 0; j < 4; j++){
        int p = (wave*4 + mt)*16 + quad*4 + j;
        float v = acc[nt][mt][j] + bz;
        s += v; s2 += v*v;
        int oa = p>>4, ob = p&15;
        op[oa*512 + ob*32 + o] = v;
      }
  }
  block_reduce2(s, s2, sbuf);
  if (tid == 0){ atomicAdd(&stat[n*2], s); atomicAdd(&stat[n*2+1], s2); }
}

// ---------------- enc_conv3 MFMA implicit GEMM ----------------
// in E2 raw (n,16,16,32)+enc2 stats -> elu(LN) staged bf16; out raw (n,8,8,64)+stats.
// M=64 pos, N=64, K=512 (k = tap*32+i). grid 384, block 256; wave = n-tile.
__global__ __launch_bounds__(256) void enc_conv3_mfma(
    const float* __restrict__ in, const short* __restrict__ Bt, const float* __restrict__ bias,
    const float* __restrict__ stat_in, float* __restrict__ outp, float* __restrict__ stat)
{
  __shared__ __align__(16) short in_t[18*18*32];
  __shared__ float sbuf[16];
  int n = blockIdx.x, tid = threadIdx.x;
  float smv = stat_in[n*2], sqv = stat_in[n*2+1];
  float m = smv*(1.f/8192.f), rs = rsqrtf(sqv*(1.f/8192.f) - m*m + 1e-5f);
  for (int l = tid; l < 18*18*32/4; l += 256) ((unsigned long long*)in_t)[l] = 0ull;
  __syncthreads();
  const float* ip = in + (size_t)n*8192;
  for (int l = tid; l < 2048; l += 256){
    int i4 = l & 7, bb = (l>>3)&15, aa = l>>7;
    float4 v = *(const float4*)&ip[aa*512 + bb*32 + i4*4];
    uint2 pk;
    pk.x = f2bf(eluf((v.x-m)*rs)) | ((unsigned)f2bf(eluf((v.y-m)*rs))<<16);
    pk.y = f2bf(eluf((v.z-m)*rs)) | ((unsigned)f2bf(eluf((v.w-m)*rs))<<16);
    *(uint2*)&in_t[((aa+1)*18 + (bb+1))*32 + i4*4] = pk;
  }
  int wave = tid>>6, ln = tid&15, quad = (tid>>4)&3;
  int o = wave*16 + ln;
  bf16x8 bfr[16];
  {
    const short* Brow = Bt + o*512;
    #pragma unroll
    for (int ks = 0; ks < 16; ks++)
      bfr[ks] = *(const bf16x8*)&Brow[ks*32 + quad*8];
  }
  __syncthreads();
  f32x4 z = {0.f,0.f,0.f,0.f};
  f32x4 acc[4] = {z,z,z,z};
  #pragma unroll
  for (int ks = 0; ks < 16; ks++){
    int kh = ks>>2, kw = ks&3;
    #pragma unroll
    for (int mt = 0; mt < 4; mt++){
      int p = mt*16 + ln;
      int oa = p>>3, ob = p&7;
      bf16x8 a = *(const bf16x8*)&in_t[((2*oa+kw)*18 + (2*ob+kh))*32 + quad*8];
      acc[mt] = __builtin_amdgcn_mfma_f32_16x16x32_bf16(a, bfr[ks], acc[mt],0,0,0);
    }
  }
  float s = 0.f, s2 = 0.f;
  float bz = bias[o];
  float* op = outp + (size_t)n*4096;
  #pragma unroll
  for (int mt = 0; mt < 4; mt++)
    #pragma unroll
    for (int j = 0; j < 4; j++){
      int p = mt*16 + quad*4 + j;
      int oa = p>>3, ob = p&7;
      float v = acc[mt][j] + bz;
      s += v; s2 += v*v;
      op[oa*512 + ob*64 + o] = v;
    }
  block_reduce2(s, s2, sbuf);
  if (tid == 0){ atomicAdd(&stat[n*2], s); atomicAdd(&stat[n*2+1], s2); }
}

// ---------------- dec_conv1 MFMA implicit GEMM (per-phase) ----------------
// in G2 (n,8,8,64) final; out raw (n,16,16,32)+stats. wave = phase; per phase:
// M=64 (ta,tb), N=32, K=256 (k = tap*64+i). grid 384, block 256.
__global__ __launch_bounds__(256) void dec_conv1_mfma(
    const float* __restrict__ in, const short* __restrict__ Bd, const float* __restrict__ bias,
    float* __restrict__ outp, float* __restrict__ stat)
{
  __shared__ __align__(16) short in_t[10*10*64];
  __shared__ float sbuf[16];
  int n = blockIdx.x, tid = threadIdx.x;
  for (int l = tid; l < 10*10*64/4; l += 256) ((unsigned long long*)in_t)[l] = 0ull;
  __syncthreads();
  const float* ip = in + (size_t)n*4096;
  for (int l = tid; l < 1024; l += 256){
    int i4 = l & 15, sb = (l>>4)&7, sa = l>>7;
    float4 v = *(const float4*)&ip[sa*512 + sb*64 + i4*4];
    uint2 pk;
    pk.x = f2bf(v.x) | ((unsigned)f2bf(v.y)<<16);
    pk.y = f2bf(v.z) | ((unsigned)f2bf(v.w)<<16);
    *(uint2*)&in_t[((sa+1)*10 + (sb+1))*64 + i4*4] = pk;
  }
  int wave = tid>>6, ln = tid&15, quad = (tid>>4)&3;
  int pa = wave & 1, pb = wave >> 1;
  bf16x8 bfr[2][8];
  #pragma unroll
  for (int nt = 0; nt < 2; nt++){
    const short* Brow = Bd + (wave*32 + nt*16 + ln)*256;
    #pragma unroll
    for (int ks = 0; ks < 8; ks++)
      bfr[nt][ks] = *(const bf16x8*)&Brow[ks*32 + quad*8];
  }
  __syncthreads();
  f32x4 z = {0.f,0.f,0.f,0.f};
  f32x4 acc[2][4] = {{z,z,z,z},{z,z,z,z}};
  #pragma unroll
  for (int ks = 0; ks < 8; ks++){
    int tap = ks>>1, ibase = (ks&1)*32 + quad*8;
    int da = tap & 1, db = tap >> 1;
    #pragma unroll
    for (int mt = 0; mt < 4; mt++){
      int p = mt*16 + ln;
      int ta = p>>3, tb = p&7;
      bf16x8 a = *(const bf16x8*)&in_t[((ta+da+pa)*10 + (tb+db+pb))*64 + ibase];
      acc[0][mt] = __builtin_amdgcn_mfma_f32_16x16x32_bf16(a, bfr[0][ks], acc[0][mt],0,0,0);
      acc[1][mt] = __builtin_amdgcn_mfma_f32_16x16x32_bf16(a, bfr[1][ks], acc[1][mt],0,0,0);
    }
  }
  float s = 0.f, s2 = 0.f;
  float* op = outp + (size_t)n*8192;
  #pragma unroll
  for (int nt = 0; nt < 2; nt++){
    int o = nt*16 + ln;
    float bz = bias[o];
    #pragma unroll
    for (int mt = 0; mt < 4; mt++)
      #pragma unroll
      for (int j = 0; j < 4; j++){
        int p = mt*16 + quad*4 + j;
        int ta = p>>3, tb = p&7;
        float v = acc[nt][mt][j] + bz;
        s += v; s2 += v*v;
        op[(2*ta+pa)*512 + (2*tb+pb)*32 + o] = v;
      }
  }
  block_reduce2(s, s2, sbuf);
  if (tid == 0){ atomicAdd(&stat[n*2], s); atomicAdd(&stat[n*2+1], s2); }
}

// ---------------- dec_conv2 MFMA implicit GEMM (per-phase) ----------------
// in D1 raw (n,16,16,32)+dec1 stats -> relu(LN) staged bf16; out raw (n,32,32,16)+stats.
// wave = phase; per phase: M=256, N=16, K=128 (k = tap*32+i). grid 384.
__global__ __launch_bounds__(256) void dec_conv2_mfma(
    const float* __restrict__ in, const short* __restrict__ Bd, const float* __restrict__ bias,
    const float* __restrict__ stat_in, float* __restrict__ outp, float* __restrict__ stat)
{
  __shared__ __align__(16) short in_t[18*18*32];
  __shared__ float sbuf[16];
  int n = blockIdx.x, tid = threadIdx.x;
  float smv = stat_in[n*2], sqv = stat_in[n*2+1];
  float m = smv*(1.f/8192.f), rs = rsqrtf(sqv*(1.f/8192.f) - m*m + 1e-5f);
  for (int l = tid; l < 18*18*32/4; l += 256) ((unsigned long long*)in_t)[l] = 0ull;
  __syncthreads();
  const float* ip = in + (size_t)n*8192;
  for (int l = tid; l < 2048; l += 256){
    int i4 = l & 7, sb = (l>>3)&15, sa = l>>7;
    float4 v = *(const float4*)&ip[sa*512 + sb*32 + i4*4];
    uint2 pk;
    pk.x = f2bf(fmaxf((v.x-m)*rs,0.f)) | ((unsigned)f2bf(fmaxf((v.y-m)*rs,0.f))<<16);
    pk.y = f2bf(fmaxf((v.z-m)*rs,0.f)) | ((unsigned)f2bf(fmaxf((v.w-m)*rs,0.f))<<16);
    *(uint2*)&in_t[((sa+1)*18 + (sb+1))*32 + i4*4] = pk;
  }
  int wave = tid>>6, ln = tid&15, quad = (tid>>4)&3;
  int pa = wave & 1, pb = wave >> 1;
  bf16x8 bfr[4];
  {
    const short* Brow = Bd + (wave*16 + ln)*128;
    #pragma unroll
    for (int ks = 0; ks < 4; ks++)
      bfr[ks] = *(const bf16x8*)&Brow[ks*32 + quad*8];
  }
  __syncthreads();
  f32x4 z = {0.f,0.f,0.f,0.f};
  f32x4 acc[16] = {z,z,z,z,z,z,z,z,z,z,z,z,z,z,z,z};
  #pragma unroll
  for (int ks = 0; ks < 4; ks++){
    int da = ks & 1, db = ks >> 1;
    #pragma unroll
    for (int mt = 0; mt < 16; mt++){
      int p = mt*16 + ln;
      int ta = p>>4, tb = p&15;
      bf16x8 a = *(const bf16x8*)&in_t[((ta+da+pa)*18 + (tb+db+pb))*32 + quad*8];
      acc[mt] = __builtin_amdgcn_mfma_f32_16x16x32_bf16(a, bfr[ks], acc[mt],0,0,0);
    }
  }
  float s = 0.f, s2 = 0.f;
  float bz = bias[ln];
  float* op = outp + (size_t)n*16384;
  #pragma unroll
  for (int mt = 0; mt < 16; mt++)
    #pragma unroll
    for (int j = 0; j < 4; j++){
      int p = mt*16 + quad*4 + j;
      int ta = p>>4, tb = p&15;
      float v = acc[mt][j] + bz;
      s += v; s2 += v*v;
      op[(2*ta+pa)*512 + (2*tb+pb)*16 + ln] = v;
    }
  block_reduce2(s, s2, sbuf);
  if (tid == 0){ atomicAdd(&stat[n*2], s); atomicAdd(&stat[n*2+1], s2); }
}

// ---------------- dec_conv3 ----------------
__global__ __launch_bounds__(256) void dec_conv3_ig(
    const float* __restrict__ in, const float* __restrict__ CWT, const float* __restrict__ bias,
    const float* __restrict__ stat_in, float* __restrict__ outp)
{
  __shared__ __align__(16) float in_t[9792];   // [sa34][sb18][i16]
  __shared__ __align__(16) float wl[256];
  int bx = blockIdx.x;
  int n = bx >> 1, b0 = (bx & 1) * 32, tb0 = b0 >> 1;
  int tid = threadIdx.x;
  float sm = stat_in[n*2], sq = stat_in[n*2+1];
  float m = sm*(1.f/16384.f), rs = rsqrtf(sq*(1.f/16384.f) - m*m + 1e-5f);
  const float* ip = in + (size_t)n*16384;
  for (int l = tid; l < 9792; l += 256){
    int i = l & 15, sb = (l >> 4) % 18, sap = l / 288;
    int sa = sap - 1, sbg = tb0 - 1 + sb;
    float v = 0.f;
    if ((unsigned)sa < 32u && (unsigned)sbg < 32u)
      v = fmaxf((ip[sa*512 + sbg*16 + i]-m)*rs, 0.f);
    in_t[(sap*18 + sb)*16 + i] = v;
  }
  for (int l = tid; l < 256; l += 256) wl[l] = CWT[l];
  __syncthreads();
  float bv = bias[0];
  int bl = tid & 31, ath = tid >> 5;
  int b = b0 + bl;
  int tb = b >> 1, pb = b & 1;
  float* op = outp + (size_t)n*4096;
  #pragma unroll
  for (int j = 0; j < 8; j++){
    int a = ath*8 + j;
    int ta = a >> 1, pa = a & 1;
    float4 s4 = make_float4(0.f,0.f,0.f,0.f);
    #pragma unroll
    for (int db = 0; db < 2; db++){
      int sb = tb + db + (pb ? 0 : -1);
      int sbl = sb - (tb0 - 1);
      #pragma unroll
      for (int da = 0; da < 2; da++){
        int sa = ta + da + (pa ? 0 : -1);
        int sap = sa + 1;
        const float4* A4 = (const float4*)&in_t[(sap*18 + sbl)*16];
        const float4* B4 = (const float4*)&wl[((pb*2+pa)*4 + db*2+da)*16];
        #pragma unroll
        for (int q = 0; q < 4; q++){
          float4 av = A4[q], bw = B4[q];
          s4.x += av.x*bw.x; s4.y += av.y*bw.y;
          s4.z += av.z*bw.z; s4.w += av.w*bw.w;
        }
      }
    }
    op[a*64 + b] = sigf(bv + s4.x + s4.y + s4.z + s4.w);
  }
}

// ---------------- pair build ----------------
__global__ __launch_bounds__(256) void pair_build(const float* __restrict__ tot, float* __restrict__ P)
{
  int r = blockIdx.x;
  int jj = r % 7, fi = r / 7;
  int i = fi & 7, j = fi >> 3;
  int jidx = jj < i ? jj : jj+1;
  const float* srcf = tot + (size_t)fi*1012;
  const float* srco = tot + (size_t)(j*8+jidx)*1012;
  float* op = P + (size_t)r*500;
  for (int c = threadIdx.x; c < 250; c += blockDim.x){
    op[c] = srcf[c];
    op[250+c] = srco[c];
  }
}

// ---------------- att2 ----------------
__global__ void att2_kernel(const float* __restrict__ A1, const float* __restrict__ w,
                            const float* __restrict__ b, float* __restrict__ att)
{
  int r = blockIdx.x*blockDim.x + threadIdx.x;
  if (r >= 2688) return;
  const float* ip = A1 + (size_t)r*100;
  float a = b[0];
  for (int c = 0; c < 100; c++) a += ip[c]*w[c];
  att[r] = sigf(a);
}

// ---------------- effect ----------------
__global__ __launch_bounds__(256) void effect_kernel(const float* __restrict__ X1,
    const float* __restrict__ att, float* __restrict__ tot)
{
  int row = blockIdx.x;
  for (int h = threadIdx.x; h < 250; h += blockDim.x){
    float s = 0.f;
    for (int jj = 0; jj < 7; jj++)
      s += X1[((size_t)row*7+jj)*250 + h] * att[row*7+jj];
    tot[(size_t)row*1012 + 250 + h] = s;
  }
}

extern "C" void kernel_launch(void* const* d_in, const int* in_sizes, int n_in,
                              void* d_out, int out_size, void* d_ws, size_t ws_size,
                              hipStream_t stream) {
  const float* x      = (const float*)d_in[0];
  const float* state  = (const float*)d_in[1];
  const float* c1w    = (const float*)d_in[2];
  const float* c1b    = (const float*)d_in[3];
  const float* c2w    = (const float*)d_in[4];
  const float* c2b    = (const float*)d_in[5];
  const float* c3w    = (const float*)d_in[6];
  const float* c3b    = (const float*)d_in[7];
  const float* efc_w  = (const float*)d_in[8];
  const float* efc_b  = (const float*)d_in[9];
  const float* renc_w = (const float*)d_in[10];
  const float* renc_b = (const float*)d_in[11];
  const float* core_w = (const float*)d_in[12];
  const float* core_b = (const float*)d_in[13];
  const float* ctx_w  = (const float*)d_in[14];
  const float* ctx_b  = (const float*)d_in[15];
  const float* att1_w = (const float*)d_in[16];
  const float* att1_b = (const float*)d_in[17];
  const float* att2_w = (const float*)d_in[18];
  const float* att2_b = (const float*)d_in[19];
  const float* out_w  = (const float*)d_in[20];
  const float* out_b  = (const float*)d_in[21];
  const float* dfc1_w = (const float*)d_in[22];
  const float* dfc1_b = (const float*)d_in[23];
  const float* dfc2_w = (const float*)d_in[24];
  const float* dfc2_b = (const float*)d_in[25];
  const float* d1w    = (const float*)d_in[26];
  const float* d1b    = (const float*)d_in[27];
  const float* d2w    = (const float*)d_in[28];
  const float* d2b    = (const float*)d_in[29];
  const float* d3w    = (const float*)d_in[30];
  const float* d3b    = (const float*)d_in[31];

  float* wsf = (float*)d_ws;
  size_t o = 0;
  float* E1  = wsf + o; o += (size_t)384*16384;   // enc1 raw; later PB, dec2 raw out
  float* E2  = wsf + o; o += (size_t)384*8192;    // enc2 raw; later dec1 raw
  float* E3  = wsf + o; o += (size_t)384*4096;    // enc3 raw; later G2
  float* TOT = wsf + o; o += (size_t)384*1012;
  float* Pr  = wsf + o; o += (size_t)2688*500;
  float* C1  = wsf + o; o += (size_t)2688*250;
  float* X1  = wsf + o; o += (size_t)2688*250;
  float* A1  = wsf + o; o += (size_t)2688*100;
  float* ATT = wsf + o; o += 2688;
  float* XR  = wsf + o; o += (size_t)384*250;
  float* G1  = wsf + o; o += (size_t)384*512;
  float* CWT3 = wsf + o; o += 256;
  float* STAT = wsf + o; o += 5*384*2;
  // bf16 weight buffers (sizes in shorts; offsets in floats)
  short* BtC2 = (short*)(wsf + o); o += 8192/2;
  short* BtC3 = (short*)(wsf + o); o += 32768/2;
  short* BD1  = (short*)(wsf + o); o += 32768/2;
  short* BD2  = (short*)(wsf + o); o += 8192/2;
  short* BT_efc  = (short*)(wsf + o); o += 2097152/2;
  short* BT_renc = (short*)(wsf + o); o += 64000/2;
  short* BT_core = (short*)(wsf + o); o += 128000/2;
  short* BT_ctx  = (short*)(wsf + o); o += 64000/2;
  short* BT_att1 = (short*)(wsf + o); o += 25600/2;
  short* BT_out  = (short*)(wsf + o); o += 256000/2;
  short* BT_dfc1 = (short*)(wsf + o); o += 131072/2;
  short* BT_dfc2 = (short*)(wsf + o); o += 2097152/2;
  float* PB  = E1;
  float* D1O = E2;
  float* D2O = E1;
  float* G2  = E3;

  float* xout = (float*)d_out;
  float* sout = xout + (size_t)384*4096;

  // fused prep: stats zero + folds + bf16 weight packing
  prep_all<<<1024, 256, 0, stream>>>(STAT,
      d3w, CWT3, c2w, BtC2, c3w, BtC3, d1w, BD1, d2w, BD2,
      efc_w, BT_efc, renc_w, BT_renc, core_w, BT_core, ctx_w, BT_ctx,
      att1_w, BT_att1, out_w, BT_out, dfc1_w, BT_dfc1, dfc2_w, BT_dfc2);

  // encoder
  enc_conv1_ig<<<384, 256, 0, stream>>>(x, c1w, c1b, E1, STAT + ST_ENC1*768);
  enc_conv2_mfma<<<384, 256, 0, stream>>>(E1, BtC2, c2b, STAT + ST_ENC1*768, E2, STAT + ST_ENC2*768);
  enc_conv3_mfma<<<384, 256, 0, stream>>>(E2, BtC3, c3b, STAT + ST_ENC2*768, E3, STAT + ST_ENC3*768);
  gemm_mfma<<<dim3(8,6,8), 256, 0, stream>>>(E3, BT_efc, PB, 384, 512, 4096, 512, 4096,
                                             STAT + ST_ENC3*768, 1.f/4096.f);
  reduce_ln<<<384, 256, 0, stream>>>(PB, efc_b, TOT+500, 384, 512, 8, 1012, 2);

  // state path
  gemm_mfma<<<dim3(4,6,8), 256, 0, stream>>>(state, BT_renc, PB, 384, 250, 250, 32, 256, nullptr, 0.f);
  reduce_ln<<<384, 256, 0, stream>>>(PB, renc_b, TOT, 384, 250, 8, 1012, 1);
  pair_build<<<2688, 256, 0, stream>>>(TOT, Pr);
  gemm_mfma<<<dim3(4,42,2), 256, 0, stream>>>(Pr, BT_core, PB, 2688, 250, 500, 256, 512, nullptr, 0.f);
  reduce_ln<<<2688, 256, 0, stream>>>(PB, core_b, C1, 2688, 250, 2, 250, 1);
  gemm_mfma<<<dim3(4,42,2), 256, 0, stream>>>(C1, BT_ctx, PB, 2688, 250, 250, 128, 256, nullptr, 0.f);
  reduce_ln<<<2688, 256, 0, stream>>>(PB, ctx_b, X1, 2688, 250, 2, 250, 1);
  gemm_mfma<<<dim3(2,42,4), 256, 0, stream>>>(C1, BT_att1, PB, 2688, 100, 250, 64, 256, nullptr, 0.f);
  reduce_ln<<<2688, 256, 0, stream>>>(PB, att1_b, A1, 2688, 100, 4, 100, 3);
  att2_kernel<<<11, 256, 0, stream>>>(A1, att2_w, att2_b, ATT);
  effect_kernel<<<384, 256, 0, stream>>>(X1, ATT, TOT);

  // combine
  gemm_mfma<<<dim3(4,6,8), 256, 0, stream>>>(TOT, BT_out, PB, 384, 250, 1012, 128, 1024, nullptr, 0.f);
  reduce_ns<<<384, 256, 0, stream>>>(PB, out_b, XR, sout, 384, 250, 8);

  // decoder FC
  gemm_mfma<<<dim3(8,6,4), 256, 0, stream>>>(XR, BT_dfc1, PB, 384, 512, 250, 64, 256, nullptr, 0.f);
  reduce_ln<<<384, 256, 0, stream>>>(PB, dfc1_b, G1, 384, 512, 4, 512, 1);
  gemm_mfma<<<dim3(64,6,1), 256, 0, stream>>>(G1, BT_dfc2, PB, 384, 4096, 512, 512, 512, nullptr, 0.f);
  reduce_ln<<<384, 256, 0, stream>>>(PB, dfc2_b, G2, 384, 4096, 1, 4096, 1);

  // decoder convs
  dec_conv1_mfma<<<384, 256, 0, stream>>>(G2, BD1, d1b, D1O, STAT + ST_DEC1*768);
  dec_conv2_mfma<<<384, 256, 0, stream>>>(D1O, BD2, d2b, STAT + ST_DEC1*768, D2O, STAT + ST_DEC2*768);
  dec_conv3_ig<<<768, 256, 0, stream>>>(D2O, CWT3, d3b, STAT + ST_DEC2*768, xout);

  (void)in_sizes; (void)n_in; (void)out_size; (void)ws_size;
}

// Round 8
// 371.609 us; speedup vs baseline: 5.9408x; 1.1810x over previous
//
#include <hip/hip_runtime.h>
#include <hip/hip_bf16.h>
#include <math.h>

// stats slots (sum,sumsq per sample), 384 samples each
#define ST_ENC2 0
#define ST_ENC3 1
#define ST_DEC1 2
#define ST_DEC2 3
#define ST_ENC1 4

typedef __attribute__((ext_vector_type(8))) short bf16x8;
typedef __attribute__((ext_vector_type(4))) float f32x4;

__device__ __forceinline__ float eluf(float v){ return v > 0.f ? v : expm1f(v); }
__device__ __forceinline__ float sigf(float v){ return 1.f/(1.f+expf(-v)); }
__device__ __forceinline__ unsigned short f2bf(float f){
  unsigned u = __float_as_uint(f);
  u += 0x7FFFu + ((u >> 16) & 1u);          // round-to-nearest-even
  return (unsigned short)(u >> 16);
}

// ---------------- block-wide sum & sumsq reduction ----------------
__device__ __forceinline__ void block_reduce2(float& a, float& b, float* sbuf){
  __syncthreads();
  for (int off = 32; off; off >>= 1){
    a += __shfl_down(a, off);
    b += __shfl_down(b, off);
  }
  int lane = threadIdx.x & 63, w = threadIdx.x >> 6;
  if (lane == 0){ sbuf[2*w] = a; sbuf[2*w+1] = b; }
  __syncthreads();
  if (threadIdx.x == 0){
    int nw = blockDim.x >> 6;
    float sa = 0.f, sb = 0.f;
    for (int i = 0; i < nw; i++){ sa += sbuf[2*i]; sb += sbuf[2*i+1]; }
    sbuf[0] = sa; sbuf[1] = sb;
  }
  __syncthreads();
  a = sbuf[0]; b = sbuf[1];
}

// ---------------- prep helpers ----------------
__device__ __forceinline__ float fold_sum(const float* __restrict__ w, int O, int I,
                                          int o, int i, int pa, int pb, int da, int db){
  float s = 0.f;
  for (int kh = 0; kh < 4; kh++){
    bool inh = (pb==0) ? (db==0 ? (kh==0) : (kh>=1)) : (db==0 ? (kh<=2) : (kh==3));
    if (!inh) continue;
    for (int kw = 0; kw < 4; kw++){
      bool inw = (pa==0) ? (da==0 ? (kw==0) : (kw>=1)) : (da==0 ? (kw<=2) : (kw==3));
      if (!inw) continue;
      s += w[((o*I + i)*4 + kh)*4 + kw];
    }
  }
  return s;
}
__device__ __forceinline__ void fold_elem(const float* __restrict__ w, float* __restrict__ CW,
                                          int O, int I, int l){
  int o = l % O; int q = l / O;
  int da = q & 1, db = (q>>1)&1, pa = (q>>2)&1, pb = (q>>3)&1, i = q>>4;
  CW[(((pb*2+pa)*4 + db*2+da)*I + i)*O + o] = fold_sum(w, O, I, o, i, pa, pb, da, db);
}
__device__ __forceinline__ void cvt_elem(const float* __restrict__ W, short* __restrict__ D,
                                         int K, int N, int Kp, int l){
  int n = l / Kp, k = l - n*Kp;
  D[l] = (k < K) ? (short)f2bf(W[(size_t)k*N + n]) : (short)0;
}
__device__ __forceinline__ void cvtc2_elem(const float* __restrict__ w, short* __restrict__ D, int l){
  int i = l & 15, t = (l>>4) & 15, o = l>>8;        // k = t*16 + i
  D[l] = (short)f2bf(w[(o*16 + i)*16 + t]);
}
__device__ __forceinline__ void cvtc3_elem(const float* __restrict__ w, short* __restrict__ D, int l){
  int i = l & 31, t = (l>>5) & 15, o = l>>9;        // k = t*32 + i
  D[l] = (short)f2bf(w[(o*32 + i)*16 + t]);
}
__device__ __forceinline__ void foldd1_elem(const float* __restrict__ w, short* __restrict__ D, int l){
  int i = l & 63, tap = (l>>6)&3, o = (l>>8)&31, ph = l>>13;
  D[l] = (short)f2bf(fold_sum(w, 32, 64, o, i, ph&1, ph>>1, tap&1, tap>>1));
}
__device__ __forceinline__ void foldd2_elem(const float* __restrict__ w, short* __restrict__ D, int l){
  int i = l & 31, tap = (l>>5)&3, o = (l>>7)&15, ph = l>>11;
  D[l] = (short)f2bf(fold_sum(w, 16, 32, o, i, ph&1, ph>>1, tap&1, tap>>1));
}

// ---------------- single fused prep kernel ----------------
__global__ __launch_bounds__(256) void prep_all(
  float* __restrict__ stat,
  const float* __restrict__ d3w, float* __restrict__ CWT3,
  const float* __restrict__ c2w, short* __restrict__ BtC2,
  const float* __restrict__ c3w, short* __restrict__ BtC3,
  const float* __restrict__ d1w, short* __restrict__ BD1,
  const float* __restrict__ d2w, short* __restrict__ BD2,
  const float* __restrict__ efcw, short* __restrict__ Befc,
  const float* __restrict__ rencw, short* __restrict__ Brenc,
  const float* __restrict__ corew, short* __restrict__ Bcore,
  const float* __restrict__ ctxw, short* __restrict__ Bctx,
  const float* __restrict__ att1w, short* __restrict__ Batt1,
  const float* __restrict__ outw, short* __restrict__ Bout,
  const float* __restrict__ dfc1w, short* __restrict__ Bdfc1,
  const float* __restrict__ dfc2w, short* __restrict__ Bdfc2,
  const float* __restrict__ state, short* __restrict__ SBF)
{
  const int S0=3840, F3=S0+256, P2=F3+8192, P3=P2+32768, P4=P3+32768, P5=P4+8192;
  const int C1=P5+2097152, C2=C1+64000, C3=C2+128000, C4=C3+64000,
            C5=C4+25600, C6=C5+256000, C7=C6+131072, C8=C7+2097152, TOTAL=C8+98304;
  for (int l = blockIdx.x*blockDim.x + threadIdx.x; l < TOTAL; l += gridDim.x*blockDim.x){
    if (l < S0)      stat[l] = 0.f;
    else if (l < F3) fold_elem(d3w, CWT3, 1, 16, l - S0);
    else if (l < P2) cvtc2_elem(c2w, BtC2, l - F3);
    else if (l < P3) cvtc3_elem(c3w, BtC3, l - P2);
    else if (l < P4) foldd1_elem(d1w, BD1, l - P3);
    else if (l < P5) foldd2_elem(d2w, BD2, l - P4);
    else if (l < C1) cvt_elem(efcw,  Befc,  4096, 512,  4096, l - P5);
    else if (l < C2) cvt_elem(rencw, Brenc, 250,  250,  256,  l - C1);
    else if (l < C3) cvt_elem(corew, Bcore, 500,  250,  512,  l - C2);
    else if (l < C4) cvt_elem(ctxw,  Bctx,  250,  250,  256,  l - C3);
    else if (l < C5) cvt_elem(att1w, Batt1, 250,  100,  256,  l - C4);
    else if (l < C6) cvt_elem(outw,  Bout,  1012, 250,  1024, l - C5);
    else if (l < C7) cvt_elem(dfc1w, Bdfc1, 250,  512,  256,  l - C6);
    else if (l < C8) cvt_elem(dfc2w, Bdfc2, 512,  4096, 512,  l - C7);
    else {
      int q = l - C8;             // state -> bf16 [384][256], zero pad
      int n = q >> 8, k = q & 255;
      SBF[q] = (k < 250) ? (short)f2bf(state[n*250 + k]) : (short)0;
    }
  }
}

// ---------------- cvt_ln_elu: E3 raw + stats -> bf16 elu(LN) [384][4096] ----------------
__global__ __launch_bounds__(256) void cvt_ln_elu(
    const float* __restrict__ in, const float* __restrict__ stat, short* __restrict__ outb)
{
  int n = blockIdx.x, tid = threadIdx.x;
  float sm = stat[n*2], sq = stat[n*2+1];
  float m = sm*(1.f/4096.f), rs = rsqrtf(sq*(1.f/4096.f) - m*m + 1e-5f);
  const float* ip = in + (size_t)n*4096;
  short* op = outb + (size_t)n*4096;
  for (int l = tid*4; l < 4096; l += 1024){
    float4 v = *(const float4*)&ip[l];
    uint2 pk;
    pk.x = f2bf(eluf((v.x-m)*rs)) | ((unsigned)f2bf(eluf((v.y-m)*rs))<<16);
    pk.y = f2bf(eluf((v.z-m)*rs)) | ((unsigned)f2bf(eluf((v.w-m)*rs))<<16);
    *(uint2*)&op[l] = pk;
  }
}

// ---------------- MFMA bf16 split-K GEMM, bf16 A ----------------
// P[ks][M][N] partial of A[M,Kp] @ B[N,Kp]^T; both bf16, K pre-padded (B pad zeroed).
// M multiple of 64. grid (ceil(N/64), M/64, KS); Kc multiple of 32.
__global__ __launch_bounds__(256) void gemm_mfma(
    const short* __restrict__ Ab, const short* __restrict__ Bt,
    float* __restrict__ P, int M, int N, int Kp, int Kc)
{
  __shared__ __align__(16) short As[64*32];
  __shared__ __align__(16) short Bs[64*32];
  int tid = threadIdx.x;
  int bm = blockIdx.y*64, bn = blockIdx.x*64;
  int kb = blockIdx.z * Kc;
  int kend = kb + Kc;

  int r = tid >> 2, c = tid & 3;
  const short* Arow = Ab + (size_t)(bm + r)*Kp;
  int gn = bn + r;
  bool bval = gn < N;
  const short* Brow = Bt + (size_t)gn*Kp;

  uint4 hA, hB;
  auto load_regs = [&](int k0){
    hA = *(const uint4*)&Arow[k0 + c*8];
    hB = bval ? *(const uint4*)&Brow[k0 + c*8] : make_uint4(0,0,0,0);
  };
  auto write_lds = [&](){
    *(uint4*)&As[r*32 + c*8] = hA;
    *(uint4*)&Bs[r*32 + c*8] = hB;
  };

  int wave = tid >> 6;
  int ln = tid & 15, quad = (tid >> 4) & 3;
  int wr = (wave >> 1) * 32, wc = (wave & 1) * 32;

  f32x4 zero = {0.f, 0.f, 0.f, 0.f};
  f32x4 acc[2][2] = {{zero, zero}, {zero, zero}};

  load_regs(kb);
  write_lds();
  __syncthreads();
  for (int k0 = kb; k0 < kend; k0 += 32){
    int nxt = k0 + 32;
    if (nxt < kend) load_regs(nxt);
    bf16x8 a0 = *(const bf16x8*)&As[(wr +      ln)*32 + quad*8];
    bf16x8 a1 = *(const bf16x8*)&As[(wr + 16 + ln)*32 + quad*8];
    bf16x8 b0 = *(const bf16x8*)&Bs[(wc +      ln)*32 + quad*8];
    bf16x8 b1 = *(const bf16x8*)&Bs[(wc + 16 + ln)*32 + quad*8];
    acc[0][0] = __builtin_amdgcn_mfma_f32_16x16x32_bf16(a0, b0, acc[0][0], 0, 0, 0);
    acc[0][1] = __builtin_amdgcn_mfma_f32_16x16x32_bf16(a0, b1, acc[0][1], 0, 0, 0);
    acc[1][0] = __builtin_amdgcn_mfma_f32_16x16x32_bf16(a1, b0, acc[1][0], 0, 0, 0);
    acc[1][1] = __builtin_amdgcn_mfma_f32_16x16x32_bf16(a1, b1, acc[1][1], 0, 0, 0);
    __syncthreads();
    if (nxt < kend){ write_lds(); __syncthreads(); }
  }

  float* Pout = P + (size_t)blockIdx.z*M*N;
  #pragma unroll
  for (int t = 0; t < 2; t++)
    #pragma unroll
    for (int u = 0; u < 2; u++)
      #pragma unroll
      for (int j = 0; j < 4; j++){
        int row = bm + wr + t*16 + quad*4 + j;
        int col = bn + wc + u*16 + ln;
        if (col < N) Pout[(size_t)row*N + col] = acc[t][u][j];
      }
}

// ---------------- fused: out = act(LN_last(sum_ks P + bias)); obf: write bf16 ----------------
__global__ __launch_bounds__(256) void reduce_ln(
    const float* __restrict__ Pp, const float* __restrict__ bias,
    void* __restrict__ outp, int M, int N, int KS, int os, int act, int obf)
{
  __shared__ float rowbuf[4096];
  __shared__ float sbuf[16];
  int row = blockIdx.x;
  size_t MN = (size_t)M*N;
  float s = 0.f, s2 = 0.f;
  for (int c = threadIdx.x; c < N; c += 256){
    float v = bias[c];
    for (int ks = 0; ks < KS; ks++) v += Pp[ks*MN + (size_t)row*N + c];
    rowbuf[c] = v; s += v; s2 += v*v;
  }
  block_reduce2(s, s2, sbuf);
  float m = s / N;
  float r = rsqrtf(s2/N - m*m + 1e-5f);
  for (int c = threadIdx.x; c < N; c += 256){
    float v = (rowbuf[c]-m)*r;
    if (act == 1) v = fmaxf(v, 0.f);
    else if (act == 2) v = eluf(v);
    else if (act == 3) v = tanhf(v);
    if (obf) ((short*)outp)[(size_t)row*os + c] = f2bf(v);
    else     ((float*)outp)[(size_t)row*os + c] = v;
  }
}

// ---------------- fused NS: XR bf16, state_out fp32 ----------------
__global__ __launch_bounds__(256) void reduce_ns(
    const float* __restrict__ Pp, const float* __restrict__ bias,
    short* __restrict__ XRb, float* __restrict__ so, int M, int N, int KS)
{
  __shared__ float rowbuf[256];
  __shared__ float sbuf[16];
  int row = blockIdx.x;
  size_t MN = (size_t)M*N;
  float s = 0.f, s2 = 0.f;
  for (int c = threadIdx.x; c < N; c += 256){
    float v = bias[c];
    for (int ks = 0; ks < KS; ks++) v += Pp[ks*MN + (size_t)row*N + c];
    rowbuf[c] = v; s += v; s2 += v*v;
  }
  block_reduce2(s, s2, sbuf);
  float m = s / N;
  float r = rsqrtf(s2/N - m*m + 1e-5f);
  for (int c = threadIdx.x; c < N; c += 256){
    float v = rowbuf[c];
    XRb[(size_t)row*256 + c] = f2bf(sigf((v-m)*r));
    so[(size_t)row*N + c] = sigf(v);
  }
}

// ---------------- enc_conv1: x(n,64,64) -> raw (n,32,32,16) + stats ----------------
__global__ __launch_bounds__(256) void enc_conv1_ig(
    const float* __restrict__ x, const float* __restrict__ w, const float* __restrict__ bias,
    float* __restrict__ outp, float* __restrict__ stat)
{
  __shared__ __align__(16) float in_t[66*68];
  __shared__ float sbuf[16];
  int n = blockIdx.x, tid = threadIdx.x;
  for (int l = tid; l < 66*68; l += 256) in_t[l] = 0.f;
  __syncthreads();
  const float* xin = x + (size_t)n*4096;
  for (int l4 = tid; l4 < 1024; l4 += 256){
    float4 v = *(const float4*)&xin[l4*4];
    int aa = (l4*4) >> 6, bb = (l4*4) & 63;
    float* dst = &in_t[(aa+1)*68 + bb + 1];
    dst[0]=v.x; dst[1]=v.y; dst[2]=v.z; dst[3]=v.w;
  }
  int o = tid & 15;
  float wr[16];
  #pragma unroll
  for (int t = 0; t < 16; t++) wr[t] = w[o*16 + t];
  float bv = bias[o];
  __syncthreads();
  float s = 0.f, s2 = 0.f;
  float* op = outp + (size_t)n*16384;
  for (int r = 0; r < 64; r++){
    int idx = tid + (r<<8);
    int bq = (idx>>4)&31, aq = idx>>9;
    int a0 = 2*aq, b0 = 2*bq;
    float acc = bv;
    #pragma unroll
    for (int kw = 0; kw < 4; kw++){
      const float* row = &in_t[(a0+kw)*68 + b0];
      float2 p0 = *(const float2*)&row[0];
      float2 p1 = *(const float2*)&row[2];
      acc += p0.x*wr[0*4+kw] + p0.y*wr[1*4+kw] + p1.x*wr[2*4+kw] + p1.y*wr[3*4+kw];
    }
    op[idx] = acc;
    s += acc; s2 += acc*acc;
  }
  block_reduce2(s, s2, sbuf);
  if (tid == 0){ atomicAdd(&stat[n*2], s); atomicAdd(&stat[n*2+1], s2); }
}

// ---------------- enc_conv2 MFMA implicit GEMM ----------------
__global__ __launch_bounds__(256) void enc_conv2_mfma(
    const float* __restrict__ in, const short* __restrict__ Bt, const float* __restrict__ bias,
    const float* __restrict__ stat_in, float* __restrict__ outp, float* __restrict__ stat)
{
  __shared__ __align__(16) short in_t[34*34*16];
  __shared__ float sbuf[16];
  int n = blockIdx.x, tid = threadIdx.x;
  float smv = stat_in[n*2], sqv = stat_in[n*2+1];
  float m = smv*(1.f/16384.f), rs = rsqrtf(sqv*(1.f/16384.f) - m*m + 1e-5f);
  for (int l = tid; l < 34*34*16/4; l += 256) ((unsigned long long*)in_t)[l] = 0ull;
  __syncthreads();
  const float* ip = in + (size_t)n*16384;
  for (int l = tid; l < 4096; l += 256){
    int i4 = l & 3, bb = (l>>2) & 31, aa = l>>7;
    float4 v = *(const float4*)&ip[aa*512 + bb*16 + i4*4];
    uint2 pk;
    pk.x = f2bf(eluf((v.x-m)*rs)) | ((unsigned)f2bf(eluf((v.y-m)*rs))<<16);
    pk.y = f2bf(eluf((v.z-m)*rs)) | ((unsigned)f2bf(eluf((v.w-m)*rs))<<16);
    *(uint2*)&in_t[((aa+1)*34 + (bb+1))*16 + i4*4] = pk;
  }
  int wave = tid>>6, ln = tid&15, quad = (tid>>4)&3;
  bf16x8 bfr[2][8];
  #pragma unroll
  for (int nt = 0; nt < 2; nt++){
    const short* Brow = Bt + (nt*16 + ln)*256;
    #pragma unroll
    for (int ks = 0; ks < 8; ks++)
      bfr[nt][ks] = *(const bf16x8*)&Brow[ks*32 + quad*8];
  }
  __syncthreads();
  f32x4 z = {0.f,0.f,0.f,0.f};
  f32x4 acc[2][4] = {{z,z,z,z},{z,z,z,z}};
  int tapq = quad>>1, io = (quad&1)*8;
  #pragma unroll
  for (int ks = 0; ks < 8; ks++){
    int t = 2*ks + tapq;
    int kh = t>>2, kw = t&3;
    #pragma unroll
    for (int mt = 0; mt < 4; mt++){
      int p = (wave*4 + mt)*16 + ln;
      int oa = p>>4, ob = p&15;
      bf16x8 a = *(const bf16x8*)&in_t[((2*oa+kw)*34 + (2*ob+kh))*16 + io];
      acc[0][mt] = __builtin_amdgcn_mfma_f32_16x16x32_bf16(a, bfr[0][ks], acc[0][mt],0,0,0);
      acc[1][mt] = __builtin_amdgcn_mfma_f32_16x16x32_bf16(a, bfr[1][ks], acc[1][mt],0,0,0);
    }
  }
  float s = 0.f, s2 = 0.f;
  float* op = outp + (size_t)n*8192;
  #pragma unroll
  for (int nt = 0; nt < 2; nt++){
    int o = nt*16 + ln;
    float bz = bias[o];
    #pragma unroll
    for (int mt = 0; mt < 4; mt++)
      #pragma unroll
      for (int j = 0; j < 4; j++){
        int p = (wave*4 + mt)*16 + quad*4 + j;
        float v = acc[nt][mt][j] + bz;
        s += v; s2 += v*v;
        int oa = p>>4, ob = p&15;
        op[oa*512 + ob*32 + o] = v;
      }
  }
  block_reduce2(s, s2, sbuf);
  if (tid == 0){ atomicAdd(&stat[n*2], s); atomicAdd(&stat[n*2+1], s2); }
}

// ---------------- enc_conv3 MFMA implicit GEMM ----------------
__global__ __launch_bounds__(256) void enc_conv3_mfma(
    const float* __restrict__ in, const short* __restrict__ Bt, const float* __restrict__ bias,
    const float* __restrict__ stat_in, float* __restrict__ outp, float* __restrict__ stat)
{
  __shared__ __align__(16) short in_t[18*18*32];
  __shared__ float sbuf[16];
  int n = blockIdx.x, tid = threadIdx.x;
  float smv = stat_in[n*2], sqv = stat_in[n*2+1];
  float m = smv*(1.f/8192.f), rs = rsqrtf(sqv*(1.f/8192.f) - m*m + 1e-5f);
  for (int l = tid; l < 18*18*32/4; l += 256) ((unsigned long long*)in_t)[l] = 0ull;
  __syncthreads();
  const float* ip = in + (size_t)n*8192;
  for (int l = tid; l < 2048; l += 256){
    int i4 = l & 7, bb = (l>>3)&15, aa = l>>7;
    float4 v = *(const float4*)&ip[aa*512 + bb*32 + i4*4];
    uint2 pk;
    pk.x = f2bf(eluf((v.x-m)*rs)) | ((unsigned)f2bf(eluf((v.y-m)*rs))<<16);
    pk.y = f2bf(eluf((v.z-m)*rs)) | ((unsigned)f2bf(eluf((v.w-m)*rs))<<16);
    *(uint2*)&in_t[((aa+1)*18 + (bb+1))*32 + i4*4] = pk;
  }
  int wave = tid>>6, ln = tid&15, quad = (tid>>4)&3;
  int o = wave*16 + ln;
  bf16x8 bfr[16];
  {
    const short* Brow = Bt + o*512;
    #pragma unroll
    for (int ks = 0; ks < 16; ks++)
      bfr[ks] = *(const bf16x8*)&Brow[ks*32 + quad*8];
  }
  __syncthreads();
  f32x4 z = {0.f,0.f,0.f,0.f};
  f32x4 acc[4] = {z,z,z,z};
  #pragma unroll
  for (int ks = 0; ks < 16; ks++){
    int kh = ks>>2, kw = ks&3;
    #pragma unroll
    for (int mt = 0; mt < 4; mt++){
      int p = mt*16 + ln;
      int oa = p>>3, ob = p&7;
      bf16x8 a = *(const bf16x8*)&in_t[((2*oa+kw)*18 + (2*ob+kh))*32 + quad*8];
      acc[mt] = __builtin_amdgcn_mfma_f32_16x16x32_bf16(a, bfr[ks], acc[mt],0,0,0);
    }
  }
  float s = 0.f, s2 = 0.f;
  float bz = bias[o];
  float* op = outp + (size_t)n*4096;
  #pragma unroll
  for (int mt = 0; mt < 4; mt++)
    #pragma unroll
    for (int j = 0; j < 4; j++){
      int p = mt*16 + quad*4 + j;
      int oa = p>>3, ob = p&7;
      float v = acc[mt][j] + bz;
      s += v; s2 += v*v;
      op[oa*512 + ob*64 + o] = v;
    }
  block_reduce2(s, s2, sbuf);
  if (tid == 0){ atomicAdd(&stat[n*2], s); atomicAdd(&stat[n*2+1], s2); }
}

// ---------------- dec_conv1 MFMA implicit GEMM (per-phase) ----------------
__global__ __launch_bounds__(256) void dec_conv1_mfma(
    const float* __restrict__ in, const short* __restrict__ Bd, const float* __restrict__ bias,
    float* __restrict__ outp, float* __restrict__ stat)
{
  __shared__ __align__(16) short in_t[10*10*64];
  __shared__ float sbuf[16];
  int n = blockIdx.x, tid = threadIdx.x;
  for (int l = tid; l < 10*10*64/4; l += 256) ((unsigned long long*)in_t)[l] = 0ull;
  __syncthreads();
  const float* ip = in + (size_t)n*4096;
  for (int l = tid; l < 1024; l += 256){
    int i4 = l & 15, sb = (l>>4)&7, sa = l>>7;
    float4 v = *(const float4*)&ip[sa*512 + sb*64 + i4*4];
    uint2 pk;
    pk.x = f2bf(v.x) | ((unsigned)f2bf(v.y)<<16);
    pk.y = f2bf(v.z) | ((unsigned)f2bf(v.w)<<16);
    *(uint2*)&in_t[((sa+1)*10 + (sb+1))*64 + i4*4] = pk;
  }
  int wave = tid>>6, ln = tid&15, quad = (tid>>4)&3;
  int pa = wave & 1, pb = wave >> 1;
  bf16x8 bfr[2][8];
  #pragma unroll
  for (int nt = 0; nt < 2; nt++){
    const short* Brow = Bd + (wave*32 + nt*16 + ln)*256;
    #pragma unroll
    for (int ks = 0; ks < 8; ks++)
      bfr[nt][ks] = *(const bf16x8*)&Brow[ks*32 + quad*8];
  }
  __syncthreads();
  f32x4 z = {0.f,0.f,0.f,0.f};
  f32x4 acc[2][4] = {{z,z,z,z},{z,z,z,z}};
  #pragma unroll
  for (int ks = 0; ks < 8; ks++){
    int tap = ks>>1, ibase = (ks&1)*32 + quad*8;
    int da = tap & 1, db = tap >> 1;
    #pragma unroll
    for (int mt = 0; mt < 4; mt++){
      int p = mt*16 + ln;
      int ta = p>>3, tb = p&7;
      bf16x8 a = *(const bf16x8*)&in_t[((ta+da+pa)*10 + (tb+db+pb))*64 + ibase];
      acc[0][mt] = __builtin_amdgcn_mfma_f32_16x16x32_bf16(a, bfr[0][ks], acc[0][mt],0,0,0);
      acc[1][mt] = __builtin_amdgcn_mfma_f32_16x16x32_bf16(a, bfr[1][ks], acc[1][mt],0,0,0);
    }
  }
  float s = 0.f, s2 = 0.f;
  float* op = outp + (size_t)n*8192;
  #pragma unroll
  for (int nt = 0; nt < 2; nt++){
    int o = nt*16 + ln;
    float bz = bias[o];
    #pragma unroll
    for (int mt = 0; mt < 4; mt++)
      #pragma unroll
      for (int j = 0; j < 4; j++){
        int p = mt*16 + quad*4 + j;
        int ta = p>>3, tb = p&7;
        float v = acc[nt][mt][j] + bz;
        s += v; s2 += v*v;
        op[(2*ta+pa)*512 + (2*tb+pb)*32 + o] = v;
      }
  }
  block_reduce2(s, s2, sbuf);
  if (tid == 0){ atomicAdd(&stat[n*2], s); atomicAdd(&stat[n*2+1], s2); }
}

// ---------------- dec_conv2 MFMA implicit GEMM (per-phase) ----------------
__global__ __launch_bounds__(256) void dec_conv2_mfma(
    const float* __restrict__ in, const short* __restrict__ Bd, const float* __restrict__ bias,
    const float* __restrict__ stat_in, float* __restrict__ outp, float* __restrict__ stat)
{
  __shared__ __align__(16) short in_t[18*18*32];
  __shared__ float sbuf[16];
  int n = blockIdx.x, tid = threadIdx.x;
  float smv = stat_in[n*2], sqv = stat_in[n*2+1];
  float m = smv*(1.f/8192.f), rs = rsqrtf(sqv*(1.f/8192.f) - m*m + 1e-5f);
  for (int l = tid; l < 18*18*32/4; l += 256) ((unsigned long long*)in_t)[l] = 0ull;
  __syncthreads();
  const float* ip = in + (size_t)n*8192;
  for (int l = tid; l < 2048; l += 256){
    int i4 = l & 7, sb = (l>>3)&15, sa = l>>7;
    float4 v = *(const float4*)&ip[sa*512 + sb*32 + i4*4];
    uint2 pk;
    pk.x = f2bf(fmaxf((v.x-m)*rs,0.f)) | ((unsigned)f2bf(fmaxf((v.y-m)*rs,0.f))<<16);
    pk.y = f2bf(fmaxf((v.z-m)*rs,0.f)) | ((unsigned)f2bf(fmaxf((v.w-m)*rs,0.f))<<16);
    *(uint2*)&in_t[((sa+1)*18 + (sb+1))*32 + i4*4] = pk;
  }
  int wave = tid>>6, ln = tid&15, quad = (tid>>4)&3;
  int pa = wave & 1, pb = wave >> 1;
  bf16x8 bfr[4];
  {
    const short* Brow = Bd + (wave*16 + ln)*128;
    #pragma unroll
    for (int ks = 0; ks < 4; ks++)
      bfr[ks] = *(const bf16x8*)&Brow[ks*32 + quad*8];
  }
  __syncthreads();
  f32x4 z = {0.f,0.f,0.f,0.f};
  f32x4 acc[16] = {z,z,z,z,z,z,z,z,z,z,z,z,z,z,z,z};
  #pragma unroll
  for (int ks = 0; ks < 4; ks++){
    int da = ks & 1, db = ks >> 1;
    #pragma unroll
    for (int mt = 0; mt < 16; mt++){
      int p = mt*16 + ln;
      int ta = p>>4, tb = p&15;
      bf16x8 a = *(const bf16x8*)&in_t[((ta+da+pa)*18 + (tb+db+pb))*32 + quad*8];
      acc[mt] = __builtin_amdgcn_mfma_f32_16x16x32_bf16(a, bfr[ks], acc[mt],0,0,0);
    }
  }
  float s = 0.f, s2 = 0.f;
  float bz = bias[ln];
  float* op = outp + (size_t)n*16384;
  #pragma unroll
  for (int mt = 0; mt < 16; mt++)
    #pragma unroll
    for (int j = 0; j < 4; j++){
      int p = mt*16 + quad*4 + j;
      int ta = p>>4, tb = p&15;
      float v = acc[mt][j] + bz;
      s += v; s2 += v*v;
      op[(2*ta+pa)*512 + (2*tb+pb)*16 + ln] = v;
    }
  block_reduce2(s, s2, sbuf);
  if (tid == 0){ atomicAdd(&stat[n*2], s); atomicAdd(&stat[n*2+1], s2); }
}

// ---------------- dec_conv3 ----------------
__global__ __launch_bounds__(256) void dec_conv3_ig(
    const float* __restrict__ in, const float* __restrict__ CWT, const float* __restrict__ bias,
    const float* __restrict__ stat_in, float* __restrict__ outp)
{
  __shared__ __align__(16) float in_t[9792];   // [sa34][sb18][i16]
  __shared__ __align__(16) float wl[256];
  int bx = blockIdx.x;
  int n = bx >> 1, b0 = (bx & 1) * 32, tb0 = b0 >> 1;
  int tid = threadIdx.x;
  float sm = stat_in[n*2], sq = stat_in[n*2+1];
  float m = sm*(1.f/16384.f), rs = rsqrtf(sq*(1.f/16384.f) - m*m + 1e-5f);
  const float* ip = in + (size_t)n*16384;
  for (int l = tid; l < 9792; l += 256){
    int i = l & 15, sb = (l >> 4) % 18, sap = l / 288;
    int sa = sap - 1, sbg = tb0 - 1 + sb;
    float v = 0.f;
    if ((unsigned)sa < 32u && (unsigned)sbg < 32u)
      v = fmaxf((ip[sa*512 + sbg*16 + i]-m)*rs, 0.f);
    in_t[(sap*18 + sb)*16 + i] = v;
  }
  for (int l = tid; l < 256; l += 256) wl[l] = CWT[l];
  __syncthreads();
  float bv = bias[0];
  int bl = tid & 31, ath = tid >> 5;
  int b = b0 + bl;
  int tb = b >> 1, pb = b & 1;
  float* op = outp + (size_t)n*4096;
  #pragma unroll
  for (int j = 0; j < 8; j++){
    int a = ath*8 + j;
    int ta = a >> 1, pa = a & 1;
    float4 s4 = make_float4(0.f,0.f,0.f,0.f);
    #pragma unroll
    for (int db = 0; db < 2; db++){
      int sb = tb + db + (pb ? 0 : -1);
      int sbl = sb - (tb0 - 1);
      #pragma unroll
      for (int da = 0; da < 2; da++){
        int sa = ta + da + (pa ? 0 : -1);
        int sap = sa + 1;
        const float4* A4 = (const float4*)&in_t[(sap*18 + sbl)*16];
        const float4* B4 = (const float4*)&wl[((pb*2+pa)*4 + db*2+da)*16];
        #pragma unroll
        for (int q = 0; q < 4; q++){
          float4 av = A4[q], bw = B4[q];
          s4.x += av.x*bw.x; s4.y += av.y*bw.y;
          s4.z += av.z*bw.z; s4.w += av.w*bw.w;
        }
      }
    }
    op[a*64 + b] = sigf(bv + s4.x + s4.y + s4.z + s4.w);
  }
}

// ---------------- pair build (bf16) ----------------
__global__ __launch_bounds__(256) void pair_build(const short* __restrict__ tot, short* __restrict__ P)
{
  int r = blockIdx.x;
  int jj = r % 7, fi = r / 7;
  int i = fi & 7, j = fi >> 3;
  int jidx = jj < i ? jj : jj+1;
  const short* srcf = tot + (size_t)fi*1024;
  const short* srco = tot + (size_t)(j*8+jidx)*1024;
  short* op = P + (size_t)r*512;
  for (int c = threadIdx.x; c < 250; c += blockDim.x){
    op[c] = srcf[c];
    op[250+c] = srco[c];
  }
  if (threadIdx.x < 12) op[500 + threadIdx.x] = 0;   // zero K-pad
}

// ---------------- att2 ----------------
__global__ void att2_kernel(const float* __restrict__ A1, const float* __restrict__ w,
                            const float* __restrict__ b, float* __restrict__ att)
{
  int r = blockIdx.x*blockDim.x + threadIdx.x;
  if (r >= 2688) return;
  const float* ip = A1 + (size_t)r*100;
  float a = b[0];
  for (int c = 0; c < 100; c++) a += ip[c]*w[c];
  att[r] = sigf(a);
}

// ---------------- effect (bf16 out into TOT) ----------------
__global__ __launch_bounds__(256) void effect_kernel(const float* __restrict__ X1,
    const float* __restrict__ att, short* __restrict__ tot)
{
  int row = blockIdx.x;
  for (int h = threadIdx.x; h < 250; h += blockDim.x){
    float s = 0.f;
    for (int jj = 0; jj < 7; jj++)
      s += X1[((size_t)row*7+jj)*250 + h] * att[row*7+jj];
    tot[(size_t)row*1024 + 250 + h] = f2bf(s);
  }
}

extern "C" void kernel_launch(void* const* d_in, const int* in_sizes, int n_in,
                              void* d_out, int out_size, void* d_ws, size_t ws_size,
                              hipStream_t stream) {
  const float* x      = (const float*)d_in[0];
  const float* state  = (const float*)d_in[1];
  const float* c1w    = (const float*)d_in[2];
  const float* c1b    = (const float*)d_in[3];
  const float* c2w    = (const float*)d_in[4];
  const float* c2b    = (const float*)d_in[5];
  const float* c3w    = (const float*)d_in[6];
  const float* c3b    = (const float*)d_in[7];
  const float* efc_w  = (const float*)d_in[8];
  const float* efc_b  = (const float*)d_in[9];
  const float* renc_w = (const float*)d_in[10];
  const float* renc_b = (const float*)d_in[11];
  const float* core_w = (const float*)d_in[12];
  const float* core_b = (const float*)d_in[13];
  const float* ctx_w  = (const float*)d_in[14];
  const float* ctx_b  = (const float*)d_in[15];
  const float* att1_w = (const float*)d_in[16];
  const float* att1_b = (const float*)d_in[17];
  const float* att2_w = (const float*)d_in[18];
  const float* att2_b = (const float*)d_in[19];
  const float* out_w  = (const float*)d_in[20];
  const float* out_b  = (const float*)d_in[21];
  const float* dfc1_w = (const float*)d_in[22];
  const float* dfc1_b = (const float*)d_in[23];
  const float* dfc2_w = (const float*)d_in[24];
  const float* dfc2_b = (const float*)d_in[25];
  const float* d1w    = (const float*)d_in[26];
  const float* d1b    = (const float*)d_in[27];
  const float* d2w    = (const float*)d_in[28];
  const float* d2b    = (const float*)d_in[29];
  const float* d3w    = (const float*)d_in[30];
  const float* d3b    = (const float*)d_in[31];

  float* wsf = (float*)d_ws;
  size_t o = 0;
  float* E1  = wsf + o; o += (size_t)384*16384;   // enc1 raw; later PB, dec2 raw out
  float* E2  = wsf + o; o += (size_t)384*8192;    // enc2 raw; later dec1 raw
  float* E3  = wsf + o; o += (size_t)384*4096;    // enc3 raw; later G2
  float* X1  = wsf + o; o += (size_t)2688*250;
  float* A1  = wsf + o; o += (size_t)2688*100;
  float* ATT = wsf + o; o += 2688;
  float* CWT3 = wsf + o; o += 256;
  float* STAT = wsf + o; o += 5*384*2;
  // bf16 buffers (sizes in shorts; offsets in floats)
  short* TOTb = (short*)(wsf + o); o += (size_t)384*1024/2;
  short* Prb  = (short*)(wsf + o); o += (size_t)2688*512/2;
  short* C1b  = (short*)(wsf + o); o += (size_t)2688*256/2;
  short* XRb  = (short*)(wsf + o); o += (size_t)384*256/2;
  short* G1b  = (short*)(wsf + o); o += (size_t)384*512/2;
  short* ECV  = (short*)(wsf + o); o += (size_t)384*4096/2;
  short* SBF  = (short*)(wsf + o); o += (size_t)384*256/2;
  short* BtC2 = (short*)(wsf + o); o += 8192/2;
  short* BtC3 = (short*)(wsf + o); o += 32768/2;
  short* BD1  = (short*)(wsf + o); o += 32768/2;
  short* BD2  = (short*)(wsf + o); o += 8192/2;
  short* BT_efc  = (short*)(wsf + o); o += 2097152/2;
  short* BT_renc = (short*)(wsf + o); o += 64000/2;
  short* BT_core = (short*)(wsf + o); o += 128000/2;
  short* BT_ctx  = (short*)(wsf + o); o += 64000/2;
  short* BT_att1 = (short*)(wsf + o); o += 25600/2;
  short* BT_out  = (short*)(wsf + o); o += 256000/2;
  short* BT_dfc1 = (short*)(wsf + o); o += 131072/2;
  short* BT_dfc2 = (short*)(wsf + o); o += 2097152/2;
  float* PB  = E1;
  float* D1O = E2;
  float* D2O = E1;
  float* G2  = E3;

  float* xout = (float*)d_out;
  float* sout = xout + (size_t)384*4096;

  // fused prep: stats zero + folds + bf16 weight packing + state cvt
  prep_all<<<1024, 256, 0, stream>>>(STAT,
      d3w, CWT3, c2w, BtC2, c3w, BtC3, d1w, BD1, d2w, BD2,
      efc_w, BT_efc, renc_w, BT_renc, core_w, BT_core, ctx_w, BT_ctx,
      att1_w, BT_att1, out_w, BT_out, dfc1_w, BT_dfc1, dfc2_w, BT_dfc2,
      state, SBF);

  // encoder
  enc_conv1_ig<<<384, 256, 0, stream>>>(x, c1w, c1b, E1, STAT + ST_ENC1*768);
  enc_conv2_mfma<<<384, 256, 0, stream>>>(E1, BtC2, c2b, STAT + ST_ENC1*768, E2, STAT + ST_ENC2*768);
  enc_conv3_mfma<<<384, 256, 0, stream>>>(E2, BtC3, c3b, STAT + ST_ENC2*768, E3, STAT + ST_ENC3*768);
  cvt_ln_elu<<<384, 256, 0, stream>>>(E3, STAT + ST_ENC3*768, ECV);
  gemm_mfma<<<dim3(8,6,8), 256, 0, stream>>>(ECV, BT_efc, PB, 384, 512, 4096, 512);
  reduce_ln<<<384, 256, 0, stream>>>(PB, efc_b, TOTb+500, 384, 512, 8, 1024, 2, 1);

  // state path
  gemm_mfma<<<dim3(4,6,8), 256, 0, stream>>>(SBF, BT_renc, PB, 384, 250, 256, 32);
  reduce_ln<<<384, 256, 0, stream>>>(PB, renc_b, TOTb, 384, 250, 8, 1024, 1, 1);
  pair_build<<<2688, 256, 0, stream>>>(TOTb, Prb);
  gemm_mfma<<<dim3(4,42,2), 256, 0, stream>>>(Prb, BT_core, PB, 2688, 250, 512, 256);
  reduce_ln<<<2688, 256, 0, stream>>>(PB, core_b, C1b, 2688, 250, 2, 256, 1, 1);
  gemm_mfma<<<dim3(4,42,2), 256, 0, stream>>>(C1b, BT_ctx, PB, 2688, 250, 256, 128);
  reduce_ln<<<2688, 256, 0, stream>>>(PB, ctx_b, X1, 2688, 250, 2, 250, 1, 0);
  gemm_mfma<<<dim3(2,42,4), 256, 0, stream>>>(C1b, BT_att1, PB, 2688, 100, 256, 64);
  reduce_ln<<<2688, 256, 0, stream>>>(PB, att1_b, A1, 2688, 100, 4, 100, 3, 0);
  att2_kernel<<<11, 256, 0, stream>>>(A1, att2_w, att2_b, ATT);
  effect_kernel<<<384, 256, 0, stream>>>(X1, ATT, TOTb);

  // combine
  gemm_mfma<<<dim3(4,6,8), 256, 0, stream>>>(TOTb, BT_out, PB, 384, 250, 1024, 128);
  reduce_ns<<<384, 256, 0, stream>>>(PB, out_b, XRb, sout, 384, 250, 8);

  // decoder FC
  gemm_mfma<<<dim3(8,6,4), 256, 0, stream>>>(XRb, BT_dfc1, PB, 384, 512, 256, 64);
  reduce_ln<<<384, 256, 0, stream>>>(PB, dfc1_b, G1b, 384, 512, 4, 512, 1, 1);
  gemm_mfma<<<dim3(64,6,1), 256, 0, stream>>>(G1b, BT_dfc2, PB, 384, 4096, 512, 512);
  reduce_ln<<<384, 256, 0, stream>>>(PB, dfc2_b, G2, 384, 4096, 1, 4096, 1, 0);

  // decoder convs
  dec_conv1_mfma<<<384, 256, 0, stream>>>(G2, BD1, d1b, D1O, STAT + ST_DEC1*768);
  dec_conv2_mfma<<<384, 256, 0, stream>>>(D1O, BD2, d2b, STAT + ST_DEC1*768, D2O, STAT + ST_DEC2*768);
  dec_conv3_ig<<<768, 256, 0, stream>>>(D2O, CWT3, d3b, STAT + ST_DEC2*768, xout);

  (void)in_sizes; (void)n_in; (void)out_size; (void)ws_size;
}

// Round 9
// 353.340 us; speedup vs baseline: 6.2480x; 1.0517x over previous
//
#include <hip/hip_runtime.h>
#include <hip/hip_bf16.h>
#include <math.h>

// stats slots (sum,sumsq per sample), 384 samples each
#define ST_ENC2 0
#define ST_ENC3 1
#define ST_DEC1 2
#define ST_DEC2 3
#define ST_ENC1 4

typedef __attribute__((ext_vector_type(8))) short bf16x8;
typedef __attribute__((ext_vector_type(4))) float f32x4;

__device__ __forceinline__ float eluf(float v){ return v > 0.f ? v : expm1f(v); }
__device__ __forceinline__ float sigf(float v){ return 1.f/(1.f+expf(-v)); }
__device__ __forceinline__ unsigned short f2bf(float f){
  unsigned u = __float_as_uint(f);
  u += 0x7FFFu + ((u >> 16) & 1u);          // round-to-nearest-even
  return (unsigned short)(u >> 16);
}
__device__ __forceinline__ float bf2f(short s){
  return __uint_as_float(((unsigned)(unsigned short)s) << 16);
}

// ---------------- block-wide sum & sumsq reduction ----------------
__device__ __forceinline__ void block_reduce2(float& a, float& b, float* sbuf){
  __syncthreads();
  for (int off = 32; off; off >>= 1){
    a += __shfl_down(a, off);
    b += __shfl_down(b, off);
  }
  int lane = threadIdx.x & 63, w = threadIdx.x >> 6;
  if (lane == 0){ sbuf[2*w] = a; sbuf[2*w+1] = b; }
  __syncthreads();
  if (threadIdx.x == 0){
    int nw = blockDim.x >> 6;
    float sa = 0.f, sb = 0.f;
    for (int i = 0; i < nw; i++){ sa += sbuf[2*i]; sb += sbuf[2*i+1]; }
    sbuf[0] = sa; sbuf[1] = sb;
  }
  __syncthreads();
  a = sbuf[0]; b = sbuf[1];
}

// ---------------- prep helpers ----------------
__device__ __forceinline__ float fold_sum(const float* __restrict__ w, int O, int I,
                                          int o, int i, int pa, int pb, int da, int db){
  float s = 0.f;
  for (int kh = 0; kh < 4; kh++){
    bool inh = (pb==0) ? (db==0 ? (kh==0) : (kh>=1)) : (db==0 ? (kh<=2) : (kh==3));
    if (!inh) continue;
    for (int kw = 0; kw < 4; kw++){
      bool inw = (pa==0) ? (da==0 ? (kw==0) : (kw>=1)) : (da==0 ? (kw<=2) : (kw==3));
      if (!inw) continue;
      s += w[((o*I + i)*4 + kh)*4 + kw];
    }
  }
  return s;
}
__device__ __forceinline__ void fold_elem(const float* __restrict__ w, float* __restrict__ CW,
                                          int O, int I, int l){
  int o = l % O; int q = l / O;
  int da = q & 1, db = (q>>1)&1, pa = (q>>2)&1, pb = (q>>3)&1, i = q>>4;
  CW[(((pb*2+pa)*4 + db*2+da)*I + i)*O + o] = fold_sum(w, O, I, o, i, pa, pb, da, db);
}
__device__ __forceinline__ void cvtc2_elem(const float* __restrict__ w, short* __restrict__ D, int l){
  int i = l & 15, t = (l>>4) & 15, o = l>>8;        // k = t*16 + i
  D[l] = (short)f2bf(w[(o*16 + i)*16 + t]);
}
__device__ __forceinline__ void cvtc3_elem(const float* __restrict__ w, short* __restrict__ D, int l){
  int i = l & 31, t = (l>>5) & 15, o = l>>9;        // k = t*32 + i
  D[l] = (short)f2bf(w[(o*32 + i)*16 + t]);
}
__device__ __forceinline__ void foldd1_elem(const float* __restrict__ w, short* __restrict__ D, int l){
  int i = l & 63, tap = (l>>6)&3, o = (l>>8)&31, ph = l>>13;
  D[l] = (short)f2bf(fold_sum(w, 32, 64, o, i, ph&1, ph>>1, tap&1, tap>>1));
}
__device__ __forceinline__ void foldd2_elem(const float* __restrict__ w, short* __restrict__ D, int l){
  int i = l & 31, tap = (l>>5)&3, o = (l>>7)&15, ph = l>>11;
  D[l] = (short)f2bf(fold_sum(w, 16, 32, o, i, ph&1, ph>>1, tap&1, tap>>1));
}

// ---------------- small prep (folds, conv weight packs, stats zero, state cvt) ----------------
__global__ __launch_bounds__(256) void prep_all(
  float* __restrict__ stat,
  const float* __restrict__ d3w, float* __restrict__ CWT3,
  const float* __restrict__ c2w, short* __restrict__ BtC2,
  const float* __restrict__ c3w, short* __restrict__ BtC3,
  const float* __restrict__ d1w, short* __restrict__ BD1,
  const float* __restrict__ d2w, short* __restrict__ BD2,
  const float* __restrict__ state, short* __restrict__ SBF)
{
  const int S0=3840, F3=S0+256, P2=F3+8192, P3=P2+32768, P4=P3+32768, P5=P4+8192,
            TOTAL=P5+98304;
  for (int l = blockIdx.x*blockDim.x + threadIdx.x; l < TOTAL; l += gridDim.x*blockDim.x){
    if (l < S0)      stat[l] = 0.f;
    else if (l < F3) fold_elem(d3w, CWT3, 1, 16, l - S0);
    else if (l < P2) cvtc2_elem(c2w, BtC2, l - F3);
    else if (l < P3) cvtc3_elem(c3w, BtC3, l - P2);
    else if (l < P4) foldd1_elem(d1w, BD1, l - P3);
    else if (l < P5) foldd2_elem(d2w, BD2, l - P4);
    else {
      int q = l - P5;             // state -> bf16 [384][256], zero pad
      int n = q >> 8, k = q & 255;
      SBF[q] = (k < 250) ? (short)f2bf(state[n*250 + k]) : (short)0;
    }
  }
}

// ---------------- coalesced transpose-convert: W[K][N] -> D[N][Kp] bf16 ----------------
// 64x64 LDS tiles; grid = 1192 blocks covering 8 matrices.
__global__ __launch_bounds__(256) void transpose_cvt_all(
  const float* __restrict__ efc,  short* __restrict__ Defc,
  const float* __restrict__ dfc2, short* __restrict__ Ddfc2,
  const float* __restrict__ outw, short* __restrict__ Dout,
  const float* __restrict__ corew,short* __restrict__ Dcore,
  const float* __restrict__ dfc1, short* __restrict__ Ddfc1,
  const float* __restrict__ renc, short* __restrict__ Drenc,
  const float* __restrict__ ctx,  short* __restrict__ Dctx,
  const float* __restrict__ att1, short* __restrict__ Datt1)
{
  int bx = blockIdx.x;
  const float* W; short* D; int K, N, Kp, base;
  if      (bx < 512) { W=efc;  D=Defc;  K=4096; N=512;  Kp=4096; base=0;    }
  else if (bx < 1024){ W=dfc2; D=Ddfc2; K=512;  N=4096; Kp=512;  base=512;  }
  else if (bx < 1088){ W=outw; D=Dout;  K=1012; N=250;  Kp=1024; base=1024; }
  else if (bx < 1120){ W=corew;D=Dcore; K=500;  N=250;  Kp=512;  base=1088; }
  else if (bx < 1152){ W=dfc1; D=Ddfc1; K=250;  N=512;  Kp=256;  base=1120; }
  else if (bx < 1168){ W=renc; D=Drenc; K=250;  N=250;  Kp=256;  base=1152; }
  else if (bx < 1184){ W=ctx;  D=Dctx;  K=250;  N=250;  Kp=256;  base=1168; }
  else               { W=att1; D=Datt1; K=250;  N=100;  Kp=256;  base=1184; }
  int t = bx - base;
  int tpr = Kp >> 6;
  int tk = t % tpr, tn = t / tpr;
  __shared__ short tile[64][65];
  int c = threadIdx.x & 63, r4 = threadIdx.x >> 6;
  int n0 = tn*64, k0 = tk*64;
  #pragma unroll 4
  for (int p = 0; p < 16; p++){
    int r = r4*16 + p;
    int k = k0 + r, n = n0 + c;
    float v = (k < K && n < N) ? W[(size_t)k*N + n] : 0.f;
    tile[c][r] = (short)f2bf(v);
  }
  __syncthreads();
  #pragma unroll 4
  for (int p = 0; p < 16; p++){
    int nn = r4*16 + p;
    int n = n0 + nn;
    if (n < N) D[(size_t)n*Kp + k0 + c] = tile[nn][c];
  }
}

// ---------------- cvt_ln_elu: E3 raw bf16 + stats -> bf16 elu(LN) [384][4096] ----------------
__global__ __launch_bounds__(256) void cvt_ln_elu(
    const short* __restrict__ inb, const float* __restrict__ stat, short* __restrict__ outb)
{
  int n = blockIdx.x, tid = threadIdx.x;
  float sm = stat[n*2], sq = stat[n*2+1];
  float m = sm*(1.f/4096.f), rs = rsqrtf(sq*(1.f/4096.f) - m*m + 1e-5f);
  const short* ip = inb + (size_t)n*4096;
  short* op = outb + (size_t)n*4096;
  for (int l = tid*4; l < 4096; l += 1024){
    uint2 rv = *(const uint2*)&ip[l];
    float v0 = bf2f((short)(rv.x & 0xFFFF)), v1 = bf2f((short)(rv.x >> 16));
    float v2 = bf2f((short)(rv.y & 0xFFFF)), v3 = bf2f((short)(rv.y >> 16));
    uint2 pk;
    pk.x = f2bf(eluf((v0-m)*rs)) | ((unsigned)f2bf(eluf((v1-m)*rs))<<16);
    pk.y = f2bf(eluf((v2-m)*rs)) | ((unsigned)f2bf(eluf((v3-m)*rs))<<16);
    *(uint2*)&op[l] = pk;
  }
}

// ---------------- MFMA bf16 split-K GEMM, bf16 A ----------------
__global__ __launch_bounds__(256) void gemm_mfma(
    const short* __restrict__ Ab, const short* __restrict__ Bt,
    float* __restrict__ P, int M, int N, int Kp, int Kc)
{
  __shared__ __align__(16) short As[64*32];
  __shared__ __align__(16) short Bs[64*32];
  int tid = threadIdx.x;
  int bm = blockIdx.y*64, bn = blockIdx.x*64;
  int kb = blockIdx.z * Kc;
  int kend = kb + Kc;

  int r = tid >> 2, c = tid & 3;
  const short* Arow = Ab + (size_t)(bm + r)*Kp;
  int gn = bn + r;
  bool bval = gn < N;
  const short* Brow = Bt + (size_t)gn*Kp;

  uint4 hA, hB;
  auto load_regs = [&](int k0){
    hA = *(const uint4*)&Arow[k0 + c*8];
    hB = bval ? *(const uint4*)&Brow[k0 + c*8] : make_uint4(0,0,0,0);
  };
  auto write_lds = [&](){
    *(uint4*)&As[r*32 + c*8] = hA;
    *(uint4*)&Bs[r*32 + c*8] = hB;
  };

  int wave = tid >> 6;
  int ln = tid & 15, quad = (tid >> 4) & 3;
  int wr = (wave >> 1) * 32, wc = (wave & 1) * 32;

  f32x4 zero = {0.f, 0.f, 0.f, 0.f};
  f32x4 acc[2][2] = {{zero, zero}, {zero, zero}};

  load_regs(kb);
  write_lds();
  __syncthreads();
  for (int k0 = kb; k0 < kend; k0 += 32){
    int nxt = k0 + 32;
    if (nxt < kend) load_regs(nxt);
    bf16x8 a0 = *(const bf16x8*)&As[(wr +      ln)*32 + quad*8];
    bf16x8 a1 = *(const bf16x8*)&As[(wr + 16 + ln)*32 + quad*8];
    bf16x8 b0 = *(const bf16x8*)&Bs[(wc +      ln)*32 + quad*8];
    bf16x8 b1 = *(const bf16x8*)&Bs[(wc + 16 + ln)*32 + quad*8];
    acc[0][0] = __builtin_amdgcn_mfma_f32_16x16x32_bf16(a0, b0, acc[0][0], 0, 0, 0);
    acc[0][1] = __builtin_amdgcn_mfma_f32_16x16x32_bf16(a0, b1, acc[0][1], 0, 0, 0);
    acc[1][0] = __builtin_amdgcn_mfma_f32_16x16x32_bf16(a1, b0, acc[1][0], 0, 0, 0);
    acc[1][1] = __builtin_amdgcn_mfma_f32_16x16x32_bf16(a1, b1, acc[1][1], 0, 0, 0);
    __syncthreads();
    if (nxt < kend){ write_lds(); __syncthreads(); }
  }

  float* Pout = P + (size_t)blockIdx.z*M*N;
  #pragma unroll
  for (int t = 0; t < 2; t++)
    #pragma unroll
    for (int u = 0; u < 2; u++)
      #pragma unroll
      for (int j = 0; j < 4; j++){
        int row = bm + wr + t*16 + quad*4 + j;
        int col = bn + wc + u*16 + ln;
        if (col < N) Pout[(size_t)row*N + col] = acc[t][u][j];
      }
}

// ---------------- fused: out = act(LN_last(sum_ks P + bias)); obf: write bf16 ----------------
__global__ __launch_bounds__(256) void reduce_ln(
    const float* __restrict__ Pp, const float* __restrict__ bias,
    void* __restrict__ outp, int M, int N, int KS, int os, int act, int obf)
{
  __shared__ float rowbuf[4096];
  __shared__ float sbuf[16];
  int row = blockIdx.x;
  size_t MN = (size_t)M*N;
  float s = 0.f, s2 = 0.f;
  for (int c = threadIdx.x; c < N; c += 256){
    float v = bias[c];
    for (int ks = 0; ks < KS; ks++) v += Pp[ks*MN + (size_t)row*N + c];
    rowbuf[c] = v; s += v; s2 += v*v;
  }
  block_reduce2(s, s2, sbuf);
  float m = s / N;
  float r = rsqrtf(s2/N - m*m + 1e-5f);
  for (int c = threadIdx.x; c < N; c += 256){
    float v = (rowbuf[c]-m)*r;
    if (act == 1) v = fmaxf(v, 0.f);
    else if (act == 2) v = eluf(v);
    else if (act == 3) v = tanhf(v);
    if (obf) ((short*)outp)[(size_t)row*os + c] = f2bf(v);
    else     ((float*)outp)[(size_t)row*os + c] = v;
  }
}

// ---------------- fused NS: XR bf16, state_out fp32 ----------------
__global__ __launch_bounds__(256) void reduce_ns(
    const float* __restrict__ Pp, const float* __restrict__ bias,
    short* __restrict__ XRb, float* __restrict__ so, int M, int N, int KS)
{
  __shared__ float rowbuf[256];
  __shared__ float sbuf[16];
  int row = blockIdx.x;
  size_t MN = (size_t)M*N;
  float s = 0.f, s2 = 0.f;
  for (int c = threadIdx.x; c < N; c += 256){
    float v = bias[c];
    for (int ks = 0; ks < KS; ks++) v += Pp[ks*MN + (size_t)row*N + c];
    rowbuf[c] = v; s += v; s2 += v*v;
  }
  block_reduce2(s, s2, sbuf);
  float m = s / N;
  float r = rsqrtf(s2/N - m*m + 1e-5f);
  for (int c = threadIdx.x; c < N; c += 256){
    float v = rowbuf[c];
    XRb[(size_t)row*256 + c] = f2bf(sigf((v-m)*r));
    so[(size_t)row*N + c] = sigf(v);
  }
}

// ---------------- enc_conv1: x(n,64,64) -> raw bf16 (n,32,32,16) + stats ----------------
__global__ __launch_bounds__(256) void enc_conv1_ig(
    const float* __restrict__ x, const float* __restrict__ w, const float* __restrict__ bias,
    short* __restrict__ outp, float* __restrict__ stat)
{
  __shared__ __align__(16) float in_t[66*68];
  __shared__ float sbuf[16];
  int n = blockIdx.x, tid = threadIdx.x;
  for (int l = tid; l < 66*68; l += 256) in_t[l] = 0.f;
  __syncthreads();
  const float* xin = x + (size_t)n*4096;
  for (int l4 = tid; l4 < 1024; l4 += 256){
    float4 v = *(const float4*)&xin[l4*4];
    int aa = (l4*4) >> 6, bb = (l4*4) & 63;
    float* dst = &in_t[(aa+1)*68 + bb + 1];
    dst[0]=v.x; dst[1]=v.y; dst[2]=v.z; dst[3]=v.w;
  }
  int o = tid & 15;
  float wr[16];
  #pragma unroll
  for (int t = 0; t < 16; t++) wr[t] = w[o*16 + t];
  float bv = bias[o];
  __syncthreads();
  float s = 0.f, s2 = 0.f;
  short* op = outp + (size_t)n*16384;
  for (int r = 0; r < 64; r++){
    int idx = tid + (r<<8);
    int bq = (idx>>4)&31, aq = idx>>9;
    int a0 = 2*aq, b0 = 2*bq;
    float acc = bv;
    #pragma unroll
    for (int kw = 0; kw < 4; kw++){
      const float* row = &in_t[(a0+kw)*68 + b0];
      float2 p0 = *(const float2*)&row[0];
      float2 p1 = *(const float2*)&row[2];
      acc += p0.x*wr[0*4+kw] + p0.y*wr[1*4+kw] + p1.x*wr[2*4+kw] + p1.y*wr[3*4+kw];
    }
    op[idx] = f2bf(acc);
    s += acc; s2 += acc*acc;
  }
  block_reduce2(s, s2, sbuf);
  if (tid == 0){ atomicAdd(&stat[n*2], s); atomicAdd(&stat[n*2+1], s2); }
}

// ---------------- enc_conv2 MFMA implicit GEMM (bf16 in/out) ----------------
__global__ __launch_bounds__(256) void enc_conv2_mfma(
    const short* __restrict__ in, const short* __restrict__ Bt, const float* __restrict__ bias,
    const float* __restrict__ stat_in, short* __restrict__ outp, float* __restrict__ stat)
{
  __shared__ __align__(16) short in_t[34*34*16];
  __shared__ float sbuf[16];
  int n = blockIdx.x, tid = threadIdx.x;
  float smv = stat_in[n*2], sqv = stat_in[n*2+1];
  float m = smv*(1.f/16384.f), rs = rsqrtf(sqv*(1.f/16384.f) - m*m + 1e-5f);
  for (int l = tid; l < 34*34*16/4; l += 256) ((unsigned long long*)in_t)[l] = 0ull;
  __syncthreads();
  const short* ip = in + (size_t)n*16384;
  for (int l = tid; l < 4096; l += 256){
    int i4 = l & 3, bb = (l>>2) & 31, aa = l>>7;
    uint2 rv = *(const uint2*)&ip[aa*512 + bb*16 + i4*4];
    float v0 = bf2f((short)(rv.x & 0xFFFF)), v1 = bf2f((short)(rv.x >> 16));
    float v2 = bf2f((short)(rv.y & 0xFFFF)), v3 = bf2f((short)(rv.y >> 16));
    uint2 pk;
    pk.x = f2bf(eluf((v0-m)*rs)) | ((unsigned)f2bf(eluf((v1-m)*rs))<<16);
    pk.y = f2bf(eluf((v2-m)*rs)) | ((unsigned)f2bf(eluf((v3-m)*rs))<<16);
    *(uint2*)&in_t[((aa+1)*34 + (bb+1))*16 + i4*4] = pk;
  }
  int wave = tid>>6, ln = tid&15, quad = (tid>>4)&3;
  bf16x8 bfr[2][8];
  #pragma unroll
  for (int nt = 0; nt < 2; nt++){
    const short* Brow = Bt + (nt*16 + ln)*256;
    #pragma unroll
    for (int ks = 0; ks < 8; ks++)
      bfr[nt][ks] = *(const bf16x8*)&Brow[ks*32 + quad*8];
  }
  __syncthreads();
  f32x4 z = {0.f,0.f,0.f,0.f};
  f32x4 acc[2][4] = {{z,z,z,z},{z,z,z,z}};
  int tapq = quad>>1, io = (quad&1)*8;
  #pragma unroll
  for (int ks = 0; ks < 8; ks++){
    int t = 2*ks + tapq;
    int kh = t>>2, kw = t&3;
    #pragma unroll
    for (int mt = 0; mt < 4; mt++){
      int p = (wave*4 + mt)*16 + ln;
      int oa = p>>4, ob = p&15;
      bf16x8 a = *(const bf16x8*)&in_t[((2*oa+kw)*34 + (2*ob+kh))*16 + io];
      acc[0][mt] = __builtin_amdgcn_mfma_f32_16x16x32_bf16(a, bfr[0][ks], acc[0][mt],0,0,0);
      acc[1][mt] = __builtin_amdgcn_mfma_f32_16x16x32_bf16(a, bfr[1][ks], acc[1][mt],0,0,0);
    }
  }
  float s = 0.f, s2 = 0.f;
  short* op = outp + (size_t)n*8192;
  #pragma unroll
  for (int nt = 0; nt < 2; nt++){
    int o = nt*16 + ln;
    float bz = bias[o];
    #pragma unroll
    for (int mt = 0; mt < 4; mt++)
      #pragma unroll
      for (int j = 0; j < 4; j++){
        int p = (wave*4 + mt)*16 + quad*4 + j;
        float v = acc[nt][mt][j] + bz;
        s += v; s2 += v*v;
        int oa = p>>4, ob = p&15;
        op[oa*512 + ob*32 + o] = f2bf(v);
      }
  }
  block_reduce2(s, s2, sbuf);
  if (tid == 0){ atomicAdd(&stat[n*2], s); atomicAdd(&stat[n*2+1], s2); }
}

// ---------------- enc_conv3 MFMA implicit GEMM (bf16 in/out) ----------------
__global__ __launch_bounds__(256) void enc_conv3_mfma(
    const short* __restrict__ in, const short* __restrict__ Bt, const float* __restrict__ bias,
    const float* __restrict__ stat_in, short* __restrict__ outp, float* __restrict__ stat)
{
  __shared__ __align__(16) short in_t[18*18*32];
  __shared__ float sbuf[16];
  int n = blockIdx.x, tid = threadIdx.x;
  float smv = stat_in[n*2], sqv = stat_in[n*2+1];
  float m = smv*(1.f/8192.f), rs = rsqrtf(sqv*(1.f/8192.f) - m*m + 1e-5f);
  for (int l = tid; l < 18*18*32/4; l += 256) ((unsigned long long*)in_t)[l] = 0ull;
  __syncthreads();
  const short* ip = in + (size_t)n*8192;
  for (int l = tid; l < 2048; l += 256){
    int i4 = l & 7, bb = (l>>3)&15, aa = l>>7;
    uint2 rv = *(const uint2*)&ip[aa*512 + bb*32 + i4*4];
    float v0 = bf2f((short)(rv.x & 0xFFFF)), v1 = bf2f((short)(rv.x >> 16));
    float v2 = bf2f((short)(rv.y & 0xFFFF)), v3 = bf2f((short)(rv.y >> 16));
    uint2 pk;
    pk.x = f2bf(eluf((v0-m)*rs)) | ((unsigned)f2bf(eluf((v1-m)*rs))<<16);
    pk.y = f2bf(eluf((v2-m)*rs)) | ((unsigned)f2bf(eluf((v3-m)*rs))<<16);
    *(uint2*)&in_t[((aa+1)*18 + (bb+1))*32 + i4*4] = pk;
  }
  int wave = tid>>6, ln = tid&15, quad = (tid>>4)&3;
  int o = wave*16 + ln;
  bf16x8 bfr[16];
  {
    const short* Brow = Bt + o*512;
    #pragma unroll
    for (int ks = 0; ks < 16; ks++)
      bfr[ks] = *(const bf16x8*)&Brow[ks*32 + quad*8];
  }
  __syncthreads();
  f32x4 z = {0.f,0.f,0.f,0.f};
  f32x4 acc[4] = {z,z,z,z};
  #pragma unroll
  for (int ks = 0; ks < 16; ks++){
    int kh = ks>>2, kw = ks&3;
    #pragma unroll
    for (int mt = 0; mt < 4; mt++){
      int p = mt*16 + ln;
      int oa = p>>3, ob = p&7;
      bf16x8 a = *(const bf16x8*)&in_t[((2*oa+kw)*18 + (2*ob+kh))*32 + quad*8];
      acc[mt] = __builtin_amdgcn_mfma_f32_16x16x32_bf16(a, bfr[ks], acc[mt],0,0,0);
    }
  }
  float s = 0.f, s2 = 0.f;
  float bz = bias[o];
  short* op = outp + (size_t)n*4096;
  #pragma unroll
  for (int mt = 0; mt < 4; mt++)
    #pragma unroll
    for (int j = 0; j < 4; j++){
      int p = mt*16 + quad*4 + j;
      int oa = p>>3, ob = p&7;
      float v = acc[mt][j] + bz;
      s += v; s2 += v*v;
      op[oa*512 + ob*64 + o] = f2bf(v);
    }
  block_reduce2(s, s2, sbuf);
  if (tid == 0){ atomicAdd(&stat[n*2], s); atomicAdd(&stat[n*2+1], s2); }
}

// ---------------- dec_conv1 MFMA implicit GEMM (bf16 in (final), bf16 out) ----------------
__global__ __launch_bounds__(256) void dec_conv1_mfma(
    const short* __restrict__ in, const short* __restrict__ Bd, const float* __restrict__ bias,
    short* __restrict__ outp, float* __restrict__ stat)
{
  __shared__ __align__(16) short in_t[10*10*64];
  __shared__ float sbuf[16];
  int n = blockIdx.x, tid = threadIdx.x;
  for (int l = tid; l < 10*10*64/4; l += 256) ((unsigned long long*)in_t)[l] = 0ull;
  __syncthreads();
  const short* ip = in + (size_t)n*4096;
  for (int l = tid; l < 1024; l += 256){
    int i4 = l & 15, sb = (l>>4)&7, sa = l>>7;
    *(uint2*)&in_t[((sa+1)*10 + (sb+1))*64 + i4*4] = *(const uint2*)&ip[sa*512 + sb*64 + i4*4];
  }
  int wave = tid>>6, ln = tid&15, quad = (tid>>4)&3;
  int pa = wave & 1, pb = wave >> 1;
  bf16x8 bfr[2][8];
  #pragma unroll
  for (int nt = 0; nt < 2; nt++){
    const short* Brow = Bd + (wave*32 + nt*16 + ln)*256;
    #pragma unroll
    for (int ks = 0; ks < 8; ks++)
      bfr[nt][ks] = *(const bf16x8*)&Brow[ks*32 + quad*8];
  }
  __syncthreads();
  f32x4 z = {0.f,0.f,0.f,0.f};
  f32x4 acc[2][4] = {{z,z,z,z},{z,z,z,z}};
  #pragma unroll
  for (int ks = 0; ks < 8; ks++){
    int tap = ks>>1, ibase = (ks&1)*32 + quad*8;
    int da = tap & 1, db = tap >> 1;
    #pragma unroll
    for (int mt = 0; mt < 4; mt++){
      int p = mt*16 + ln;
      int ta = p>>3, tb = p&7;
      bf16x8 a = *(const bf16x8*)&in_t[((ta+da+pa)*10 + (tb+db+pb))*64 + ibase];
      acc[0][mt] = __builtin_amdgcn_mfma_f32_16x16x32_bf16(a, bfr[0][ks], acc[0][mt],0,0,0);
      acc[1][mt] = __builtin_amdgcn_mfma_f32_16x16x32_bf16(a, bfr[1][ks], acc[1][mt],0,0,0);
    }
  }
  float s = 0.f, s2 = 0.f;
  short* op = outp + (size_t)n*8192;
  #pragma unroll
  for (int nt = 0; nt < 2; nt++){
    int o = nt*16 + ln;
    float bz = bias[o];
    #pragma unroll
    for (int mt = 0; mt < 4; mt++)
      #pragma unroll
      for (int j = 0; j < 4; j++){
        int p = mt*16 + quad*4 + j;
        int ta = p>>3, tb = p&7;
        float v = acc[nt][mt][j] + bz;
        s += v; s2 += v*v;
        op[(2*ta+pa)*512 + (2*tb+pb)*32 + o] = f2bf(v);
      }
  }
  block_reduce2(s, s2, sbuf);
  if (tid == 0){ atomicAdd(&stat[n*2], s); atomicAdd(&stat[n*2+1], s2); }
}

// ---------------- dec_conv2 MFMA implicit GEMM (bf16 in/out) ----------------
__global__ __launch_bounds__(256) void dec_conv2_mfma(
    const short* __restrict__ in, const short* __restrict__ Bd, const float* __restrict__ bias,
    const float* __restrict__ stat_in, short* __restrict__ outp, float* __restrict__ stat)
{
  __shared__ __align__(16) short in_t[18*18*32];
  __shared__ float sbuf[16];
  int n = blockIdx.x, tid = threadIdx.x;
  float smv = stat_in[n*2], sqv = stat_in[n*2+1];
  float m = smv*(1.f/8192.f), rs = rsqrtf(sqv*(1.f/8192.f) - m*m + 1e-5f);
  for (int l = tid; l < 18*18*32/4; l += 256) ((unsigned long long*)in_t)[l] = 0ull;
  __syncthreads();
  const short* ip = in + (size_t)n*8192;
  for (int l = tid; l < 2048; l += 256){
    int i4 = l & 7, sb = (l>>3)&15, sa = l>>7;
    uint2 rv = *(const uint2*)&ip[sa*512 + sb*32 + i4*4];
    float v0 = bf2f((short)(rv.x & 0xFFFF)), v1 = bf2f((short)(rv.x >> 16));
    float v2 = bf2f((short)(rv.y & 0xFFFF)), v3 = bf2f((short)(rv.y >> 16));
    uint2 pk;
    pk.x = f2bf(fmaxf((v0-m)*rs,0.f)) | ((unsigned)f2bf(fmaxf((v1-m)*rs,0.f))<<16);
    pk.y = f2bf(fmaxf((v2-m)*rs,0.f)) | ((unsigned)f2bf(fmaxf((v3-m)*rs,0.f))<<16);
    *(uint2*)&in_t[((sa+1)*18 + (sb+1))*32 + i4*4] = pk;
  }
  int wave = tid>>6, ln = tid&15, quad = (tid>>4)&3;
  int pa = wave & 1, pb = wave >> 1;
  bf16x8 bfr[4];
  {
    const short* Brow = Bd + (wave*16 + ln)*128;
    #pragma unroll
    for (int ks = 0; ks < 4; ks++)
      bfr[ks] = *(const bf16x8*)&Brow[ks*32 + quad*8];
  }
  __syncthreads();
  f32x4 z = {0.f,0.f,0.f,0.f};
  f32x4 acc[16] = {z,z,z,z,z,z,z,z,z,z,z,z,z,z,z,z};
  #pragma unroll
  for (int ks = 0; ks < 4; ks++){
    int da = ks & 1, db = ks >> 1;
    #pragma unroll
    for (int mt = 0; mt < 16; mt++){
      int p = mt*16 + ln;
      int ta = p>>4, tb = p&15;
      bf16x8 a = *(const bf16x8*)&in_t[((ta+da+pa)*18 + (tb+db+pb))*32 + quad*8];
      acc[mt] = __builtin_amdgcn_mfma_f32_16x16x32_bf16(a, bfr[ks], acc[mt],0,0,0);
    }
  }
  float s = 0.f, s2 = 0.f;
  float bz = bias[ln];
  short* op = outp + (size_t)n*16384;
  #pragma unroll
  for (int mt = 0; mt < 16; mt++)
    #pragma unroll
    for (int j = 0; j < 4; j++){
      int p = mt*16 + quad*4 + j;
      int ta = p>>4, tb = p&15;
      float v = acc[mt][j] + bz;
      s += v; s2 += v*v;
      op[(2*ta+pa)*512 + (2*tb+pb)*16 + ln] = f2bf(v);
    }
  block_reduce2(s, s2, sbuf);
  if (tid == 0){ atomicAdd(&stat[n*2], s); atomicAdd(&stat[n*2+1], s2); }
}

// ---------------- dec_conv3 (bf16 in) ----------------
__global__ __launch_bounds__(256) void dec_conv3_ig(
    const short* __restrict__ in, const float* __restrict__ CWT, const float* __restrict__ bias,
    const float* __restrict__ stat_in, float* __restrict__ outp)
{
  __shared__ __align__(16) float in_t[9792];   // [sa34][sb18][i16]
  __shared__ __align__(16) float wl[256];
  int bx = blockIdx.x;
  int n = bx >> 1, b0 = (bx & 1) * 32, tb0 = b0 >> 1;
  int tid = threadIdx.x;
  float sm = stat_in[n*2], sq = stat_in[n*2+1];
  float m = sm*(1.f/16384.f), rs = rsqrtf(sq*(1.f/16384.f) - m*m + 1e-5f);
  const short* ip = in + (size_t)n*16384;
  for (int l = tid; l < 9792; l += 256){
    int i = l & 15, sb = (l >> 4) % 18, sap = l / 288;
    int sa = sap - 1, sbg = tb0 - 1 + sb;
    float v = 0.f;
    if ((unsigned)sa < 32u && (unsigned)sbg < 32u)
      v = fmaxf((bf2f(ip[sa*512 + sbg*16 + i])-m)*rs, 0.f);
    in_t[(sap*18 + sb)*16 + i] = v;
  }
  for (int l = tid; l < 256; l += 256) wl[l] = CWT[l];
  __syncthreads();
  float bv = bias[0];
  int bl = tid & 31, ath = tid >> 5;
  int b = b0 + bl;
  int tb = b >> 1, pb = b & 1;
  float* op = outp + (size_t)n*4096;
  #pragma unroll
  for (int j = 0; j < 8; j++){
    int a = ath*8 + j;
    int ta = a >> 1, pa = a & 1;
    float4 s4 = make_float4(0.f,0.f,0.f,0.f);
    #pragma unroll
    for (int db = 0; db < 2; db++){
      int sb = tb + db + (pb ? 0 : -1);
      int sbl = sb - (tb0 - 1);
      #pragma unroll
      for (int da = 0; da < 2; da++){
        int sa = ta + da + (pa ? 0 : -1);
        int sap = sa + 1;
        const float4* A4 = (const float4*)&in_t[(sap*18 + sbl)*16];
        const float4* B4 = (const float4*)&wl[((pb*2+pa)*4 + db*2+da)*16];
        #pragma unroll
        for (int q = 0; q < 4; q++){
          float4 av = A4[q], bw = B4[q];
          s4.x += av.x*bw.x; s4.y += av.y*bw.y;
          s4.z += av.z*bw.z; s4.w += av.w*bw.w;
        }
      }
    }
    op[a*64 + b] = sigf(bv + s4.x + s4.y + s4.z + s4.w);
  }
}

// ---------------- pair build (bf16) ----------------
__global__ __launch_bounds__(256) void pair_build(const short* __restrict__ tot, short* __restrict__ P)
{
  int r = blockIdx.x;
  int jj = r % 7, fi = r / 7;
  int i = fi & 7, j = fi >> 3;
  int jidx = jj < i ? jj : jj+1;
  const short* srcf = tot + (size_t)fi*1024;
  const short* srco = tot + (size_t)(j*8+jidx)*1024;
  short* op = P + (size_t)r*512;
  for (int c = threadIdx.x; c < 250; c += blockDim.x){
    op[c] = srcf[c];
    op[250+c] = srco[c];
  }
  if (threadIdx.x < 12) op[500 + threadIdx.x] = 0;   // zero K-pad
}

// ---------------- effect (fused att2): tot[:,250:500) = sum_jj ctx*sig(A1@w2+b2) ----------------
__global__ __launch_bounds__(256) void effect_kernel(const float* __restrict__ X1,
    const float* __restrict__ A1, const float* __restrict__ w2, const float* __restrict__ b2,
    short* __restrict__ tot)
{
  __shared__ float att_s[8];
  int row = blockIdx.x, tid = threadIdx.x;
  int jj = tid >> 5, l = tid & 31;
  float d = 0.f;
  if (jj < 7){
    const float* ip = A1 + ((size_t)row*7 + jj)*100;
    for (int c = l; c < 100; c += 32) d += ip[c]*w2[c];
  }
  for (int off = 16; off; off >>= 1) d += __shfl_down(d, off, 32);
  if (jj < 7 && l == 0) att_s[jj] = sigf(d + b2[0]);
  __syncthreads();
  for (int h = tid; h < 250; h += 256){
    float s = 0.f;
    #pragma unroll
    for (int q = 0; q < 7; q++)
      s += X1[((size_t)row*7+q)*250 + h] * att_s[q];
    tot[(size_t)row*1024 + 250 + h] = f2bf(s);
  }
}

extern "C" void kernel_launch(void* const* d_in, const int* in_sizes, int n_in,
                              void* d_out, int out_size, void* d_ws, size_t ws_size,
                              hipStream_t stream) {
  const float* x      = (const float*)d_in[0];
  const float* state  = (const float*)d_in[1];
  const float* c1w    = (const float*)d_in[2];
  const float* c1b    = (const float*)d_in[3];
  const float* c2w    = (const float*)d_in[4];
  const float* c2b    = (const float*)d_in[5];
  const float* c3w    = (const float*)d_in[6];
  const float* c3b    = (const float*)d_in[7];
  const float* efc_w  = (const float*)d_in[8];
  const float* efc_b  = (const float*)d_in[9];
  const float* renc_w = (const float*)d_in[10];
  const float* renc_b = (const float*)d_in[11];
  const float* core_w = (const float*)d_in[12];
  const float* core_b = (const float*)d_in[13];
  const float* ctx_w  = (const float*)d_in[14];
  const float* ctx_b  = (const float*)d_in[15];
  const float* att1_w = (const float*)d_in[16];
  const float* att1_b = (const float*)d_in[17];
  const float* att2_w = (const float*)d_in[18];
  const float* att2_b = (const float*)d_in[19];
  const float* out_w  = (const float*)d_in[20];
  const float* out_b  = (const float*)d_in[21];
  const float* dfc1_w = (const float*)d_in[22];
  const float* dfc1_b = (const float*)d_in[23];
  const float* dfc2_w = (const float*)d_in[24];
  const float* dfc2_b = (const float*)d_in[25];
  const float* d1w    = (const float*)d_in[26];
  const float* d1b    = (const float*)d_in[27];
  const float* d2w    = (const float*)d_in[28];
  const float* d2b    = (const float*)d_in[29];
  const float* d3w    = (const float*)d_in[30];
  const float* d3b    = (const float*)d_in[31];

  float* wsf = (float*)d_ws;
  size_t o = 0;
  float* PB  = wsf + o; o += (size_t)1600*1024;     // split-K partials (fp32, 6.4 MB)
  float* X1  = wsf + o; o += (size_t)2688*250;
  float* A1  = wsf + o; o += (size_t)2688*100;
  float* CWT3 = wsf + o; o += 256;
  float* STAT = wsf + o; o += 5*384*2;
  // bf16 buffers (sizes in shorts; offsets in floats)
  short* E1b  = (short*)(wsf + o); o += (size_t)384*16384/2;   // enc1 raw; later dec2 raw
  short* E2b  = (short*)(wsf + o); o += (size_t)384*8192/2;    // enc2 raw; later dec1 raw
  short* E3b  = (short*)(wsf + o); o += (size_t)384*4096/2;    // enc3 raw; later G2 final
  short* TOTb = (short*)(wsf + o); o += (size_t)384*1024/2;
  short* Prb  = (short*)(wsf + o); o += (size_t)2688*512/2;
  short* C1b  = (short*)(wsf + o); o += (size_t)2688*256/2;
  short* XRb  = (short*)(wsf + o); o += (size_t)384*256/2;
  short* G1b  = (short*)(wsf + o); o += (size_t)384*512/2;
  short* ECV  = (short*)(wsf + o); o += (size_t)384*4096/2;
  short* SBF  = (short*)(wsf + o); o += (size_t)384*256/2;
  short* BtC2 = (short*)(wsf + o); o += 8192/2;
  short* BtC3 = (short*)(wsf + o); o += 32768/2;
  short* BD1  = (short*)(wsf + o); o += 32768/2;
  short* BD2  = (short*)(wsf + o); o += 8192/2;
  short* BT_efc  = (short*)(wsf + o); o += 2097152/2;
  short* BT_renc = (short*)(wsf + o); o += 64000/2;
  short* BT_core = (short*)(wsf + o); o += 128000/2;
  short* BT_ctx  = (short*)(wsf + o); o += 64000/2;
  short* BT_att1 = (short*)(wsf + o); o += 25600/2;
  short* BT_out  = (short*)(wsf + o); o += 256000/2;
  short* BT_dfc1 = (short*)(wsf + o); o += 131072/2;
  short* BT_dfc2 = (short*)(wsf + o); o += 2097152/2;
  short* D1b = E2b;
  short* D2b = E1b;
  short* G2b = E3b;

  float* xout = (float*)d_out;
  float* sout = xout + (size_t)384*4096;

  // prep: small packs + coalesced weight transposes
  prep_all<<<256, 256, 0, stream>>>(STAT,
      d3w, CWT3, c2w, BtC2, c3w, BtC3, d1w, BD1, d2w, BD2, state, SBF);
  transpose_cvt_all<<<1192, 256, 0, stream>>>(
      efc_w, BT_efc, dfc2_w, BT_dfc2, out_w, BT_out, core_w, BT_core,
      dfc1_w, BT_dfc1, renc_w, BT_renc, ctx_w, BT_ctx, att1_w, BT_att1);

  // encoder
  enc_conv1_ig<<<384, 256, 0, stream>>>(x, c1w, c1b, E1b, STAT + ST_ENC1*768);
  enc_conv2_mfma<<<384, 256, 0, stream>>>(E1b, BtC2, c2b, STAT + ST_ENC1*768, E2b, STAT + ST_ENC2*768);
  enc_conv3_mfma<<<384, 256, 0, stream>>>(E2b, BtC3, c3b, STAT + ST_ENC2*768, E3b, STAT + ST_ENC3*768);
  cvt_ln_elu<<<384, 256, 0, stream>>>(E3b, STAT + ST_ENC3*768, ECV);
  gemm_mfma<<<dim3(8,6,8), 256, 0, stream>>>(ECV, BT_efc, PB, 384, 512, 4096, 512);
  reduce_ln<<<384, 256, 0, stream>>>(PB, efc_b, TOTb+500, 384, 512, 8, 1024, 2, 1);

  // state path
  gemm_mfma<<<dim3(4,6,8), 256, 0, stream>>>(SBF, BT_renc, PB, 384, 250, 256, 32);
  reduce_ln<<<384, 256, 0, stream>>>(PB, renc_b, TOTb, 384, 250, 8, 1024, 1, 1);
  pair_build<<<2688, 256, 0, stream>>>(TOTb, Prb);
  gemm_mfma<<<dim3(4,42,2), 256, 0, stream>>>(Prb, BT_core, PB, 2688, 250, 512, 256);
  reduce_ln<<<2688, 256, 0, stream>>>(PB, core_b, C1b, 2688, 250, 2, 256, 1, 1);
  gemm_mfma<<<dim3(4,42,2), 256, 0, stream>>>(C1b, BT_ctx, PB, 2688, 250, 256, 128);
  reduce_ln<<<2688, 256, 0, stream>>>(PB, ctx_b, X1, 2688, 250, 2, 250, 1, 0);
  gemm_mfma<<<dim3(2,42,4), 256, 0, stream>>>(C1b, BT_att1, PB, 2688, 100, 256, 64);
  reduce_ln<<<2688, 256, 0, stream>>>(PB, att1_b, A1, 2688, 100, 4, 100, 3, 0);
  effect_kernel<<<384, 256, 0, stream>>>(X1, A1, att2_w, att2_b, TOTb);

  // combine
  gemm_mfma<<<dim3(4,6,8), 256, 0, stream>>>(TOTb, BT_out, PB, 384, 250, 1024, 128);
  reduce_ns<<<384, 256, 0, stream>>>(PB, out_b, XRb, sout, 384, 250, 8);

  // decoder FC
  gemm_mfma<<<dim3(8,6,4), 256, 0, stream>>>(XRb, BT_dfc1, PB, 384, 512, 256, 64);
  reduce_ln<<<384, 256, 0, stream>>>(PB, dfc1_b, G1b, 384, 512, 4, 512, 1, 1);
  gemm_mfma<<<dim3(64,6,1), 256, 0, stream>>>(G1b, BT_dfc2, PB, 384, 4096, 512, 512);
  reduce_ln<<<384, 256, 0, stream>>>(PB, dfc2_b, G2b, 384, 4096, 1, 4096, 1, 1);

  // decoder convs
  dec_conv1_mfma<<<384, 256, 0, stream>>>(G2b, BD1, d1b, D1b, STAT + ST_DEC1*768);
  dec_conv2_mfma<<<384, 256, 0, stream>>>(D1b, BD2, d2b, STAT + ST_DEC1*768, D2b, STAT + ST_DEC2*768);
  dec_conv3_ig<<<768, 256, 0, stream>>>(D2b, CWT3, d3b, STAT + ST_DEC2*768, xout);

  (void)in_sizes; (void)n_in; (void)out_size; (void)ws_size;
}